// Round 1
// baseline (5740.075 us; speedup 1.0000x reference)
//
#include <hip/hip_runtime.h>
#include <math.h>

#define BB 16
#define CIN 40
#define CH 256
#define NN 1024
#define KROWS 257
#define KP 272          // 257 padded to 17*16 for clean GEMM k-loop
#define NLAYERS 6

// ---------- block reduction (256 threads = 4 waves) ----------
__device__ __forceinline__ float blockReduceSum(float v) {
  __shared__ float sred[4];
  const int lane = threadIdx.x & 63;
  const int wid  = threadIdx.x >> 6;
  #pragma unroll
  for (int off = 32; off > 0; off >>= 1) v += __shfl_down(v, off, 64);
  __syncthreads();
  if (lane == 0) sred[wid] = v;
  __syncthreads();
  return sred[0] + sred[1] + sred[2] + sred[3];
}

// ---------- Z0 = tanh(K0 @ Zin) * mask ----------
__global__ void k0_kernel(const float* __restrict__ Zin, const float* __restrict__ K0,
                          const float* __restrict__ mask, float* __restrict__ Zc) {
  const int b = blockIdx.y;
  const int o = blockIdx.x;
  __shared__ float w[CIN];
  if (threadIdx.x < CIN) w[threadIdx.x] = K0[o * CIN + threadIdx.x];
  __syncthreads();
  for (int n = threadIdx.x; n < NN; n += 256) {
    float acc = 0.f;
    #pragma unroll
    for (int c = 0; c < CIN; c++) acc += w[c] * Zin[((size_t)b * CIN + c) * NN + n];
    Zc[((size_t)b * CH + o) * NN + n] = tanhf(acc) * mask[b * NN + n];
  }
}

__global__ void masksum_kernel(const float* __restrict__ mask, float* __restrict__ msum) {
  const int b = blockIdx.x;
  float v = 0.f;
  for (int n = threadIdx.x; n < NN; n += 256) v += mask[b * NN + n];
  v = blockReduceSum(v);
  if (threadIdx.x == 0) msum[b] = v;
}

// ---------- per-row masked center + normalize, then plain center; writes Y ----------
__global__ void rownorm_kernel(const float* __restrict__ Z, const float* __restrict__ mask,
                               const float* __restrict__ msum, float* __restrict__ Y) {
  const int b = blockIdx.y;
  const int c = blockIdx.x;            // 0..256 (c==256 is the pos row)
  const int t = threadIdx.x;
  const float* mrow = mask + b * NN;
  float x[4];
  if (c < CH) {
    const float* row = Z + ((size_t)b * CH + c) * NN;
    float mv[4];
    float s = 0.f;
    #pragma unroll
    for (int j = 0; j < 4; j++) { int n = t + j * 256; x[j] = row[n]; mv[j] = mrow[n]; s += x[j] * mv[j]; }
    s = blockReduceSum(s);
    const float mean = s / msum[b];
    float q = 0.f;
    #pragma unroll
    for (int j = 0; j < 4; j++) { x[j] -= mean * mv[j]; q += x[j] * x[j]; }
    q = blockReduceSum(q);
    const float rs = 1.0f / sqrtf(q / msum[b] + 1e-4f);
    #pragma unroll
    for (int j = 0; j < 4; j++) x[j] *= rs;
  } else {
    #pragma unroll
    for (int j = 0; j < 4; j++) { int n = t + j * 256; x[j] = 0.5f * ((float)n * (1.0f / (NN - 1))) * mrow[n]; }
  }
  float s2 = 0.f;
  #pragma unroll
  for (int j = 0; j < 4; j++) s2 += x[j];
  s2 = blockReduceSum(s2);
  const float pm = s2 * (1.0f / NN);
  float* yrow = Y + ((size_t)b * KP + c) * NN;
  #pragma unroll
  for (int j = 0; j < 4; j++) yrow[t + j * 256] = x[j] - pm;
}

// ---------- n2[b,n] = sum_k Y[b,k,n]^2 ----------
__global__ void n2_kernel(const float* __restrict__ Y, float* __restrict__ n2) {
  const int idx = blockIdx.x * 256 + threadIdx.x;   // over BB*NN
  const int b = idx >> 10, n = idx & 1023;
  const float* yb = Y + (size_t)b * KP * NN + n;
  float s = 0.f;
  for (int k = 0; k < KROWS; k++) { float v = yb[(size_t)k * NN]; s += v * v; }
  n2[idx] = s;
}

// ---------- Gram + distance: Wd = sqrt(max(3/257*(n2n+n2m-2G),eps))*mm ----------
__launch_bounds__(256)
__global__ void gram_kernel(const float* __restrict__ Y, const float* __restrict__ n2,
                            const float* __restrict__ mask, float* __restrict__ Wd,
                            float* __restrict__ sigpart) {
  const int b = blockIdx.z;
  const int n0 = blockIdx.x * 64, m0 = blockIdx.y * 64;
  const int tid = threadIdx.x;
  const int jl = tid >> 4, il = (tid & 15) << 2;
  const int to = (tid >> 4) << 2, tn = (tid & 15) << 2;
  __shared__ float sA[16][64];
  __shared__ float sB[16][64];
  const float* Yb = Y + (size_t)b * KP * NN;
  float acc[4][4] = {};
  for (int k0 = 0; k0 < KP; k0 += 16) {
    *(float4*)&sA[jl][il] = *(const float4*)&Yb[(size_t)(k0 + jl) * NN + n0 + il];
    *(float4*)&sB[jl][il] = *(const float4*)&Yb[(size_t)(k0 + jl) * NN + m0 + il];
    __syncthreads();
    #pragma unroll
    for (int kk = 0; kk < 16; kk++) {
      const float4 a4 = *(const float4*)&sA[kk][to];
      const float4 b4 = *(const float4*)&sB[kk][tn];
      const float av[4] = {a4.x, a4.y, a4.z, a4.w};
      const float bv[4] = {b4.x, b4.y, b4.z, b4.w};
      #pragma unroll
      for (int i = 0; i < 4; i++)
        #pragma unroll
        for (int j = 0; j < 4; j++) acc[i][j] += av[i] * bv[j];
    }
    __syncthreads();
  }
  float nn_[4], mkn[4];
  #pragma unroll
  for (int i = 0; i < 4; i++) { nn_[i] = n2[b * NN + n0 + to + i]; mkn[i] = mask[b * NN + n0 + to + i]; }
  const float4 m2 = *(const float4*)&n2[b * NN + m0 + tn];
  const float4 mk4 = *(const float4*)&mask[b * NN + m0 + tn];
  const float mm2[4] = {m2.x, m2.y, m2.z, m2.w};
  const float mkm[4] = {mk4.x, mk4.y, mk4.z, mk4.w};
  const float scale = 3.0f / 257.0f;
  float lsum = 0.f;
  #pragma unroll
  for (int i = 0; i < 4; i++) {
    float ov[4];
    #pragma unroll
    for (int j = 0; j < 4; j++) {
      float D = scale * (nn_[i] + mm2[j] - 2.0f * acc[i][j]);
      float d = sqrtf(fmaxf(D, 1e-12f));
      float mmv = mkn[i] * mkm[j];
      float wd = d * mmv;
      ov[j] = wd;
      lsum += wd * mmv;
    }
    float4 o4; o4.x = ov[0]; o4.y = ov[1]; o4.z = ov[2]; o4.w = ov[3];
    *(float4*)&Wd[((size_t)b * NN + n0 + to + i) * NN + m0 + tn] = o4;
  }
  lsum = blockReduceSum(lsum);
  if (tid == 0) sigpart[b * 256 + blockIdx.y * 16 + blockIdx.x] = lsum;
}

// ---------- finalize sigma -> fb = -10*msum^2/signum ----------
__global__ void sigfinal_kernel(const float* __restrict__ sigpart, const float* __restrict__ msum,
                                float* __restrict__ fbuf) {
  const int b = blockIdx.x;
  float v = sigpart[b * 256 + threadIdx.x];
  v = blockReduceSum(v);
  if (threadIdx.x == 0) { const float ms = msum[b]; fbuf[b] = -10.0f * ms * ms / v; }
}

// ---------- W = exp(fb*Wd)*mm in-place; Wsum row sums ----------
__global__ void exp_kernel(float* __restrict__ Wd, const float* __restrict__ mask,
                           const float* __restrict__ fbuf, float* __restrict__ wsum) {
  const int b = blockIdx.y, n = blockIdx.x;
  const float fb = fbuf[b];
  const float mn = mask[b * NN + n];
  float4* row = (float4*)(Wd + ((size_t)b * NN + n) * NN);
  const float4 mk = ((const float4*)(mask + b * NN))[threadIdx.x];
  float4 w = row[threadIdx.x];
  w.x = expf(fb * w.x) * mn * mk.x;
  w.y = expf(fb * w.y) * mn * mk.y;
  w.z = expf(fb * w.z) * mn * mk.z;
  w.w = expf(fb * w.w) * mn * mk.w;
  row[threadIdx.x] = w;
  float s = w.x + w.y + w.z + w.w;
  s = blockReduceSum(s);
  if (threadIdx.x == 0) wsum[b * NN + n] = s;
}

// ---------- cv GEMM: out = alpha*(op(Wm)@X)*mask [+ add] [Z - h*(...)] ----------
// MODE 0: out = v;  MODE 1: out = v + add;  MODE 2: out = zin - 0.01*(v + add)
template <int TRANS, int MODE>
__launch_bounds__(256)
__global__ void cv_kernel(const float* __restrict__ Wm, const float* __restrict__ Xin,
                          const float* __restrict__ add, const float* __restrict__ zin,
                          const float* __restrict__ mask, const float* __restrict__ alphap,
                          float* __restrict__ out) {
  __shared__ float sA[16][64];
  __shared__ float sB[16][64];
  const int b = blockIdx.z;
  const int r0 = blockIdx.y * 64;
  const int c0 = blockIdx.x * 64;
  const int tid = threadIdx.x;
  const int to = (tid >> 4) << 2;
  const int tn = (tid & 15) << 2;
  float acc[4][4] = {};
  const float* Xb = Xin + (size_t)b * CH * NN;
  for (int k0 = 0; k0 < CH; k0 += 16) {
    if (TRANS) {
      const int j = tid >> 4, i2 = (tid & 15) << 2;
      *(float4*)&sA[j][i2] = *(const float4*)&Wm[(size_t)(k0 + j) * CH + r0 + i2];
    } else {
      const int i2 = tid >> 2, j = (tid & 3) << 2;
      float4 a = *(const float4*)&Wm[(size_t)(r0 + i2) * CH + k0 + j];
      sA[j + 0][i2] = a.x; sA[j + 1][i2] = a.y; sA[j + 2][i2] = a.z; sA[j + 3][i2] = a.w;
    }
    { const int j = tid >> 4, i2 = (tid & 15) << 2;
      *(float4*)&sB[j][i2] = *(const float4*)&Xb[(size_t)(k0 + j) * NN + c0 + i2]; }
    __syncthreads();
    #pragma unroll
    for (int kk = 0; kk < 16; kk++) {
      const float4 a4 = *(const float4*)&sA[kk][to];
      const float4 b4 = *(const float4*)&sB[kk][tn];
      const float av[4] = {a4.x, a4.y, a4.z, a4.w};
      const float bv[4] = {b4.x, b4.y, b4.z, b4.w};
      #pragma unroll
      for (int i = 0; i < 4; i++)
        #pragma unroll
        for (int j = 0; j < 4; j++) acc[i][j] += av[i] * bv[j];
    }
    __syncthreads();
  }
  const float alpha = alphap[0];
  const float4 mk4 = *(const float4*)&mask[b * NN + c0 + tn];
  const float mk[4] = {mk4.x, mk4.y, mk4.z, mk4.w};
  #pragma unroll
  for (int i = 0; i < 4; i++) {
    const size_t off = ((size_t)b * CH + r0 + to + i) * NN + c0 + tn;
    float v[4];
    #pragma unroll
    for (int j = 0; j < 4; j++) v[j] = alpha * acc[i][j] * mk[j];
    if (MODE >= 1) {
      const float4 ad = *(const float4*)&add[off];
      v[0] += ad.x; v[1] += ad.y; v[2] += ad.z; v[3] += ad.w;
    }
    float4 o4;
    if (MODE == 2) {
      const float4 z4 = *(const float4*)&zin[off];
      o4.x = z4.x - 0.01f * v[0]; o4.y = z4.y - 0.01f * v[1];
      o4.z = z4.z - 0.01f * v[2]; o4.w = z4.w - 0.01f * v[3];
    } else {
      o4.x = v[0]; o4.y = v[1]; o4.z = v[2]; o4.w = v[3];
    }
    *(float4*)&out[off] = o4;
  }
}

// ---------- mm1: out = X*Wsum(col) - X @ W ----------
__launch_bounds__(256)
__global__ void mm1_kernel(const float* __restrict__ Xin, const float* __restrict__ Wb,
                           const float* __restrict__ wsum, float* __restrict__ out) {
  __shared__ float sA[16][64];
  __shared__ float sB[16][64];
  const int b = blockIdx.z;
  const int r0 = blockIdx.y * 64;
  const int m0 = blockIdx.x * 64;
  const int tid = threadIdx.x;
  const int to = (tid >> 4) << 2;
  const int tn = (tid & 15) << 2;
  float acc[4][4] = {};
  const float* Xb = Xin + (size_t)b * CH * NN;
  const float* Wbb = Wb + (size_t)b * NN * NN;
  for (int k0 = 0; k0 < NN; k0 += 16) {
    { const int i2 = tid >> 2, j = (tid & 3) << 2;
      float4 a = *(const float4*)&Xb[(size_t)(r0 + i2) * NN + k0 + j];
      sA[j + 0][i2] = a.x; sA[j + 1][i2] = a.y; sA[j + 2][i2] = a.z; sA[j + 3][i2] = a.w; }
    { const int j = tid >> 4, i2 = (tid & 15) << 2;
      *(float4*)&sB[j][i2] = *(const float4*)&Wbb[(size_t)(k0 + j) * NN + m0 + i2]; }
    __syncthreads();
    #pragma unroll
    for (int kk = 0; kk < 16; kk++) {
      const float4 a4 = *(const float4*)&sA[kk][to];
      const float4 b4 = *(const float4*)&sB[kk][tn];
      const float av[4] = {a4.x, a4.y, a4.z, a4.w};
      const float bv[4] = {b4.x, b4.y, b4.z, b4.w};
      #pragma unroll
      for (int i = 0; i < 4; i++)
        #pragma unroll
        for (int j = 0; j < 4; j++) acc[i][j] += av[i] * bv[j];
    }
    __syncthreads();
  }
  const float4 ws4 = *(const float4*)&wsum[b * NN + m0 + tn];
  const float ws[4] = {ws4.x, ws4.y, ws4.z, ws4.w};
  #pragma unroll
  for (int i = 0; i < 4; i++) {
    const size_t off = ((size_t)b * CH + r0 + to + i) * NN + m0 + tn;
    const float4 xv = *(const float4*)&Xin[off];
    float4 o4;
    o4.x = xv.x * ws[0] - acc[i][0];
    o4.y = xv.y * ws[1] - acc[i][1];
    o4.z = xv.z * ws[2] - acc[i][2];
    o4.w = xv.w * ws[3] - acc[i][3];
    *(float4*)&out[off] = o4;
  }
}

// ---------- A = (A - masked_mean(A))*mask ----------
__global__ void centerA_kernel(float* __restrict__ A, const float* __restrict__ mask,
                               const float* __restrict__ msum) {
  const int b = blockIdx.y, c = blockIdx.x;
  float* row = A + ((size_t)b * CH + c) * NN;
  const float* mrow = mask + b * NN;
  const int t = threadIdx.x;
  float x[4], mv[4];
  float s = 0.f;
  #pragma unroll
  for (int j = 0; j < 4; j++) { int n = t + j * 256; x[j] = row[n]; mv[j] = mrow[n]; s += x[j] * mv[j]; }
  s = blockReduceSum(s);
  const float mean = s / msum[b];
  #pragma unroll
  for (int j = 0; j < 4; j++) row[t + j * 256] = (x[j] - mean) * mv[j];
}

// ---------- A = relu(A / sqrt(sum_c A^2 + 0.001)) ----------
__global__ void colnorm_kernel(float* __restrict__ A) {
  const int idx = blockIdx.x * 256 + threadIdx.x;
  const int b = idx >> 10, n = idx & 1023;
  float* col = A + (size_t)b * CH * NN + n;
  float s = 0.001f;
  for (int c = 0; c < CH; c++) { float v = col[(size_t)c * NN]; s += v * v; }
  const float rs = 1.0f / sqrtf(s);
  for (int c = 0; c < CH; c++) {
    float v = col[(size_t)c * NN] * rs;
    col[(size_t)c * NN] = v > 0.f ? v : 0.f;
  }
}

// ---------- Zout = (Wend @ Z)*mask; write + centered copy ----------
__global__ void zout_kernel(const float* __restrict__ Z, const float* __restrict__ Wend,
                            const float* __restrict__ mask, float* __restrict__ outZ,
                            float* __restrict__ Zcent) {
  const int b = blockIdx.x;
  __shared__ float w[3 * CH];
  for (int i = threadIdx.x; i < 3 * CH; i += 256) w[i] = Wend[i];
  __syncthreads();
  float a[3][4];
  #pragma unroll
  for (int j = 0; j < 4; j++) { a[0][j] = 0.f; a[1][j] = 0.f; a[2][j] = 0.f; }
  const float* Zb = Z + (size_t)b * CH * NN;
  for (int c = 0; c < CH; c++) {
    const float w0 = w[c], w1 = w[CH + c], w2 = w[2 * CH + c];
    #pragma unroll
    for (int j = 0; j < 4; j++) {
      float zv = Zb[(size_t)c * NN + threadIdx.x + j * 256];
      a[0][j] += w0 * zv; a[1][j] += w1 * zv; a[2][j] += w2 * zv;
    }
  }
  float sum[3] = {0.f, 0.f, 0.f};
  #pragma unroll
  for (int j = 0; j < 4; j++) {
    const int n = threadIdx.x + j * 256;
    const float mv = mask[b * NN + n];
    #pragma unroll
    for (int o = 0; o < 3; o++) {
      a[o][j] *= mv;
      outZ[((size_t)b * 3 + o) * NN + n] = a[o][j];
      sum[o] += a[o][j];
    }
  }
  for (int o = 0; o < 3; o++) {
    float s = blockReduceSum(sum[o]);
    const float mean = s * (1.0f / NN);
    #pragma unroll
    for (int j = 0; j < 4; j++) {
      const int n = threadIdx.x + j * 256;
      Zcent[((size_t)b * 3 + o) * NN + n] = a[o][j] - mean;
    }
  }
}

// ---------- final distances ----------
__global__ void dist_kernel(const float* __restrict__ Zcent, float* __restrict__ outD) {
  const int b = blockIdx.z;
  const int n = blockIdx.y;
  const int m = blockIdx.x * 256 + threadIdx.x;
  const float* Zb = Zcent + (size_t)b * 3 * NN;
  const float x0 = Zb[n], x1 = Zb[NN + n], x2 = Zb[2 * NN + n];
  const float d0 = x0 - Zb[m], d1 = x1 - Zb[NN + m], d2 = x2 - Zb[2 * NN + m];
  const float D = d0 * d0 + d1 * d1 + d2 * d2;
  outD[((size_t)b * NN + n) * NN + m] = sqrtf(fmaxf(D, 1e-12f));
}

extern "C" void kernel_launch(void* const* d_in, const int* in_sizes, int n_in,
                              void* d_out, int out_size, void* d_ws, size_t ws_size,
                              hipStream_t stream) {
  const float* Zin  = (const float*)d_in[0];
  const float* mask = (const float*)d_in[1];
  const float* K0   = (const float*)d_in[2];
  const float* Knet = (const float*)d_in[3];
  const float* W    = (const float*)d_in[4];
  const float* Wend = (const float*)d_in[5];
  float* out = (float*)d_out;

  // Adjacency/Gram buffer lives in d_out's dist region (written last).
  float* Wbuf = out;                          // BB*NN*NN
  float* outZ = out + (size_t)BB * NN * NN;   // BB*3*NN

  float* p = (float*)d_ws;
  float* Y    = p; p += (size_t)BB * KP * NN;   // 4,456,448
  float* Zcur = p; p += (size_t)BB * CH * NN;   // 4,194,304
  float* U    = p; p += (size_t)BB * CH * NN;
  float* V    = p; p += (size_t)BB * CH * NN;
  float* n2b  = p; p += BB * NN;
  float* wsb  = p; p += BB * NN;
  float* msum = p; p += BB;
  float* sigp = p; p += BB * 256;
  float* fbuf = p; p += BB;
  float* Zcent= p; p += BB * 3 * NN;
  float* Xb = Y;   // alias: Y is free after exp_kernel each layer

  const dim3 gcv(NN / 64, CH / 64, BB);

  masksum_kernel<<<BB, 256, 0, stream>>>(mask, msum);
  k0_kernel<<<dim3(CH, BB), 256, 0, stream>>>(Zin, K0, mask, Zcur);

  for (int layer = 0; layer < NLAYERS; layer++) {
    // Y gets clobbered by the Xb alias each layer; re-zero so pad rows are 0.
    hipMemsetAsync(Y, 0, (size_t)BB * KP * NN * sizeof(float), stream);
    rownorm_kernel<<<dim3(KROWS, BB), 256, 0, stream>>>(Zcur, mask, msum, Y);
    n2_kernel<<<BB * NN / 256, 256, 0, stream>>>(Y, n2b);
    gram_kernel<<<dim3(16, 16, BB), 256, 0, stream>>>(Y, n2b, mask, Wbuf, sigp);
    sigfinal_kernel<<<BB, 256, 0, stream>>>(sigp, msum, fbuf);
    exp_kernel<<<dim3(NN, BB), 256, 0, stream>>>(Wbuf, mask, fbuf, wsb);

    const float* Wi = W + (size_t)layer * 3 * CH * CH;
    const float* Ki = Knet + layer * 3;

    // Ai = K0*cv(W0,Z) + mm1(K1*cv(W1,Z) + mm1(K2*cv(W2,Z)))
    cv_kernel<0, 0><<<gcv, 256, 0, stream>>>(Wi + 2 * CH * CH, Zcur, nullptr, nullptr, mask, Ki + 2, U);
    mm1_kernel<<<gcv, 256, 0, stream>>>(U, Wbuf, wsb, V);
    cv_kernel<0, 1><<<gcv, 256, 0, stream>>>(Wi + 1 * CH * CH, Zcur, V, nullptr, mask, Ki + 1, U);
    mm1_kernel<<<gcv, 256, 0, stream>>>(U, Wbuf, wsb, V);
    cv_kernel<0, 1><<<gcv, 256, 0, stream>>>(Wi, Zcur, V, nullptr, mask, Ki, U);

    centerA_kernel<<<dim3(CH, BB), 256, 0, stream>>>(U, mask, msum);
    colnorm_kernel<<<BB * NN / 256, 256, 0, stream>>>(U);

    // Z -= h * (K0*cvT(W0,A) + mm1(K1*cvT(W1,A) + mm1(K2*cvT(W2,A))))
    cv_kernel<1, 0><<<gcv, 256, 0, stream>>>(Wi + 2 * CH * CH, U, nullptr, nullptr, mask, Ki + 2, V);
    mm1_kernel<<<gcv, 256, 0, stream>>>(V, Wbuf, wsb, Xb);
    cv_kernel<1, 1><<<gcv, 256, 0, stream>>>(Wi + 1 * CH * CH, U, Xb, nullptr, mask, Ki + 1, V);
    mm1_kernel<<<gcv, 256, 0, stream>>>(V, Wbuf, wsb, Xb);
    cv_kernel<1, 2><<<gcv, 256, 0, stream>>>(Wi, U, Xb, Zcur, mask, Ki, Zcur);
  }

  zout_kernel<<<BB, 256, 0, stream>>>(Zcur, Wend, mask, outZ, Zcent);
  dist_kernel<<<dim3(NN / 256, NN, BB), 256, 0, stream>>>(Zcent, out);
}

// Round 2
// 3848.029 us; speedup vs baseline: 1.4917x; 1.4917x over previous
//
#include <hip/hip_runtime.h>
#include <math.h>

#define BB 16
#define CIN 40
#define CH 256
#define NN 1024
#define KROWS 257
#define KP 272          // 257 padded to 17*16 for clean GEMM k-loop
#define NLAYERS 6

typedef __attribute__((ext_vector_type(8))) short bh8;
typedef __attribute__((ext_vector_type(4))) float f4;

__device__ __forceinline__ unsigned short bf16_rne(float x) {
  unsigned int u = __float_as_uint(x);
  u += 0x7fffu + ((u >> 16) & 1u);
  return (unsigned short)(u >> 16);
}
__device__ __forceinline__ float bf16_f(unsigned short h) {
  return __uint_as_float(((unsigned int)h) << 16);
}

#define GLD16(gp, lp) __builtin_amdgcn_global_load_lds( \
    (const __attribute__((address_space(1))) void*)(gp), \
    (__attribute__((address_space(3))) void*)(lp), 16, 0, 0)

// ---------- block reduction (256 threads = 4 waves) ----------
__device__ __forceinline__ float blockReduceSum(float v) {
  __shared__ float sred[4];
  const int lane = threadIdx.x & 63;
  const int wid  = threadIdx.x >> 6;
  #pragma unroll
  for (int off = 32; off > 0; off >>= 1) v += __shfl_down(v, off, 64);
  __syncthreads();
  if (lane == 0) sred[wid] = v;
  __syncthreads();
  return sred[0] + sred[1] + sred[2] + sred[3];
}

// ---------- Z0 = tanh(K0 @ Zin) * mask ----------
__global__ void k0_kernel(const float* __restrict__ Zin, const float* __restrict__ K0,
                          const float* __restrict__ mask, float* __restrict__ Zc) {
  const int b = blockIdx.y;
  const int o = blockIdx.x;
  __shared__ float w[CIN];
  if (threadIdx.x < CIN) w[threadIdx.x] = K0[o * CIN + threadIdx.x];
  __syncthreads();
  for (int n = threadIdx.x; n < NN; n += 256) {
    float acc = 0.f;
    #pragma unroll
    for (int c = 0; c < CIN; c++) acc += w[c] * Zin[((size_t)b * CIN + c) * NN + n];
    Zc[((size_t)b * CH + o) * NN + n] = tanhf(acc) * mask[b * NN + n];
  }
}

__global__ void masksum_kernel(const float* __restrict__ mask, float* __restrict__ msum) {
  const int b = blockIdx.x;
  float v = 0.f;
  for (int n = threadIdx.x; n < NN; n += 256) v += mask[b * NN + n];
  v = blockReduceSum(v);
  if (threadIdx.x == 0) msum[b] = v;
}

// ---------- per-row masked center + normalize, then plain center; writes Y ----------
__global__ void rownorm_kernel(const float* __restrict__ Z, const float* __restrict__ mask,
                               const float* __restrict__ msum, float* __restrict__ Y) {
  const int b = blockIdx.y;
  const int c = blockIdx.x;            // 0..256 (c==256 is the pos row)
  const int t = threadIdx.x;
  const float* mrow = mask + b * NN;
  float x[4];
  if (c < CH) {
    const float* row = Z + ((size_t)b * CH + c) * NN;
    float mv[4];
    float s = 0.f;
    #pragma unroll
    for (int j = 0; j < 4; j++) { int n = t + j * 256; x[j] = row[n]; mv[j] = mrow[n]; s += x[j] * mv[j]; }
    s = blockReduceSum(s);
    const float mean = s / msum[b];
    float q = 0.f;
    #pragma unroll
    for (int j = 0; j < 4; j++) { x[j] -= mean * mv[j]; q += x[j] * x[j]; }
    q = blockReduceSum(q);
    const float rs = 1.0f / sqrtf(q / msum[b] + 1e-4f);
    #pragma unroll
    for (int j = 0; j < 4; j++) x[j] *= rs;
  } else {
    #pragma unroll
    for (int j = 0; j < 4; j++) { int n = t + j * 256; x[j] = 0.5f * ((float)n * (1.0f / (NN - 1))) * mrow[n]; }
  }
  float s2 = 0.f;
  #pragma unroll
  for (int j = 0; j < 4; j++) s2 += x[j];
  s2 = blockReduceSum(s2);
  const float pm = s2 * (1.0f / NN);
  float* yrow = Y + ((size_t)b * KP + c) * NN;
  #pragma unroll
  for (int j = 0; j < 4; j++) yrow[t + j * 256] = x[j] - pm;
}

// ---------- n2[b,n] = sum_k Y[b,k,n]^2 ----------
__global__ void n2_kernel(const float* __restrict__ Y, float* __restrict__ n2) {
  const int idx = blockIdx.x * 256 + threadIdx.x;   // over BB*NN
  const int b = idx >> 10, n = idx & 1023;
  const float* yb = Y + (size_t)b * KP * NN + n;
  float s = 0.f;
  for (int k = 0; k < KROWS; k++) { float v = yb[(size_t)k * NN]; s += v * v; }
  n2[idx] = s;
}

// ---------- Gram + distance: dist = sqrt(max(3/257*(n2n+n2m-2G),eps))*mm ----------
__launch_bounds__(256)
__global__ void gram_kernel(const float* __restrict__ Y, const float* __restrict__ n2,
                            const float* __restrict__ mask, float* __restrict__ Wd,
                            float* __restrict__ sigpart) {
  const int b = blockIdx.z;
  const int n0 = blockIdx.x * 64, m0 = blockIdx.y * 64;
  const int tid = threadIdx.x;
  const int jl = tid >> 4, il = (tid & 15) << 2;
  const int to = (tid >> 4) << 2, tn = (tid & 15) << 2;
  __shared__ float sA[16][64];
  __shared__ float sB[16][64];
  const float* Yb = Y + (size_t)b * KP * NN;
  float acc[4][4] = {};
  for (int k0 = 0; k0 < KP; k0 += 16) {
    *(float4*)&sA[jl][il] = *(const float4*)&Yb[(size_t)(k0 + jl) * NN + n0 + il];
    *(float4*)&sB[jl][il] = *(const float4*)&Yb[(size_t)(k0 + jl) * NN + m0 + il];
    __syncthreads();
    #pragma unroll
    for (int kk = 0; kk < 16; kk++) {
      const float4 a4 = *(const float4*)&sA[kk][to];
      const float4 b4 = *(const float4*)&sB[kk][tn];
      const float av[4] = {a4.x, a4.y, a4.z, a4.w};
      const float bv[4] = {b4.x, b4.y, b4.z, b4.w};
      #pragma unroll
      for (int i = 0; i < 4; i++)
        #pragma unroll
        for (int j = 0; j < 4; j++) acc[i][j] += av[i] * bv[j];
    }
    __syncthreads();
  }
  float nn_[4], mkn[4];
  #pragma unroll
  for (int i = 0; i < 4; i++) { nn_[i] = n2[b * NN + n0 + to + i]; mkn[i] = mask[b * NN + n0 + to + i]; }
  const float4 m2 = *(const float4*)&n2[b * NN + m0 + tn];
  const float4 mk4 = *(const float4*)&mask[b * NN + m0 + tn];
  const float mm2[4] = {m2.x, m2.y, m2.z, m2.w};
  const float mkm[4] = {mk4.x, mk4.y, mk4.z, mk4.w};
  const float scale = 3.0f / 257.0f;
  float lsum = 0.f;
  #pragma unroll
  for (int i = 0; i < 4; i++) {
    float ov[4];
    #pragma unroll
    for (int j = 0; j < 4; j++) {
      float D = scale * (nn_[i] + mm2[j] - 2.0f * acc[i][j]);
      float d = sqrtf(fmaxf(D, 1e-12f));
      float mmv = mkn[i] * mkm[j];
      float wd = d * mmv;
      ov[j] = wd;
      lsum += wd * mmv;
    }
    float4 o4; o4.x = ov[0]; o4.y = ov[1]; o4.z = ov[2]; o4.w = ov[3];
    *(float4*)&Wd[((size_t)b * NN + n0 + to + i) * NN + m0 + tn] = o4;
  }
  lsum = blockReduceSum(lsum);
  if (tid == 0) sigpart[b * 256 + blockIdx.y * 16 + blockIdx.x] = lsum;
}

// ---------- finalize sigma -> fb = -10*msum^2/signum ----------
__global__ void sigfinal_kernel(const float* __restrict__ sigpart, const float* __restrict__ msum,
                                float* __restrict__ fbuf) {
  const int b = blockIdx.x;
  float v = sigpart[b * 256 + threadIdx.x];
  v = blockReduceSum(v);
  if (threadIdx.x == 0) { const float ms = msum[b]; fbuf[b] = -10.0f * ms * ms / v; }
}

// ---------- W = exp(fb*dist)*mm -> split bf16 (Wh,Wl); Wsum row sums ----------
__global__ void exp2_kernel(const float* __restrict__ dist, const float* __restrict__ mask,
                            const float* __restrict__ fbuf, unsigned short* __restrict__ Wh,
                            unsigned short* __restrict__ Wl, float* __restrict__ wsum) {
  const int b = blockIdx.y, n = blockIdx.x;
  const float fb = fbuf[b];
  const float mn = mask[b * NN + n];
  const size_t roff = ((size_t)b * NN + n) * NN;
  const float4 mk = ((const float4*)(mask + b * NN))[threadIdx.x];
  float4 w = ((const float4*)(dist + roff))[threadIdx.x];
  w.x = expf(fb * w.x) * mn * mk.x;
  w.y = expf(fb * w.y) * mn * mk.y;
  w.z = expf(fb * w.z) * mn * mk.z;
  w.w = expf(fb * w.w) * mn * mk.w;
  ushort4 h4, l4;
  h4.x = bf16_rne(w.x); l4.x = bf16_rne(w.x - bf16_f(h4.x));
  h4.y = bf16_rne(w.y); l4.y = bf16_rne(w.y - bf16_f(h4.y));
  h4.z = bf16_rne(w.z); l4.z = bf16_rne(w.z - bf16_f(h4.z));
  h4.w = bf16_rne(w.w); l4.w = bf16_rne(w.w - bf16_f(h4.w));
  ((ushort4*)(Wh + roff))[threadIdx.x] = h4;
  ((ushort4*)(Wl + roff))[threadIdx.x] = l4;
  float s = w.x + w.y + w.z + w.w;
  s = blockReduceSum(s);
  if (threadIdx.x == 0) wsum[b * NN + n] = s;
}

// ---------- cv GEMM (fp32): out = alpha*(op(Wm)@X)*mask [+ add] [Z - h*(...)] ----------
// MODE 0: out = v;  MODE 1: out = v + add;  MODE 2: out = zin - 0.01*(v + add)
// CONV 1: also write split-bf16 copy of out into Xh/Xl
template <int TRANS, int MODE, int CONV>
__launch_bounds__(256)
__global__ void cv_kernel(const float* __restrict__ Wm, const float* __restrict__ Xin,
                          const float* __restrict__ add, const float* __restrict__ zin,
                          const float* __restrict__ mask, const float* __restrict__ alphap,
                          float* __restrict__ out, unsigned short* __restrict__ Xh,
                          unsigned short* __restrict__ Xl) {
  __shared__ float sA[16][64];
  __shared__ float sB[16][64];
  const int b = blockIdx.z;
  const int r0 = blockIdx.y * 64;
  const int c0 = blockIdx.x * 64;
  const int tid = threadIdx.x;
  const int to = (tid >> 4) << 2;
  const int tn = (tid & 15) << 2;
  float acc[4][4] = {};
  const float* Xb = Xin + (size_t)b * CH * NN;
  for (int k0 = 0; k0 < CH; k0 += 16) {
    if (TRANS) {
      const int j = tid >> 4, i2 = (tid & 15) << 2;
      *(float4*)&sA[j][i2] = *(const float4*)&Wm[(size_t)(k0 + j) * CH + r0 + i2];
    } else {
      const int i2 = tid >> 2, j = (tid & 3) << 2;
      float4 a = *(const float4*)&Wm[(size_t)(r0 + i2) * CH + k0 + j];
      sA[j + 0][i2] = a.x; sA[j + 1][i2] = a.y; sA[j + 2][i2] = a.z; sA[j + 3][i2] = a.w;
    }
    { const int j = tid >> 4, i2 = (tid & 15) << 2;
      *(float4*)&sB[j][i2] = *(const float4*)&Xb[(size_t)(k0 + j) * NN + c0 + i2]; }
    __syncthreads();
    #pragma unroll
    for (int kk = 0; kk < 16; kk++) {
      const float4 a4 = *(const float4*)&sA[kk][to];
      const float4 b4 = *(const float4*)&sB[kk][tn];
      const float av[4] = {a4.x, a4.y, a4.z, a4.w};
      const float bv[4] = {b4.x, b4.y, b4.z, b4.w};
      #pragma unroll
      for (int i = 0; i < 4; i++)
        #pragma unroll
        for (int j = 0; j < 4; j++) acc[i][j] += av[i] * bv[j];
    }
    __syncthreads();
  }
  const float alpha = alphap[0];
  const float4 mk4 = *(const float4*)&mask[b * NN + c0 + tn];
  const float mk[4] = {mk4.x, mk4.y, mk4.z, mk4.w};
  #pragma unroll
  for (int i = 0; i < 4; i++) {
    const size_t off = ((size_t)b * CH + r0 + to + i) * NN + c0 + tn;
    float v[4];
    #pragma unroll
    for (int j = 0; j < 4; j++) v[j] = alpha * acc[i][j] * mk[j];
    if (MODE >= 1) {
      const float4 ad = *(const float4*)&add[off];
      v[0] += ad.x; v[1] += ad.y; v[2] += ad.z; v[3] += ad.w;
    }
    float4 o4;
    if (MODE == 2) {
      const float4 z4 = *(const float4*)&zin[off];
      o4.x = z4.x - 0.01f * v[0]; o4.y = z4.y - 0.01f * v[1];
      o4.z = z4.z - 0.01f * v[2]; o4.w = z4.w - 0.01f * v[3];
    } else {
      o4.x = v[0]; o4.y = v[1]; o4.z = v[2]; o4.w = v[3];
    }
    *(float4*)&out[off] = o4;
    if (CONV) {
      ushort4 h4, l4;
      h4.x = bf16_rne(o4.x); l4.x = bf16_rne(o4.x - bf16_f(h4.x));
      h4.y = bf16_rne(o4.y); l4.y = bf16_rne(o4.y - bf16_f(h4.y));
      h4.z = bf16_rne(o4.z); l4.z = bf16_rne(o4.z - bf16_f(h4.z));
      h4.w = bf16_rne(o4.w); l4.w = bf16_rne(o4.w - bf16_f(h4.w));
      *(ushort4*)&Xh[off] = h4;
      *(ushort4*)&Xl[off] = l4;
    }
  }
}

// ---------- mm1 via split-bf16 MFMA: out = X*wsum(col) - X @ W ----------
// X approx Xh+Xl, W approx Wh+Wl (W symmetric -> B tile reads W rows).
// acc = Xh*Wh + Xh*Wl + Xl*Wh (fp32 MFMA accum). BM=128 BN=64 BK=32.
__launch_bounds__(256, 2)
__global__ void mm1_mfma_kernel(const unsigned short* __restrict__ Xh,
                                const unsigned short* __restrict__ Xl,
                                const unsigned short* __restrict__ Wh,
                                const unsigned short* __restrict__ Wl,
                                const float* __restrict__ Xf, const float* __restrict__ wsum,
                                float* __restrict__ outp) {
  __shared__ unsigned short lds[12288];     // Ah[128*32] Al[128*32] Bh[64*32] Bl[64*32] = 24 KB
  unsigned short* sAh = lds;
  unsigned short* sAl = lds + 4096;
  unsigned short* sBh = lds + 8192;
  unsigned short* sBl = lds + 10240;
  const int b = blockIdx.z;
  const int r0 = blockIdx.y * 128;
  const int n0 = blockIdx.x * 64;
  const int tid = threadIdx.x;
  const int lane = tid & 63;
  const int wid = tid >> 6;
  const int wr = wid >> 1, wc = wid & 1;   // wave tile: rows wr*64, cols wc*32
  const int srow = lane >> 2;              // staging: row within 16-row chunk
  const int q = lane & 3;                  // staging: 16B slot within row
  const int sl = q ^ ((srow >> 1) & 3);    // pre-swizzled source slot (rule 21)
  const int frow = lane & 15;
  const int h = lane >> 4;
  const int slot8 = (h ^ ((frow >> 1) & 3)) << 3;  // swizzled read slot (ushorts)

  const size_t XB = (size_t)b * CH * NN;
  const size_t WB = (size_t)b * NN * NN;

  f4 zero4 = {0.f, 0.f, 0.f, 0.f};
  f4 acc[4][2];
  #pragma unroll
  for (int mi = 0; mi < 4; mi++)
    #pragma unroll
    for (int ni = 0; ni < 2; ni++) acc[mi][ni] = zero4;

  for (int kt = 0; kt < NN; kt += 32) {
    // ---- stage 24 KB: 24 chunks of 1 KB, 6 per wave ----
    #pragma unroll
    for (int cc = 0; cc < 6; cc++) {
      const int c = wid * 6 + cc;
      const unsigned short* src;
      unsigned short* dst;
      if (c < 8) {
        src = Xh + XB + (size_t)(r0 + c * 16 + srow) * NN + kt + sl * 8;
        dst = sAh + c * 512;
      } else if (c < 16) {
        src = Xl + XB + (size_t)(r0 + (c - 8) * 16 + srow) * NN + kt + sl * 8;
        dst = sAl + (c - 8) * 512;
      } else if (c < 20) {
        src = Wh + WB + (size_t)(n0 + (c - 16) * 16 + srow) * NN + kt + sl * 8;
        dst = sBh + (c - 16) * 512;
      } else {
        src = Wl + WB + (size_t)(n0 + (c - 20) * 16 + srow) * NN + kt + sl * 8;
        dst = sBl + (c - 20) * 512;
      }
      GLD16(src, dst + lane * 8);
    }
    __syncthreads();   // drains vmcnt before barrier (compiler-inserted waitcnt)
    // ---- fragments + 24 MFMA ----
    bh8 ah[4], al[4], bh[2], bl[2];
    #pragma unroll
    for (int mi = 0; mi < 4; mi++) {
      const int off = (wr * 64 + mi * 16 + frow) * 32 + slot8;
      ah[mi] = *(const bh8*)&sAh[off];
      al[mi] = *(const bh8*)&sAl[off];
    }
    #pragma unroll
    for (int ni = 0; ni < 2; ni++) {
      const int off = (wc * 32 + ni * 16 + frow) * 32 + slot8;
      bh[ni] = *(const bh8*)&sBh[off];
      bl[ni] = *(const bh8*)&sBl[off];
    }
    #pragma unroll
    for (int mi = 0; mi < 4; mi++)
      #pragma unroll
      for (int ni = 0; ni < 2; ni++) {
        acc[mi][ni] = __builtin_amdgcn_mfma_f32_16x16x32_bf16(ah[mi], bh[ni], acc[mi][ni], 0, 0, 0);
        acc[mi][ni] = __builtin_amdgcn_mfma_f32_16x16x32_bf16(ah[mi], bl[ni], acc[mi][ni], 0, 0, 0);
        acc[mi][ni] = __builtin_amdgcn_mfma_f32_16x16x32_bf16(al[mi], bh[ni], acc[mi][ni], 0, 0, 0);
      }
    __syncthreads();   // protect LDS before next stage
  }

  // ---- epilogue: out = Xf*wsum - acc.  C/D: col=lane&15, row=(lane>>4)*4+reg ----
  #pragma unroll
  for (int ni = 0; ni < 2; ni++) {
    const int col = n0 + wc * 32 + ni * 16 + frow;
    const float ws = wsum[b * NN + col];
    #pragma unroll
    for (int mi = 0; mi < 4; mi++) {
      #pragma unroll
      for (int r = 0; r < 4; r++) {
        const int row = r0 + wr * 64 + mi * 16 + h * 4 + r;
        const size_t off = XB + (size_t)row * NN + col;
        outp[off] = Xf[off] * ws - acc[mi][ni][r];
      }
    }
  }
}

// ---------- A = (A - masked_mean(A))*mask ----------
__global__ void centerA_kernel(float* __restrict__ A, const float* __restrict__ mask,
                               const float* __restrict__ msum) {
  const int b = blockIdx.y, c = blockIdx.x;
  float* row = A + ((size_t)b * CH + c) * NN;
  const float* mrow = mask + b * NN;
  const int t = threadIdx.x;
  float x[4], mv[4];
  float s = 0.f;
  #pragma unroll
  for (int j = 0; j < 4; j++) { int n = t + j * 256; x[j] = row[n]; mv[j] = mrow[n]; s += x[j] * mv[j]; }
  s = blockReduceSum(s);
  const float mean = s / msum[b];
  #pragma unroll
  for (int j = 0; j < 4; j++) row[t + j * 256] = (x[j] - mean) * mv[j];
}

// ---------- A = relu(A / sqrt(sum_c A^2 + 0.001)) ----------
__global__ void colnorm_kernel(float* __restrict__ A) {
  const int idx = blockIdx.x * 256 + threadIdx.x;
  const int b = idx >> 10, n = idx & 1023;
  float* col = A + (size_t)b * CH * NN + n;
  float s = 0.001f;
  for (int c = 0; c < CH; c++) { float v = col[(size_t)c * NN]; s += v * v; }
  const float rs = 1.0f / sqrtf(s);
  for (int c = 0; c < CH; c++) {
    float v = col[(size_t)c * NN] * rs;
    col[(size_t)c * NN] = v > 0.f ? v : 0.f;
  }
}

// ---------- Zout = (Wend @ Z)*mask; write + centered copy ----------
__global__ void zout_kernel(const float* __restrict__ Z, const float* __restrict__ Wend,
                            const float* __restrict__ mask, float* __restrict__ outZ,
                            float* __restrict__ Zcent) {
  const int b = blockIdx.x;
  __shared__ float w[3 * CH];
  for (int i = threadIdx.x; i < 3 * CH; i += 256) w[i] = Wend[i];
  __syncthreads();
  float a[3][4];
  #pragma unroll
  for (int j = 0; j < 4; j++) { a[0][j] = 0.f; a[1][j] = 0.f; a[2][j] = 0.f; }
  const float* Zb = Z + (size_t)b * CH * NN;
  for (int c = 0; c < CH; c++) {
    const float w0 = w[c], w1 = w[CH + c], w2 = w[2 * CH + c];
    #pragma unroll
    for (int j = 0; j < 4; j++) {
      float zv = Zb[(size_t)c * NN + threadIdx.x + j * 256];
      a[0][j] += w0 * zv; a[1][j] += w1 * zv; a[2][j] += w2 * zv;
    }
  }
  float sum[3] = {0.f, 0.f, 0.f};
  #pragma unroll
  for (int j = 0; j < 4; j++) {
    const int n = threadIdx.x + j * 256;
    const float mv = mask[b * NN + n];
    #pragma unroll
    for (int o = 0; o < 3; o++) {
      a[o][j] *= mv;
      outZ[((size_t)b * 3 + o) * NN + n] = a[o][j];
      sum[o] += a[o][j];
    }
  }
  for (int o = 0; o < 3; o++) {
    float s = blockReduceSum(sum[o]);
    const float mean = s * (1.0f / NN);
    #pragma unroll
    for (int j = 0; j < 4; j++) {
      const int n = threadIdx.x + j * 256;
      Zcent[((size_t)b * 3 + o) * NN + n] = a[o][j] - mean;
    }
  }
}

// ---------- final distances ----------
__global__ void dist_kernel(const float* __restrict__ Zcent, float* __restrict__ outD) {
  const int b = blockIdx.z;
  const int n = blockIdx.y;
  const int m = blockIdx.x * 256 + threadIdx.x;
  const float* Zb = Zcent + (size_t)b * 3 * NN;
  const float x0 = Zb[n], x1 = Zb[NN + n], x2 = Zb[2 * NN + n];
  const float d0 = x0 - Zb[m], d1 = x1 - Zb[NN + m], d2 = x2 - Zb[2 * NN + m];
  const float D = d0 * d0 + d1 * d1 + d2 * d2;
  outD[((size_t)b * NN + n) * NN + m] = sqrtf(fmaxf(D, 1e-12f));
}

extern "C" void kernel_launch(void* const* d_in, const int* in_sizes, int n_in,
                              void* d_out, int out_size, void* d_ws, size_t ws_size,
                              hipStream_t stream) {
  const float* Zin  = (const float*)d_in[0];
  const float* mask = (const float*)d_in[1];
  const float* K0   = (const float*)d_in[2];
  const float* Knet = (const float*)d_in[3];
  const float* W    = (const float*)d_in[4];
  const float* Wend = (const float*)d_in[5];
  float* out = (float*)d_out;

  // d_out scratch: fp32 dist (gram->exp2), then Xh/Xl bf16 (cv->mm1). Final
  // outputs (dist_kernel + zout) are written at the very end.
  float* distbuf = out;                             // BB*NN*NN fp32
  unsigned short* Xh = (unsigned short*)out;        // BB*CH*NN bf16
  unsigned short* Xl = Xh + (size_t)BB * CH * NN;
  float* outZ = out + (size_t)BB * NN * NN;

  float* p = (float*)d_ws;
  float* Y    = p; p += (size_t)BB * KP * NN;
  float* Zcur = p; p += (size_t)BB * CH * NN;
  float* U    = p; p += (size_t)BB * CH * NN;
  float* V    = p; p += (size_t)BB * CH * NN;
  unsigned short* Whb = (unsigned short*)p; p += (size_t)BB * NN * NN / 2;  // bf16 hi
  unsigned short* Wlb = (unsigned short*)p; p += (size_t)BB * NN * NN / 2;  // bf16 lo
  float* n2b  = p; p += BB * NN;
  float* wsb  = p; p += BB * NN;
  float* msum = p; p += BB;
  float* sigp = p; p += BB * 256;
  float* fbuf = p; p += BB;
  float* Zcent= p; p += BB * 3 * NN;
  float* Xb = Y;   // alias: Y free after gram each layer

  const dim3 gcv(NN / 64, CH / 64, BB);
  const dim3 gmm(NN / 64, CH / 128, BB);

  masksum_kernel<<<BB, 256, 0, stream>>>(mask, msum);
  k0_kernel<<<dim3(CH, BB), 256, 0, stream>>>(Zin, K0, mask, Zcur);

  for (int layer = 0; layer < NLAYERS; layer++) {
    hipMemsetAsync(Y, 0, (size_t)BB * KP * NN * sizeof(float), stream);
    rownorm_kernel<<<dim3(KROWS, BB), 256, 0, stream>>>(Zcur, mask, msum, Y);
    n2_kernel<<<BB * NN / 256, 256, 0, stream>>>(Y, n2b);
    gram_kernel<<<dim3(16, 16, BB), 256, 0, stream>>>(Y, n2b, mask, distbuf, sigp);
    sigfinal_kernel<<<BB, 256, 0, stream>>>(sigp, msum, fbuf);
    exp2_kernel<<<dim3(NN, BB), 256, 0, stream>>>(distbuf, mask, fbuf, Whb, Wlb, wsb);

    const float* Wi = W + (size_t)layer * 3 * CH * CH;
    const float* Ki = Knet + layer * 3;

    // Ai = K0*cv(W0,Z) + mm1(K1*cv(W1,Z) + mm1(K2*cv(W2,Z)))
    cv_kernel<0, 0, 1><<<gcv, 256, 0, stream>>>(Wi + 2 * CH * CH, Zcur, nullptr, nullptr, mask, Ki + 2, U, Xh, Xl);
    mm1_mfma_kernel<<<gmm, 256, 0, stream>>>(Xh, Xl, Whb, Wlb, U, wsb, V);
    cv_kernel<0, 1, 1><<<gcv, 256, 0, stream>>>(Wi + 1 * CH * CH, Zcur, V, nullptr, mask, Ki + 1, U, Xh, Xl);
    mm1_mfma_kernel<<<gmm, 256, 0, stream>>>(Xh, Xl, Whb, Wlb, U, wsb, V);
    cv_kernel<0, 1, 0><<<gcv, 256, 0, stream>>>(Wi, Zcur, V, nullptr, mask, Ki, U, nullptr, nullptr);

    centerA_kernel<<<dim3(CH, BB), 256, 0, stream>>>(U, mask, msum);
    colnorm_kernel<<<BB * NN / 256, 256, 0, stream>>>(U);

    // Z -= h * (K0*cvT(W0,A) + mm1(K1*cvT(W1,A) + mm1(K2*cvT(W2,A))))
    cv_kernel<1, 0, 1><<<gcv, 256, 0, stream>>>(Wi + 2 * CH * CH, U, nullptr, nullptr, mask, Ki + 2, V, Xh, Xl);
    mm1_mfma_kernel<<<gmm, 256, 0, stream>>>(Xh, Xl, Whb, Wlb, V, wsb, Xb);
    cv_kernel<1, 1, 1><<<gcv, 256, 0, stream>>>(Wi + 1 * CH * CH, U, Xb, nullptr, mask, Ki + 1, V, Xh, Xl);
    mm1_mfma_kernel<<<gmm, 256, 0, stream>>>(Xh, Xl, Whb, Wlb, V, wsb, Xb);
    cv_kernel<1, 2, 0><<<gcv, 256, 0, stream>>>(Wi, U, Xb, Zcur, mask, Ki, Zcur, nullptr, nullptr);
  }

  zout_kernel<<<BB, 256, 0, stream>>>(Zcur, Wend, mask, outZ, Zcent);
  dist_kernel<<<dim3(NN / 256, NN, BB), 256, 0, stream>>>(Zcent, out);
}

// Round 3
// 2919.320 us; speedup vs baseline: 1.9662x; 1.3181x over previous
//
#include <hip/hip_runtime.h>
#include <math.h>

#define BB 16
#define CIN 40
#define CH 256
#define NN 1024
#define KROWS 257
#define KP 272
#define KPAD 288        // gram K padded to 9*32
#define NLAYERS 6

typedef __attribute__((ext_vector_type(8))) short bh8;
typedef __attribute__((ext_vector_type(4))) float f4;

__device__ __forceinline__ unsigned short bf16_rne(float x) {
  unsigned int u = __float_as_uint(x);
  u += 0x7fffu + ((u >> 16) & 1u);
  return (unsigned short)(u >> 16);
}
__device__ __forceinline__ float bf16_f(unsigned short h) {
  return __uint_as_float(((unsigned int)h) << 16);
}

#define GLD16(gp, lp) __builtin_amdgcn_global_load_lds( \
    (const __attribute__((address_space(1))) void*)(gp), \
    (__attribute__((address_space(3))) void*)(lp), 16, 0, 0)

// ---------- block reduction (256 threads = 4 waves) ----------
__device__ __forceinline__ float blockReduceSum(float v) {
  __shared__ float sred[4];
  const int lane = threadIdx.x & 63;
  const int wid  = threadIdx.x >> 6;
  #pragma unroll
  for (int off = 32; off > 0; off >>= 1) v += __shfl_down(v, off, 64);
  __syncthreads();
  if (lane == 0) sred[wid] = v;
  __syncthreads();
  return sred[0] + sred[1] + sred[2] + sred[3];
}

// ---------- shared split-bf16 GEMM core: 128x64 tile, BK=32, 3-product ----------
// A rows = output rows (128), B rows = output cols (64), k contiguous in both.
__device__ __forceinline__ void gemm_bf16_core(
    const unsigned short* __restrict__ Ah, const unsigned short* __restrict__ Al,
    const int strideA,
    const unsigned short* __restrict__ Bh, const unsigned short* __restrict__ Bl,
    const int strideB, const int K, unsigned short* lds, f4 acc[4][2]) {
  const int tid = threadIdx.x;
  const int lane = tid & 63;
  const int wid = tid >> 6;
  const int srow = lane >> 2;
  const int q = lane & 3;
  const int sl = q ^ ((srow >> 1) & 3);
  const int frow = lane & 15;
  const int h = lane >> 4;
  const int slot8 = (h ^ ((frow >> 1) & 3)) << 3;
  const int wr = wid >> 1, wc = wid & 1;
  unsigned short* sAh = lds;
  unsigned short* sAl = lds + 4096;
  unsigned short* sBh = lds + 8192;
  unsigned short* sBl = lds + 10240;
  for (int kt = 0; kt < K; kt += 32) {
    #pragma unroll
    for (int cc = 0; cc < 6; cc++) {
      const int c = wid * 6 + cc;
      const unsigned short* src;
      unsigned short* dst;
      if (c < 8)       { src = Ah + (size_t)(c * 16 + srow) * strideA + kt + sl * 8;        dst = sAh + c * 512; }
      else if (c < 16) { src = Al + (size_t)((c - 8) * 16 + srow) * strideA + kt + sl * 8;  dst = sAl + (c - 8) * 512; }
      else if (c < 20) { src = Bh + (size_t)((c - 16) * 16 + srow) * strideB + kt + sl * 8; dst = sBh + (c - 16) * 512; }
      else             { src = Bl + (size_t)((c - 20) * 16 + srow) * strideB + kt + sl * 8; dst = sBl + (c - 20) * 512; }
      GLD16(src, dst + lane * 8);
    }
    __syncthreads();
    bh8 a_h[4], a_l[4], b_h[2], b_l[2];
    #pragma unroll
    for (int mi = 0; mi < 4; mi++) {
      const int off = (wr * 64 + mi * 16 + frow) * 32 + slot8;
      a_h[mi] = *(const bh8*)&sAh[off];
      a_l[mi] = *(const bh8*)&sAl[off];
    }
    #pragma unroll
    for (int ni = 0; ni < 2; ni++) {
      const int off = (wc * 32 + ni * 16 + frow) * 32 + slot8;
      b_h[ni] = *(const bh8*)&sBh[off];
      b_l[ni] = *(const bh8*)&sBl[off];
    }
    #pragma unroll
    for (int mi = 0; mi < 4; mi++)
      #pragma unroll
      for (int ni = 0; ni < 2; ni++) {
        acc[mi][ni] = __builtin_amdgcn_mfma_f32_16x16x32_bf16(a_h[mi], b_h[ni], acc[mi][ni], 0, 0, 0);
        acc[mi][ni] = __builtin_amdgcn_mfma_f32_16x16x32_bf16(a_h[mi], b_l[ni], acc[mi][ni], 0, 0, 0);
        acc[mi][ni] = __builtin_amdgcn_mfma_f32_16x16x32_bf16(a_l[mi], b_h[ni], acc[mi][ni], 0, 0, 0);
      }
    __syncthreads();
  }
}

// ---------- Z0 = tanh(K0 @ Zin) * mask ----------
__global__ void k0_kernel(const float* __restrict__ Zin, const float* __restrict__ K0,
                          const float* __restrict__ mask, float* __restrict__ Zc) {
  const int b = blockIdx.y;
  const int o = blockIdx.x;
  __shared__ float w[CIN];
  if (threadIdx.x < CIN) w[threadIdx.x] = K0[o * CIN + threadIdx.x];
  __syncthreads();
  for (int n = threadIdx.x; n < NN; n += 256) {
    float acc = 0.f;
    #pragma unroll
    for (int c = 0; c < CIN; c++) acc += w[c] * Zin[((size_t)b * CIN + c) * NN + n];
    Zc[((size_t)b * CH + o) * NN + n] = tanhf(acc) * mask[b * NN + n];
  }
}

__global__ void masksum_kernel(const float* __restrict__ mask, float* __restrict__ msum) {
  const int b = blockIdx.x;
  float v = 0.f;
  for (int n = threadIdx.x; n < NN; n += 256) v += mask[b * NN + n];
  v = blockReduceSum(v);
  if (threadIdx.x == 0) msum[b] = v;
}

// ---------- W prep: split-bf16 of W and W^T for all 18 matrices ----------
__global__ void wprep_kernel(const float* __restrict__ W, unsigned short* __restrict__ Wmh,
                             unsigned short* __restrict__ Wml, unsigned short* __restrict__ Wth,
                             unsigned short* __restrict__ Wtl) {
  __shared__ float t[64][65];
  const int mat = blockIdx.y;
  const int ty = blockIdx.x >> 2, tx = blockIdx.x & 3;
  const float* src = W + (size_t)mat * CH * CH;
  const int tid = threadIdx.x;
  const int lr = tid >> 2;
  const int lc = (tid & 3) * 16;
  float v[16];
  #pragma unroll
  for (int j = 0; j < 16; j += 4)
    *(float4*)&v[j] = *(const float4*)&src[(size_t)(ty * 64 + lr) * CH + tx * 64 + lc + j];
  unsigned short hv[16], lv[16];
  #pragma unroll
  for (int j = 0; j < 16; j++) {
    hv[j] = bf16_rne(v[j]); lv[j] = bf16_rne(v[j] - bf16_f(hv[j]));
    t[lr][lc + j] = v[j];
  }
  const size_t offm = (size_t)mat * CH * CH + (size_t)(ty * 64 + lr) * CH + tx * 64 + lc;
  #pragma unroll
  for (int j = 0; j < 16; j += 4) {
    *(ushort4*)&Wmh[offm + j] = *(ushort4*)&hv[j];
    *(ushort4*)&Wml[offm + j] = *(ushort4*)&lv[j];
  }
  __syncthreads();
  #pragma unroll
  for (int j = 0; j < 16; j++) {
    const float w = t[lc + j][lr];
    hv[j] = bf16_rne(w); lv[j] = bf16_rne(w - bf16_f(hv[j]));
  }
  const size_t offt = (size_t)mat * CH * CH + (size_t)(tx * 64 + lr) * CH + ty * 64 + lc;
  #pragma unroll
  for (int j = 0; j < 16; j += 4) {
    *(ushort4*)&Wth[offt + j] = *(ushort4*)&hv[j];
    *(ushort4*)&Wtl[offt + j] = *(ushort4*)&lv[j];
  }
}

// ---------- per-row masked center + normalize, then plain center; writes Y ----------
__global__ void rownorm_kernel(const float* __restrict__ Z, const float* __restrict__ mask,
                               const float* __restrict__ msum, float* __restrict__ Y) {
  const int b = blockIdx.y;
  const int c = blockIdx.x;
  const int t = threadIdx.x;
  const float* mrow = mask + b * NN;
  float x[4];
  if (c < CH) {
    const float* row = Z + ((size_t)b * CH + c) * NN;
    float mv[4];
    float s = 0.f;
    #pragma unroll
    for (int j = 0; j < 4; j++) { int n = t + j * 256; x[j] = row[n]; mv[j] = mrow[n]; s += x[j] * mv[j]; }
    s = blockReduceSum(s);
    const float mean = s / msum[b];
    float q = 0.f;
    #pragma unroll
    for (int j = 0; j < 4; j++) { x[j] -= mean * mv[j]; q += x[j] * x[j]; }
    q = blockReduceSum(q);
    const float rs = 1.0f / sqrtf(q / msum[b] + 1e-4f);
    #pragma unroll
    for (int j = 0; j < 4; j++) x[j] *= rs;
  } else {
    #pragma unroll
    for (int j = 0; j < 4; j++) { int n = t + j * 256; x[j] = 0.5f * ((float)n * (1.0f / (NN - 1))) * mrow[n]; }
  }
  float s2 = 0.f;
  #pragma unroll
  for (int j = 0; j < 4; j++) s2 += x[j];
  s2 = blockReduceSum(s2);
  const float pm = s2 * (1.0f / NN);
  float* yrow = Y + ((size_t)b * KP + c) * NN;
  #pragma unroll
  for (int j = 0; j < 4; j++) yrow[t + j * 256] = x[j] - pm;
}

// ---------- n2[b,n] = sum_k Y[b,k,n]^2 ----------
__global__ void n2_kernel(const float* __restrict__ Y, float* __restrict__ n2) {
  const int idx = blockIdx.x * 256 + threadIdx.x;
  const int b = idx >> 10, n = idx & 1023;
  const float* yb = Y + (size_t)b * KP * NN + n;
  float s = 0.f;
  for (int k = 0; k < KROWS; k++) { float v = yb[(size_t)k * NN]; s += v * v; }
  n2[idx] = s;
}

// ---------- transpose+split: in fp32 [M][NN] -> Th/Tl bf16 [NN][Kpad] ----------
__global__ void tsplit_kernel(const float* __restrict__ in, const int inBatch, const int Mvalid,
                              unsigned short* __restrict__ Th, unsigned short* __restrict__ Tl,
                              const int Kpad) {
  __shared__ float t[32][65];
  const int b = blockIdx.z;
  const int n0 = blockIdx.x * 64;
  const int k0 = blockIdx.y * 32;
  const float* src = in + (size_t)b * inBatch;
  const int tid = threadIdx.x;
  const int lr = tid >> 3;
  const int lc = (tid & 7) * 8;
  const int gk = k0 + lr;
  if (gk < Mvalid) {
    *(float4*)&t[lr][lc]     = *(const float4*)&src[(size_t)gk * NN + n0 + lc];
    *(float4*)&t[lr][lc + 4] = *(const float4*)&src[(size_t)gk * NN + n0 + lc + 4];
  } else {
    const float4 z4 = {0.f, 0.f, 0.f, 0.f};
    *(float4*)&t[lr][lc] = z4; *(float4*)&t[lr][lc + 4] = z4;
  }
  __syncthreads();
  const int on = tid >> 2;
  const int ok = (tid & 3) * 8;
  unsigned short hv[8], lv[8];
  #pragma unroll
  for (int j = 0; j < 8; j++) {
    const float v = t[ok + j][on];
    hv[j] = bf16_rne(v); lv[j] = bf16_rne(v - bf16_f(hv[j]));
  }
  const size_t off = ((size_t)b * NN + n0 + on) * Kpad + k0 + ok;
  *(ushort4*)&Th[off] = *(ushort4*)&hv[0];
  *(ushort4*)&Th[off + 4] = *(ushort4*)&hv[4];
  *(ushort4*)&Tl[off] = *(ushort4*)&lv[0];
  *(ushort4*)&Tl[off + 4] = *(ushort4*)&lv[4];
}

// ---------- gram via MFMA: D=scale*(n2i+n2j-2*YtYt^T); write dist splits ----------
__launch_bounds__(256, 2)
__global__ void gram_mfma_kernel(const unsigned short* __restrict__ Yth,
                                 const unsigned short* __restrict__ Ytl,
                                 const float* __restrict__ n2, const float* __restrict__ mask,
                                 unsigned short* __restrict__ Dh, unsigned short* __restrict__ Dl,
                                 float* __restrict__ sigpart) {
  __shared__ unsigned short lds[12288];
  const int b = blockIdx.z;
  const int i0 = blockIdx.y * 128;
  const int j0 = blockIdx.x * 64;
  const unsigned short* Yh = Yth + (size_t)b * NN * KPAD;
  const unsigned short* Yl = Ytl + (size_t)b * NN * KPAD;
  f4 acc[4][2];
  const f4 z4 = {0.f, 0.f, 0.f, 0.f};
  #pragma unroll
  for (int mi = 0; mi < 4; mi++) { acc[mi][0] = z4; acc[mi][1] = z4; }
  gemm_bf16_core(Yh + (size_t)i0 * KPAD, Yl + (size_t)i0 * KPAD, KPAD,
                 Yh + (size_t)j0 * KPAD, Yl + (size_t)j0 * KPAD, KPAD, KPAD, lds, acc);
  const int tid = threadIdx.x;
  const int lane = tid & 63;
  const int wid = tid >> 6;
  const int wr = wid >> 1, wc = wid & 1;
  const int frow = lane & 15, hh = lane >> 4;
  const float scale = 3.0f / 257.0f;
  float lsum = 0.f;
  #pragma unroll
  for (int ni = 0; ni < 2; ni++) {
    const int j = j0 + wc * 32 + ni * 16 + frow;
    const float n2j = n2[b * NN + j];
    const float mkj = mask[b * NN + j];
    #pragma unroll
    for (int mi = 0; mi < 4; mi++) {
      #pragma unroll
      for (int r = 0; r < 4; r++) {
        const int i = i0 + wr * 64 + mi * 16 + hh * 4 + r;
        const float D = scale * (n2[b * NN + i] + n2j - 2.0f * acc[mi][ni][r]);
        const float d = sqrtf(fmaxf(D, 1e-12f));
        const float mmv = mask[b * NN + i] * mkj;
        const float wd = d * mmv;
        const size_t off = ((size_t)b * NN + i) * NN + j;
        const unsigned short dh = bf16_rne(wd);
        Dh[off] = dh;
        Dl[off] = bf16_rne(wd - bf16_f(dh));
        lsum += wd * mmv;
      }
    }
  }
  lsum = blockReduceSum(lsum);
  if (tid == 0) sigpart[b * 128 + blockIdx.y * 16 + blockIdx.x] = lsum;
}

// ---------- finalize sigma -> fb = -10*msum^2/signum ----------
__global__ void sigfinal_kernel(const float* __restrict__ sigpart, const float* __restrict__ msum,
                                float* __restrict__ fbuf) {
  const int b = blockIdx.x;
  float v = (threadIdx.x < 128) ? sigpart[b * 128 + threadIdx.x] : 0.f;
  v = blockReduceSum(v);
  if (threadIdx.x == 0) { const float ms = msum[b]; fbuf[b] = -10.0f * ms * ms / v; }
}

// ---------- exp in-place on split pairs; wsum from reconstructed values ----------
__global__ void exp2_kernel(unsigned short* __restrict__ Wh, unsigned short* __restrict__ Wl,
                            const float* __restrict__ mask, const float* __restrict__ fbuf,
                            float* __restrict__ wsum) {
  const int b = blockIdx.y, n = blockIdx.x;
  const float fb = fbuf[b];
  const float mn = mask[b * NN + n];
  const size_t roff = ((size_t)b * NN + n) * NN;
  const float4 mk = ((const float4*)(mask + b * NN))[threadIdx.x];
  ushort4 dh = *(ushort4*)&Wh[roff + threadIdx.x * 4];
  ushort4 dl = *(ushort4*)&Wl[roff + threadIdx.x * 4];
  float w0 = expf(fb * (bf16_f(dh.x) + bf16_f(dl.x))) * mn * mk.x;
  float w1 = expf(fb * (bf16_f(dh.y) + bf16_f(dl.y))) * mn * mk.y;
  float w2 = expf(fb * (bf16_f(dh.z) + bf16_f(dl.z))) * mn * mk.z;
  float w3 = expf(fb * (bf16_f(dh.w) + bf16_f(dl.w))) * mn * mk.w;
  ushort4 h4, l4;
  h4.x = bf16_rne(w0); l4.x = bf16_rne(w0 - bf16_f(h4.x));
  h4.y = bf16_rne(w1); l4.y = bf16_rne(w1 - bf16_f(h4.y));
  h4.z = bf16_rne(w2); l4.z = bf16_rne(w2 - bf16_f(h4.z));
  h4.w = bf16_rne(w3); l4.w = bf16_rne(w3 - bf16_f(h4.w));
  *(ushort4*)&Wh[roff + threadIdx.x * 4] = h4;
  *(ushort4*)&Wl[roff + threadIdx.x * 4] = l4;
  // sum the reconstructed (hi+lo) values so diag cancellation in mm1 is tight
  float s = (bf16_f(h4.x) + bf16_f(l4.x)) + (bf16_f(h4.y) + bf16_f(l4.y)) +
            (bf16_f(h4.z) + bf16_f(l4.z)) + (bf16_f(h4.w) + bf16_f(l4.w));
  s = blockReduceSum(s);
  if (threadIdx.x == 0) wsum[b * NN + n] = s;
}

// ---------- cv via MFMA: out = alpha*(Wm@X)*mask [+add] [zin-0.01*(...)] ----------
// MODE 0: v; MODE 1: v+add; MODE 2: zin-0.01*(v+add). CONV: write splits of out.
template <int MODE, int CONV>
__launch_bounds__(256, 2)
__global__ void cv_mfma_kernel(const unsigned short* __restrict__ Wmh,
                               const unsigned short* __restrict__ Wml,
                               const unsigned short* __restrict__ Bth,
                               const unsigned short* __restrict__ Btl,
                               const float* __restrict__ add, const float* __restrict__ zin,
                               const float* __restrict__ mask, const float* __restrict__ alphap,
                               float* __restrict__ out, unsigned short* __restrict__ Gh,
                               unsigned short* __restrict__ Gl) {
  __shared__ unsigned short lds[12288];
  const int b = blockIdx.z;
  const int r0 = blockIdx.y * 128;
  const int n0 = blockIdx.x * 64;
  f4 acc[4][2];
  const f4 z4 = {0.f, 0.f, 0.f, 0.f};
  #pragma unroll
  for (int mi = 0; mi < 4; mi++) { acc[mi][0] = z4; acc[mi][1] = z4; }
  gemm_bf16_core(Wmh + (size_t)r0 * CH, Wml + (size_t)r0 * CH, CH,
                 Bth + ((size_t)b * NN + n0) * CH, Btl + ((size_t)b * NN + n0) * CH, CH,
                 CH, lds, acc);
  const int tid = threadIdx.x;
  const int lane = tid & 63;
  const int wid = tid >> 6;
  const int wr = wid >> 1, wc = wid & 1;
  const int frow = lane & 15, hh = lane >> 4;
  const float alpha = alphap[0];
  #pragma unroll
  for (int ni = 0; ni < 2; ni++) {
    const int col = n0 + wc * 32 + ni * 16 + frow;
    const float mk = mask[b * NN + col];
    #pragma unroll
    for (int mi = 0; mi < 4; mi++) {
      #pragma unroll
      for (int r = 0; r < 4; r++) {
        const int row = r0 + wr * 64 + mi * 16 + hh * 4 + r;
        const size_t off = ((size_t)b * CH + row) * NN + col;
        float v = alpha * acc[mi][ni][r] * mk;
        if (MODE >= 1) v += add[off];
        float o_;
        if (MODE == 2) o_ = zin[off] - 0.01f * v;
        else o_ = v;
        out[off] = o_;
        if (CONV) {
          const unsigned short oh = bf16_rne(o_);
          Gh[off] = oh;
          Gl[off] = bf16_rne(o_ - bf16_f(oh));
        }
      }
    }
  }
}

// ---------- mm1 via split-bf16 MFMA: out = X*wsum(col) - X @ W ----------
__launch_bounds__(256, 2)
__global__ void mm1_mfma_kernel(const unsigned short* __restrict__ Xh,
                                const unsigned short* __restrict__ Xl,
                                const unsigned short* __restrict__ Wh,
                                const unsigned short* __restrict__ Wl,
                                const float* __restrict__ Xf, const float* __restrict__ wsum,
                                float* __restrict__ outp) {
  __shared__ unsigned short lds[12288];
  const int b = blockIdx.z;
  const int r0 = blockIdx.y * 128;
  const int n0 = blockIdx.x * 64;
  const size_t XB = (size_t)b * CH * NN;
  const size_t WB = (size_t)b * NN * NN;
  f4 acc[4][2];
  const f4 z4 = {0.f, 0.f, 0.f, 0.f};
  #pragma unroll
  for (int mi = 0; mi < 4; mi++) { acc[mi][0] = z4; acc[mi][1] = z4; }
  gemm_bf16_core(Xh + XB + (size_t)r0 * NN, Xl + XB + (size_t)r0 * NN, NN,
                 Wh + WB + (size_t)n0 * NN, Wl + WB + (size_t)n0 * NN, NN,
                 NN, lds, acc);
  const int tid = threadIdx.x;
  const int lane = tid & 63;
  const int wid = tid >> 6;
  const int wr = wid >> 1, wc = wid & 1;
  const int frow = lane & 15, hh = lane >> 4;
  #pragma unroll
  for (int ni = 0; ni < 2; ni++) {
    const int col = n0 + wc * 32 + ni * 16 + frow;
    const float ws = wsum[b * NN + col];
    #pragma unroll
    for (int mi = 0; mi < 4; mi++) {
      #pragma unroll
      for (int r = 0; r < 4; r++) {
        const int row = r0 + wr * 64 + mi * 16 + hh * 4 + r;
        const size_t off = XB + (size_t)row * NN + col;
        outp[off] = Xf[off] * ws - acc[mi][ni][r];
      }
    }
  }
}

// ---------- A = (A - masked_mean(A))*mask ----------
__global__ void centerA_kernel(float* __restrict__ A, const float* __restrict__ mask,
                               const float* __restrict__ msum) {
  const int b = blockIdx.y, c = blockIdx.x;
  float* row = A + ((size_t)b * CH + c) * NN;
  const float* mrow = mask + b * NN;
  const int t = threadIdx.x;
  float x[4], mv[4];
  float s = 0.f;
  #pragma unroll
  for (int j = 0; j < 4; j++) { int n = t + j * 256; x[j] = row[n]; mv[j] = mrow[n]; s += x[j] * mv[j]; }
  s = blockReduceSum(s);
  const float mean = s / msum[b];
  #pragma unroll
  for (int j = 0; j < 4; j++) row[t + j * 256] = (x[j] - mean) * mv[j];
}

// ---------- A = relu(A / sqrt(sum_c A^2 + 0.001)) ----------
__global__ void colnorm_kernel(float* __restrict__ A) {
  const int idx = blockIdx.x * 256 + threadIdx.x;
  const int b = idx >> 10, n = idx & 1023;
  float* col = A + (size_t)b * CH * NN + n;
  float s = 0.001f;
  for (int c = 0; c < CH; c++) { float v = col[(size_t)c * NN]; s += v * v; }
  const float rs = 1.0f / sqrtf(s);
  for (int c = 0; c < CH; c++) {
    float v = col[(size_t)c * NN] * rs;
    col[(size_t)c * NN] = v > 0.f ? v : 0.f;
  }
}

// ---------- Zout = (Wend @ Z)*mask; write + centered copy ----------
__global__ void zout_kernel(const float* __restrict__ Z, const float* __restrict__ Wend,
                            const float* __restrict__ mask, float* __restrict__ outZ,
                            float* __restrict__ Zcent) {
  const int b = blockIdx.x;
  __shared__ float w[3 * CH];
  for (int i = threadIdx.x; i < 3 * CH; i += 256) w[i] = Wend[i];
  __syncthreads();
  float a[3][4];
  #pragma unroll
  for (int j = 0; j < 4; j++) { a[0][j] = 0.f; a[1][j] = 0.f; a[2][j] = 0.f; }
  const float* Zb = Z + (size_t)b * CH * NN;
  for (int c = 0; c < CH; c++) {
    const float w0 = w[c], w1 = w[CH + c], w2 = w[2 * CH + c];
    #pragma unroll
    for (int j = 0; j < 4; j++) {
      float zv = Zb[(size_t)c * NN + threadIdx.x + j * 256];
      a[0][j] += w0 * zv; a[1][j] += w1 * zv; a[2][j] += w2 * zv;
    }
  }
  float sum[3] = {0.f, 0.f, 0.f};
  #pragma unroll
  for (int j = 0; j < 4; j++) {
    const int n = threadIdx.x + j * 256;
    const float mv = mask[b * NN + n];
    #pragma unroll
    for (int o = 0; o < 3; o++) {
      a[o][j] *= mv;
      outZ[((size_t)b * 3 + o) * NN + n] = a[o][j];
      sum[o] += a[o][j];
    }
  }
  for (int o = 0; o < 3; o++) {
    float s = blockReduceSum(sum[o]);
    const float mean = s * (1.0f / NN);
    #pragma unroll
    for (int j = 0; j < 4; j++) {
      const int n = threadIdx.x + j * 256;
      Zcent[((size_t)b * 3 + o) * NN + n] = a[o][j] - mean;
    }
  }
}

// ---------- final distances ----------
__global__ void dist_kernel(const float* __restrict__ Zcent, float* __restrict__ outD) {
  const int b = blockIdx.z;
  const int n = blockIdx.y;
  const int m = blockIdx.x * 256 + threadIdx.x;
  const float* Zb = Zcent + (size_t)b * 3 * NN;
  const float x0 = Zb[n], x1 = Zb[NN + n], x2 = Zb[2 * NN + n];
  const float d0 = x0 - Zb[m], d1 = x1 - Zb[NN + m], d2 = x2 - Zb[2 * NN + m];
  const float D = d0 * d0 + d1 * d1 + d2 * d2;
  outD[((size_t)b * NN + n) * NN + m] = sqrtf(fmaxf(D, 1e-12f));
}

extern "C" void kernel_launch(void* const* d_in, const int* in_sizes, int n_in,
                              void* d_out, int out_size, void* d_ws, size_t ws_size,
                              hipStream_t stream) {
  const float* Zin  = (const float*)d_in[0];
  const float* mask = (const float*)d_in[1];
  const float* K0   = (const float*)d_in[2];
  const float* Knet = (const float*)d_in[3];
  const float* W    = (const float*)d_in[4];
  const float* Wend = (const float*)d_in[5];
  float* out = (float*)d_out;

  // d_out scratch: dist region holds Wh/Wl bf16 split pair (64 MB) until the end.
  unsigned short* Whb = (unsigned short*)out;                    // BB*NN*NN
  unsigned short* Wlb = Whb + (size_t)BB * NN * NN;              // BB*NN*NN
  float* outZ = out + (size_t)BB * NN * NN;

  float* p = (float*)d_ws;
  float* Y    = p; p += (size_t)BB * KP * NN;     // fp32, rows 0..256 used; aliases Xb
  float* Zcur = p; p += (size_t)BB * CH * NN;
  float* U    = p; p += (size_t)BB * CH * NN;
  float* V    = p; p += (size_t)BB * CH * NN;
  unsigned short* Yth = (unsigned short*)p; p += (size_t)BB * NN * KPAD / 2;  // bf16
  unsigned short* Ytl = (unsigned short*)p; p += (size_t)BB * NN * KPAD / 2;
  unsigned short* Zth = (unsigned short*)p; p += (size_t)BB * NN * CH / 2;
  unsigned short* Ztl = (unsigned short*)p; p += (size_t)BB * NN * CH / 2;
  unsigned short* Wmh = (unsigned short*)p; p += (size_t)18 * CH * CH / 2;
  unsigned short* Wml = (unsigned short*)p; p += (size_t)18 * CH * CH / 2;
  unsigned short* Wth = (unsigned short*)p; p += (size_t)18 * CH * CH / 2;
  unsigned short* Wtl = (unsigned short*)p; p += (size_t)18 * CH * CH / 2;
  float* n2b  = p; p += BB * NN;
  float* wsb  = p; p += BB * NN;
  float* msum = p; p += BB;
  float* sigp = p; p += BB * 128;
  float* fbuf = p; p += BB;
  float* Zcent= p; p += BB * 3 * NN;
  float* Xb = Y;                                   // alias: Y free after gram
  // G splits (mm1 inputs) alias the Yt region (dead after gram each layer)
  unsigned short* Gh = Yth;
  unsigned short* Gl = Yth + (size_t)BB * CH * NN;

  const dim3 gcv(NN / 64, CH / 128, BB);           // cv + mm1 grid
  const dim3 ggram(NN / 64, NN / 128, BB);
  const dim3 gtsZ(NN / 64, CH / 32, BB);
  const dim3 gtsY(NN / 64, KPAD / 32, BB);

  masksum_kernel<<<BB, 256, 0, stream>>>(mask, msum);
  wprep_kernel<<<dim3(16, 18), 256, 0, stream>>>(W, Wmh, Wml, Wth, Wtl);
  k0_kernel<<<dim3(CH, BB), 256, 0, stream>>>(Zin, K0, mask, Zcur);

  for (int layer = 0; layer < NLAYERS; layer++) {
    rownorm_kernel<<<dim3(KROWS, BB), 256, 0, stream>>>(Zcur, mask, msum, Y);
    n2_kernel<<<BB * NN / 256, 256, 0, stream>>>(Y, n2b);
    tsplit_kernel<<<gtsY, 256, 0, stream>>>(Y, KP * NN, KROWS, Yth, Ytl, KPAD);
    gram_mfma_kernel<<<ggram, 256, 0, stream>>>(Yth, Ytl, n2b, mask, Whb, Wlb, sigp);
    sigfinal_kernel<<<BB, 256, 0, stream>>>(sigp, msum, fbuf);
    exp2_kernel<<<dim3(NN, BB), 256, 0, stream>>>(Whb, Wlb, mask, fbuf, wsb);
    tsplit_kernel<<<gtsZ, 256, 0, stream>>>(Zcur, CH * NN, CH, Zth, Ztl, CH);

    const unsigned short* m2h = Wmh + (size_t)(layer * 3 + 2) * CH * CH;
    const unsigned short* m2l = Wml + (size_t)(layer * 3 + 2) * CH * CH;
    const unsigned short* m1h = Wmh + (size_t)(layer * 3 + 1) * CH * CH;
    const unsigned short* m1l = Wml + (size_t)(layer * 3 + 1) * CH * CH;
    const unsigned short* m0h = Wmh + (size_t)(layer * 3 + 0) * CH * CH;
    const unsigned short* m0l = Wml + (size_t)(layer * 3 + 0) * CH * CH;
    const unsigned short* t2h = Wth + (size_t)(layer * 3 + 2) * CH * CH;
    const unsigned short* t2l = Wtl + (size_t)(layer * 3 + 2) * CH * CH;
    const unsigned short* t1h = Wth + (size_t)(layer * 3 + 1) * CH * CH;
    const unsigned short* t1l = Wtl + (size_t)(layer * 3 + 1) * CH * CH;
    const unsigned short* t0h = Wth + (size_t)(layer * 3 + 0) * CH * CH;
    const unsigned short* t0l = Wtl + (size_t)(layer * 3 + 0) * CH * CH;
    const float* Ki = Knet + layer * 3;

    // Ai = K0*cv(W0,Z) + mm1(K1*cv(W1,Z) + mm1(K2*cv(W2,Z)))
    cv_mfma_kernel<0, 1><<<gcv, 256, 0, stream>>>(m2h, m2l, Zth, Ztl, nullptr, nullptr, mask, Ki + 2, U, Gh, Gl);
    mm1_mfma_kernel<<<gcv, 256, 0, stream>>>(Gh, Gl, Whb, Wlb, U, wsb, V);
    cv_mfma_kernel<1, 1><<<gcv, 256, 0, stream>>>(m1h, m1l, Zth, Ztl, V, nullptr, mask, Ki + 1, U, Gh, Gl);
    mm1_mfma_kernel<<<gcv, 256, 0, stream>>>(Gh, Gl, Whb, Wlb, U, wsb, V);
    cv_mfma_kernel<1, 0><<<gcv, 256, 0, stream>>>(m0h, m0l, Zth, Ztl, V, nullptr, mask, Ki, U, nullptr, nullptr);

    centerA_kernel<<<dim3(CH, BB), 256, 0, stream>>>(U, mask, msum);
    colnorm_kernel<<<BB * NN / 256, 256, 0, stream>>>(U);
    tsplit_kernel<<<gtsZ, 256, 0, stream>>>(U, CH * NN, CH, Zth, Ztl, CH);

    // Z -= h * (K0*cvT(W0,A) + mm1(K1*cvT(W1,A) + mm1(K2*cvT(W2,A))))
    cv_mfma_kernel<0, 1><<<gcv, 256, 0, stream>>>(t2h, t2l, Zth, Ztl, nullptr, nullptr, mask, Ki + 2, V, Gh, Gl);
    mm1_mfma_kernel<<<gcv, 256, 0, stream>>>(Gh, Gl, Whb, Wlb, V, wsb, Xb);
    cv_mfma_kernel<1, 1><<<gcv, 256, 0, stream>>>(t1h, t1l, Zth, Ztl, Xb, nullptr, mask, Ki + 1, V, Gh, Gl);
    mm1_mfma_kernel<<<gcv, 256, 0, stream>>>(Gh, Gl, Whb, Wlb, V, wsb, Xb);
    cv_mfma_kernel<2, 0><<<gcv, 256, 0, stream>>>(t0h, t0l, Zth, Ztl, Xb, Zcur, mask, Ki, Zcur, nullptr, nullptr);
  }

  zout_kernel<<<BB, 256, 0, stream>>>(Zcur, Wend, mask, outZ, Zcent);
  dist_kernel<<<dim3(NN / 256, NN, BB), 256, 0, stream>>>(Zcent, out);
}

// Round 4
// 2661.005 us; speedup vs baseline: 2.1571x; 1.0971x over previous
//
#include <hip/hip_runtime.h>
#include <math.h>

#define BB 16
#define CIN 40
#define CH 256
#define NN 1024
#define KROWS 257
#define KP 272
#define KPAD 288        // gram K padded to 9*32
#define NLAYERS 6

typedef unsigned short ush;
typedef __attribute__((ext_vector_type(8))) short bh8;
typedef __attribute__((ext_vector_type(4))) float f4;

__device__ __forceinline__ ush bf16_rne(float x) {
  unsigned int u = __float_as_uint(x);
  u += 0x7fffu + ((u >> 16) & 1u);
  return (ush)(u >> 16);
}
__device__ __forceinline__ float bf16_f(ush h) {
  return __uint_as_float(((unsigned int)h) << 16);
}

#define GLD16(gp, lp) __builtin_amdgcn_global_load_lds( \
    (const __attribute__((address_space(1))) void*)(gp), \
    (__attribute__((address_space(3))) void*)(lp), 16, 0, 0)

// ---------- block reduction (256 threads = 4 waves) ----------
__device__ __forceinline__ float blockReduceSum(float v) {
  __shared__ float sred[4];
  const int lane = threadIdx.x & 63;
  const int wid  = threadIdx.x >> 6;
  #pragma unroll
  for (int off = 32; off > 0; off >>= 1) v += __shfl_down(v, off, 64);
  __syncthreads();
  if (lane == 0) sred[wid] = v;
  __syncthreads();
  return sred[0] + sred[1] + sred[2] + sred[3];
}

// ================= core A: 128x128 tile, BK=32, double-buffered =================
// LDS per buf: Ah[0,4096) Al[4096,8192) Bh[8192,12288) Bl[12288,16384) (ush)
__device__ __forceinline__ void stageA(
    const ush* __restrict__ Ah, const ush* __restrict__ Al, const int sA,
    const ush* __restrict__ Bh, const ush* __restrict__ Bl, const int sB,
    const int kt, ush* buf) {
  const int lane = threadIdx.x & 63;
  const int wid = threadIdx.x >> 6;
  const int srow = lane >> 2;
  const int sl = (lane & 3) ^ ((srow >> 1) & 3);
  #pragma unroll
  for (int cc = 0; cc < 8; cc++) {
    const int c = wid * 8 + cc;
    const ush* src;
    if (c < 8)       src = Ah + (size_t)(c * 16 + srow) * sA + kt + sl * 8;
    else if (c < 16) src = Al + (size_t)((c - 8) * 16 + srow) * sA + kt + sl * 8;
    else if (c < 24) src = Bh + (size_t)((c - 16) * 16 + srow) * sB + kt + sl * 8;
    else             src = Bl + (size_t)((c - 24) * 16 + srow) * sB + kt + sl * 8;
    GLD16(src, buf + c * 512 + lane * 8);
  }
}

__device__ __forceinline__ void computeA(const ush* buf, f4 acc[4][4]) {
  const int lane = threadIdx.x & 63;
  const int wid = threadIdx.x >> 6;
  const int wr = wid >> 1, wc = wid & 1;
  const int frow = lane & 15;
  const int slot8 = (((lane >> 4) ^ ((frow >> 1) & 3)) << 3);
  bh8 ah[4], al[4], bh_[4], bl_[4];
  #pragma unroll
  for (int mi = 0; mi < 4; mi++) {
    const int off = (wr * 64 + mi * 16 + frow) * 32 + slot8;
    ah[mi] = *(const bh8*)&buf[off];
    al[mi] = *(const bh8*)&buf[4096 + off];
  }
  #pragma unroll
  for (int ni = 0; ni < 4; ni++) {
    const int off = (wc * 64 + ni * 16 + frow) * 32 + slot8;
    bh_[ni] = *(const bh8*)&buf[8192 + off];
    bl_[ni] = *(const bh8*)&buf[12288 + off];
  }
  #pragma unroll
  for (int mi = 0; mi < 4; mi++)
    #pragma unroll
    for (int ni = 0; ni < 4; ni++) {
      acc[mi][ni] = __builtin_amdgcn_mfma_f32_16x16x32_bf16(ah[mi], bh_[ni], acc[mi][ni], 0, 0, 0);
      acc[mi][ni] = __builtin_amdgcn_mfma_f32_16x16x32_bf16(ah[mi], bl_[ni], acc[mi][ni], 0, 0, 0);
      acc[mi][ni] = __builtin_amdgcn_mfma_f32_16x16x32_bf16(al[mi], bh_[ni], acc[mi][ni], 0, 0, 0);
    }
}

// ================= core B: 64x128 tile, BK=32, double-buffered =================
// LDS per buf: Ah[0,2048) Al[2048,4096) Bh[4096,8192) Bl[8192,12288) (ush)
__device__ __forceinline__ void stageB(
    const ush* __restrict__ Ah, const ush* __restrict__ Al, const int sA,
    const ush* __restrict__ Bh, const ush* __restrict__ Bl, const int sB,
    const int kt, ush* buf) {
  const int lane = threadIdx.x & 63;
  const int wid = threadIdx.x >> 6;
  const int srow = lane >> 2;
  const int sl = (lane & 3) ^ ((srow >> 1) & 3);
  #pragma unroll
  for (int cc = 0; cc < 6; cc++) {
    const int c = wid * 6 + cc;
    const ush* src;
    if (c < 4)       src = Ah + (size_t)(c * 16 + srow) * sA + kt + sl * 8;
    else if (c < 8)  src = Al + (size_t)((c - 4) * 16 + srow) * sA + kt + sl * 8;
    else if (c < 16) src = Bh + (size_t)((c - 8) * 16 + srow) * sB + kt + sl * 8;
    else             src = Bl + (size_t)((c - 16) * 16 + srow) * sB + kt + sl * 8;
    GLD16(src, buf + c * 512 + lane * 8);
  }
}

__device__ __forceinline__ void computeB(const ush* buf, f4 acc[4][2]) {
  const int lane = threadIdx.x & 63;
  const int wid = threadIdx.x >> 6;
  const int frow = lane & 15;
  const int slot8 = (((lane >> 4) ^ ((frow >> 1) & 3)) << 3);
  bh8 ah[4], al[4], bh_[2], bl_[2];
  #pragma unroll
  for (int mi = 0; mi < 4; mi++) {
    const int off = (mi * 16 + frow) * 32 + slot8;
    ah[mi] = *(const bh8*)&buf[off];
    al[mi] = *(const bh8*)&buf[2048 + off];
  }
  #pragma unroll
  for (int ni = 0; ni < 2; ni++) {
    const int off = (wid * 32 + ni * 16 + frow) * 32 + slot8;
    bh_[ni] = *(const bh8*)&buf[4096 + off];
    bl_[ni] = *(const bh8*)&buf[8192 + off];
  }
  #pragma unroll
  for (int mi = 0; mi < 4; mi++)
    #pragma unroll
    for (int ni = 0; ni < 2; ni++) {
      acc[mi][ni] = __builtin_amdgcn_mfma_f32_16x16x32_bf16(ah[mi], bh_[ni], acc[mi][ni], 0, 0, 0);
      acc[mi][ni] = __builtin_amdgcn_mfma_f32_16x16x32_bf16(ah[mi], bl_[ni], acc[mi][ni], 0, 0, 0);
      acc[mi][ni] = __builtin_amdgcn_mfma_f32_16x16x32_bf16(al[mi], bh_[ni], acc[mi][ni], 0, 0, 0);
    }
}

// ---------- Z0 = tanh(K0 @ Zin) * mask ----------
__global__ void k0_kernel(const float* __restrict__ Zin, const float* __restrict__ K0,
                          const float* __restrict__ mask, float* __restrict__ Zc) {
  const int b = blockIdx.y;
  const int o = blockIdx.x;
  __shared__ float w[CIN];
  if (threadIdx.x < CIN) w[threadIdx.x] = K0[o * CIN + threadIdx.x];
  __syncthreads();
  for (int n = threadIdx.x; n < NN; n += 256) {
    float acc = 0.f;
    #pragma unroll
    for (int c = 0; c < CIN; c++) acc += w[c] * Zin[((size_t)b * CIN + c) * NN + n];
    Zc[((size_t)b * CH + o) * NN + n] = tanhf(acc) * mask[b * NN + n];
  }
}

__global__ void masksum_kernel(const float* __restrict__ mask, float* __restrict__ msum) {
  const int b = blockIdx.x;
  float v = 0.f;
  for (int n = threadIdx.x; n < NN; n += 256) v += mask[b * NN + n];
  v = blockReduceSum(v);
  if (threadIdx.x == 0) msum[b] = v;
}

// ---------- W prep: split-bf16 of W and W^T for all 18 matrices ----------
__global__ void wprep_kernel(const float* __restrict__ W, ush* __restrict__ Wmh,
                             ush* __restrict__ Wml, ush* __restrict__ Wth,
                             ush* __restrict__ Wtl) {
  __shared__ float t[64][65];
  const int mat = blockIdx.y;
  const int ty = blockIdx.x >> 2, tx = blockIdx.x & 3;
  const float* src = W + (size_t)mat * CH * CH;
  const int tid = threadIdx.x;
  const int lr = tid >> 2;
  const int lc = (tid & 3) * 16;
  float v[16];
  #pragma unroll
  for (int j = 0; j < 16; j += 4)
    *(float4*)&v[j] = *(const float4*)&src[(size_t)(ty * 64 + lr) * CH + tx * 64 + lc + j];
  ush hv[16], lv[16];
  #pragma unroll
  for (int j = 0; j < 16; j++) {
    hv[j] = bf16_rne(v[j]); lv[j] = bf16_rne(v[j] - bf16_f(hv[j]));
    t[lr][lc + j] = v[j];
  }
  const size_t offm = (size_t)mat * CH * CH + (size_t)(ty * 64 + lr) * CH + tx * 64 + lc;
  #pragma unroll
  for (int j = 0; j < 16; j += 4) {
    *(ushort4*)&Wmh[offm + j] = *(ushort4*)&hv[j];
    *(ushort4*)&Wml[offm + j] = *(ushort4*)&lv[j];
  }
  __syncthreads();
  #pragma unroll
  for (int j = 0; j < 16; j++) {
    const float w = t[lc + j][lr];
    hv[j] = bf16_rne(w); lv[j] = bf16_rne(w - bf16_f(hv[j]));
  }
  const size_t offt = (size_t)mat * CH * CH + (size_t)(tx * 64 + lr) * CH + ty * 64 + lc;
  #pragma unroll
  for (int j = 0; j < 16; j += 4) {
    *(ushort4*)&Wth[offt + j] = *(ushort4*)&hv[j];
    *(ushort4*)&Wtl[offt + j] = *(ushort4*)&lv[j];
  }
}

// ---------- per-row masked center + normalize, then plain center; writes Y ----------
__global__ void rownorm_kernel(const float* __restrict__ Z, const float* __restrict__ mask,
                               const float* __restrict__ msum, float* __restrict__ Y) {
  const int b = blockIdx.y;
  const int c = blockIdx.x;
  const int t = threadIdx.x;
  const float* mrow = mask + b * NN;
  float x[4];
  if (c < CH) {
    const float* row = Z + ((size_t)b * CH + c) * NN;
    float mv[4];
    float s = 0.f;
    #pragma unroll
    for (int j = 0; j < 4; j++) { int n = t + j * 256; x[j] = row[n]; mv[j] = mrow[n]; s += x[j] * mv[j]; }
    s = blockReduceSum(s);
    const float mean = s / msum[b];
    float q = 0.f;
    #pragma unroll
    for (int j = 0; j < 4; j++) { x[j] -= mean * mv[j]; q += x[j] * x[j]; }
    q = blockReduceSum(q);
    const float rs = 1.0f / sqrtf(q / msum[b] + 1e-4f);
    #pragma unroll
    for (int j = 0; j < 4; j++) x[j] *= rs;
  } else {
    #pragma unroll
    for (int j = 0; j < 4; j++) { int n = t + j * 256; x[j] = 0.5f * ((float)n * (1.0f / (NN - 1))) * mrow[n]; }
  }
  float s2 = 0.f;
  #pragma unroll
  for (int j = 0; j < 4; j++) s2 += x[j];
  s2 = blockReduceSum(s2);
  const float pm = s2 * (1.0f / NN);
  float* yrow = Y + ((size_t)b * KP + c) * NN;
  #pragma unroll
  for (int j = 0; j < 4; j++) yrow[t + j * 256] = x[j] - pm;
}

// ---------- n2[b,n] = sum_k Y[b,k,n]^2 ----------
__global__ void n2_kernel(const float* __restrict__ Y, float* __restrict__ n2) {
  const int idx = blockIdx.x * 256 + threadIdx.x;
  const int b = idx >> 10, n = idx & 1023;
  const float* yb = Y + (size_t)b * KP * NN + n;
  float s = 0.f;
  for (int k = 0; k < KROWS; k++) { float v = yb[(size_t)k * NN]; s += v * v; }
  n2[idx] = s;
}

// ---------- transpose+split: in fp32 [M][NN] -> Th/Tl bf16 [NN][Kpad] ----------
__global__ void tsplit_kernel(const float* __restrict__ in, const int inBatch, const int Mvalid,
                              ush* __restrict__ Th, ush* __restrict__ Tl, const int Kpad) {
  __shared__ float t[32][65];
  const int b = blockIdx.z;
  const int n0 = blockIdx.x * 64;
  const int k0 = blockIdx.y * 32;
  const float* src = in + (size_t)b * inBatch;
  const int tid = threadIdx.x;
  const int lr = tid >> 3;
  const int lc = (tid & 7) * 8;
  const int gk = k0 + lr;
  if (gk < Mvalid) {
    *(float4*)&t[lr][lc]     = *(const float4*)&src[(size_t)gk * NN + n0 + lc];
    *(float4*)&t[lr][lc + 4] = *(const float4*)&src[(size_t)gk * NN + n0 + lc + 4];
  } else {
    const float4 z4 = {0.f, 0.f, 0.f, 0.f};
    *(float4*)&t[lr][lc] = z4; *(float4*)&t[lr][lc + 4] = z4;
  }
  __syncthreads();
  const int on = tid >> 2;
  const int ok = (tid & 3) * 8;
  ush hv[8], lv[8];
  #pragma unroll
  for (int j = 0; j < 8; j++) {
    const float v = t[ok + j][on];
    hv[j] = bf16_rne(v); lv[j] = bf16_rne(v - bf16_f(hv[j]));
  }
  const size_t off = ((size_t)b * NN + n0 + on) * Kpad + k0 + ok;
  *(ushort4*)&Th[off] = *(ushort4*)&hv[0];
  *(ushort4*)&Th[off + 4] = *(ushort4*)&hv[4];
  *(ushort4*)&Tl[off] = *(ushort4*)&lv[0];
  *(ushort4*)&Tl[off + 4] = *(ushort4*)&lv[4];
}

// ---------- gram v2: 128x128 dbuf; writes dist splits + sigma partials ----------
__global__ __launch_bounds__(256, 2)
void gram_v2_kernel(const ush* __restrict__ Yth, const ush* __restrict__ Ytl,
                    const float* __restrict__ n2, const float* __restrict__ mask,
                    ush* __restrict__ Dh, ush* __restrict__ Dl,
                    float* __restrict__ sigpart) {
  __shared__ ush lds[32768];
  const int b = blockIdx.z;
  const int i0 = blockIdx.y * 128;
  const int j0 = blockIdx.x * 128;
  const ush* Ah = Yth + (size_t)b * NN * KPAD + (size_t)i0 * KPAD;
  const ush* Al = Ytl + (size_t)b * NN * KPAD + (size_t)i0 * KPAD;
  const ush* Bh = Yth + (size_t)b * NN * KPAD + (size_t)j0 * KPAD;
  const ush* Bl = Ytl + (size_t)b * NN * KPAD + (size_t)j0 * KPAD;
  f4 acc[4][4];
  const f4 z4 = {0.f, 0.f, 0.f, 0.f};
  #pragma unroll
  for (int mi = 0; mi < 4; mi++)
    #pragma unroll
    for (int ni = 0; ni < 4; ni++) acc[mi][ni] = z4;
  stageA(Ah, Al, KPAD, Bh, Bl, KPAD, 0, lds);
  __syncthreads();
  int pb = 0;
  for (int kt = 32; kt < KPAD; kt += 32) {
    stageA(Ah, Al, KPAD, Bh, Bl, KPAD, kt, lds + (pb ^ 1) * 16384);
    computeA(lds + pb * 16384, acc);
    __syncthreads();
    pb ^= 1;
  }
  computeA(lds + pb * 16384, acc);
  const int lane = threadIdx.x & 63;
  const int wid = threadIdx.x >> 6;
  const int wr = wid >> 1, wc = wid & 1;
  const int frow = lane & 15, hh = lane >> 4;
  const float scale = 3.0f / 257.0f;
  float lsum = 0.f;
  #pragma unroll
  for (int ni = 0; ni < 4; ni++) {
    const int j = j0 + wc * 64 + ni * 16 + frow;
    const float n2j = n2[b * NN + j];
    const float mkj = mask[b * NN + j];
    #pragma unroll
    for (int mi = 0; mi < 4; mi++) {
      #pragma unroll
      for (int r = 0; r < 4; r++) {
        const int i = i0 + wr * 64 + mi * 16 + hh * 4 + r;
        const float D = scale * (n2[b * NN + i] + n2j - 2.0f * acc[mi][ni][r]);
        const float d = sqrtf(fmaxf(D, 1e-12f));
        const float mmv = mask[b * NN + i] * mkj;
        const float wd = d * mmv;
        const size_t off = ((size_t)b * NN + i) * NN + j;
        const ush dh = bf16_rne(wd);
        Dh[off] = dh;
        Dl[off] = bf16_rne(wd - bf16_f(dh));
        lsum += wd * mmv;
      }
    }
  }
  #pragma unroll
  for (int off = 32; off > 0; off >>= 1) lsum += __shfl_down(lsum, off, 64);
  __syncthreads();                 // LDS compute reads all done
  float* rbuf = (float*)lds;
  if (lane == 0) rbuf[wid] = lsum;
  __syncthreads();
  if (threadIdx.x == 0)
    sigpart[(size_t)b * 64 + blockIdx.y * 8 + blockIdx.x] =
        rbuf[0] + rbuf[1] + rbuf[2] + rbuf[3];
}

// ---------- finalize sigma -> fb = -10*msum^2/signum ----------
__global__ void sigfinal_kernel(const float* __restrict__ sigpart, const float* __restrict__ msum,
                                float* __restrict__ fbuf) {
  const int b = blockIdx.x;
  float v = (threadIdx.x < 64) ? sigpart[b * 64 + threadIdx.x] : 0.f;
  v = blockReduceSum(v);
  if (threadIdx.x == 0) { const float ms = msum[b]; fbuf[b] = -10.0f * ms * ms / v; }
}

// ---------- exp in-place on split pairs; wsum from reconstructed values ----------
__global__ void exp2_kernel(ush* __restrict__ Wh, ush* __restrict__ Wl,
                            const float* __restrict__ mask, const float* __restrict__ fbuf,
                            float* __restrict__ wsum) {
  const int b = blockIdx.y, n = blockIdx.x;
  const float fb = fbuf[b];
  const float mn = mask[b * NN + n];
  const size_t roff = ((size_t)b * NN + n) * NN;
  const float4 mk = ((const float4*)(mask + b * NN))[threadIdx.x];
  ushort4 dh = *(ushort4*)&Wh[roff + threadIdx.x * 4];
  ushort4 dl = *(ushort4*)&Wl[roff + threadIdx.x * 4];
  float w0 = expf(fb * (bf16_f(dh.x) + bf16_f(dl.x))) * mn * mk.x;
  float w1 = expf(fb * (bf16_f(dh.y) + bf16_f(dl.y))) * mn * mk.y;
  float w2 = expf(fb * (bf16_f(dh.z) + bf16_f(dl.z))) * mn * mk.z;
  float w3 = expf(fb * (bf16_f(dh.w) + bf16_f(dl.w))) * mn * mk.w;
  ushort4 h4, l4;
  h4.x = bf16_rne(w0); l4.x = bf16_rne(w0 - bf16_f(h4.x));
  h4.y = bf16_rne(w1); l4.y = bf16_rne(w1 - bf16_f(h4.y));
  h4.z = bf16_rne(w2); l4.z = bf16_rne(w2 - bf16_f(h4.z));
  h4.w = bf16_rne(w3); l4.w = bf16_rne(w3 - bf16_f(h4.w));
  *(ushort4*)&Wh[roff + threadIdx.x * 4] = h4;
  *(ushort4*)&Wl[roff + threadIdx.x * 4] = l4;
  float s = (bf16_f(h4.x) + bf16_f(l4.x)) + (bf16_f(h4.y) + bf16_f(l4.y)) +
            (bf16_f(h4.z) + bf16_f(l4.z)) + (bf16_f(h4.w) + bf16_f(l4.w));
  s = blockReduceSum(s);
  if (threadIdx.x == 0) wsum[b * NN + n] = s;
}

// ---------- cvall: C[g] = Kis[g]*(W[g]@X)*mask, 3 stacked mats (768 rows) ----------
__global__ __launch_bounds__(256, 2)
void cvall_kernel(const ush* __restrict__ Amh, const ush* __restrict__ Aml,
                  const ush* __restrict__ Bth, const ush* __restrict__ Btl,
                  const float* __restrict__ mask, const float* __restrict__ Kis,
                  ush* __restrict__ Ch, ush* __restrict__ Cl) {
  __shared__ ush lds[32768];
  const int b = blockIdx.z;
  const int r0 = blockIdx.y * 128;
  const int c0 = blockIdx.x * 128;
  const ush* Ah = Amh + (size_t)r0 * CH;
  const ush* Al = Aml + (size_t)r0 * CH;
  const ush* Bh = Bth + (size_t)b * NN * CH + (size_t)c0 * CH;
  const ush* Bl = Btl + (size_t)b * NN * CH + (size_t)c0 * CH;
  f4 acc[4][4];
  const f4 z4 = {0.f, 0.f, 0.f, 0.f};
  #pragma unroll
  for (int mi = 0; mi < 4; mi++)
    #pragma unroll
    for (int ni = 0; ni < 4; ni++) acc[mi][ni] = z4;
  stageA(Ah, Al, CH, Bh, Bl, CH, 0, lds);
  __syncthreads();
  int pb = 0;
  for (int kt = 32; kt < CH; kt += 32) {
    stageA(Ah, Al, CH, Bh, Bl, CH, kt, lds + (pb ^ 1) * 16384);
    computeA(lds + pb * 16384, acc);
    __syncthreads();
    pb ^= 1;
  }
  computeA(lds + pb * 16384, acc);
  const int lane = threadIdx.x & 63;
  const int wid = threadIdx.x >> 6;
  const int wr = wid >> 1, wc = wid & 1;
  const int frow = lane & 15, hh = lane >> 4;
  const float alpha = Kis[blockIdx.y >> 1];
  #pragma unroll
  for (int ni = 0; ni < 4; ni++) {
    const int col = c0 + wc * 64 + ni * 16 + frow;
    const float am = alpha * mask[b * NN + col];
    #pragma unroll
    for (int mi = 0; mi < 4; mi++) {
      #pragma unroll
      for (int r = 0; r < 4; r++) {
        const int row = r0 + wr * 64 + mi * 16 + hh * 4 + r;
        const size_t off = ((size_t)b * 768 + row) * NN + col;
        const float v = acc[mi][ni][r] * am;
        const ush vh = bf16_rne(v);
        Ch[off] = vh;
        Cl[off] = bf16_rne(v - bf16_f(vh));
      }
    }
  }
}

// ---------- mm1 v2: out = X*wsum - X@W + add.  64x128 dbuf core ----------
// OUTMODE 0: split write; 1: fp32 write; 2: outF = zin - 0.01*out (fp32)
template <int OUTMODE>
__global__ __launch_bounds__(256, 3)
void mm1_v2_kernel(const ush* __restrict__ Xh, const ush* __restrict__ Xl, const size_t xBatch,
                   const ush* __restrict__ Wh, const ush* __restrict__ Wl,
                   const ush* __restrict__ addh, const ush* __restrict__ addl, const size_t aBatch,
                   const float* __restrict__ zin, const float* __restrict__ wsum,
                   float* __restrict__ outF, ush* __restrict__ outH, ush* __restrict__ outL) {
  __shared__ ush lds[24576];
  const int b = blockIdx.z;
  const int r0 = blockIdx.y * 64;
  const int n0 = blockIdx.x * 128;
  const ush* Ah = Xh + (size_t)b * xBatch + (size_t)r0 * NN;
  const ush* Al = Xl + (size_t)b * xBatch + (size_t)r0 * NN;
  const ush* Bh = Wh + (size_t)b * NN * NN + (size_t)n0 * NN;
  const ush* Bl = Wl + (size_t)b * NN * NN + (size_t)n0 * NN;
  f4 acc[4][2];
  const f4 z4 = {0.f, 0.f, 0.f, 0.f};
  #pragma unroll
  for (int mi = 0; mi < 4; mi++) { acc[mi][0] = z4; acc[mi][1] = z4; }
  stageB(Ah, Al, NN, Bh, Bl, NN, 0, lds);
  __syncthreads();
  int pb = 0;
  for (int kt = 32; kt < NN; kt += 32) {
    stageB(Ah, Al, NN, Bh, Bl, NN, kt, lds + (pb ^ 1) * 12288);
    computeB(lds + pb * 12288, acc);
    __syncthreads();
    pb ^= 1;
  }
  computeB(lds + pb * 12288, acc);
  const int lane = threadIdx.x & 63;
  const int wid = threadIdx.x >> 6;
  const int frow = lane & 15, hh = lane >> 4;
  #pragma unroll
  for (int ni = 0; ni < 2; ni++) {
    const int col = n0 + wid * 32 + ni * 16 + frow;
    const float ws = wsum[b * NN + col];
    #pragma unroll
    for (int mi = 0; mi < 4; mi++) {
      #pragma unroll
      for (int r = 0; r < 4; r++) {
        const int row = r0 + mi * 16 + hh * 4 + r;
        const size_t xoff = (size_t)b * xBatch + (size_t)row * NN + col;
        const size_t aoff = (size_t)b * aBatch + (size_t)row * NN + col;
        const size_t ooff = (size_t)b * CH * NN + (size_t)row * NN + col;
        const float xv = bf16_f(Xh[xoff]) + bf16_f(Xl[xoff]);
        const float av = bf16_f(addh[aoff]) + bf16_f(addl[aoff]);
        const float o = xv * ws - acc[mi][ni][r] + av;
        if (OUTMODE == 0) {
          const ush oh = bf16_rne(o);
          outH[ooff] = oh;
          outL[ooff] = bf16_rne(o - bf16_f(oh));
        } else if (OUTMODE == 1) {
          outF[ooff] = o;
        } else {
          outF[ooff] = zin[ooff] - 0.01f * o;
        }
      }
    }
  }
}

// ---------- A = (A - masked_mean(A))*mask ----------
__global__ void centerA_kernel(float* __restrict__ A, const float* __restrict__ mask,
                               const float* __restrict__ msum) {
  const int b = blockIdx.y, c = blockIdx.x;
  float* row = A + ((size_t)b * CH + c) * NN;
  const float* mrow = mask + b * NN;
  const int t = threadIdx.x;
  float x[4], mv[4];
  float s = 0.f;
  #pragma unroll
  for (int j = 0; j < 4; j++) { int n = t + j * 256; x[j] = row[n]; mv[j] = mrow[n]; s += x[j] * mv[j]; }
  s = blockReduceSum(s);
  const float mean = s / msum[b];
  #pragma unroll
  for (int j = 0; j < 4; j++) row[t + j * 256] = (x[j] - mean) * mv[j];
}

// ---------- A = relu(A / sqrt(sum_c A^2 + 0.001)) ----------
__global__ void colnorm_kernel(float* __restrict__ A) {
  const int idx = blockIdx.x * 256 + threadIdx.x;
  const int b = idx >> 10, n = idx & 1023;
  float* col = A + (size_t)b * CH * NN + n;
  float s = 0.001f;
  for (int c = 0; c < CH; c++) { float v = col[(size_t)c * NN]; s += v * v; }
  const float rs = 1.0f / sqrtf(s);
  for (int c = 0; c < CH; c++) {
    float v = col[(size_t)c * NN] * rs;
    col[(size_t)c * NN] = v > 0.f ? v : 0.f;
  }
}

// ---------- Zout = (Wend @ Z)*mask; write + centered copy ----------
__global__ void zout_kernel(const float* __restrict__ Z, const float* __restrict__ Wend,
                            const float* __restrict__ mask, float* __restrict__ outZ,
                            float* __restrict__ Zcent) {
  const int b = blockIdx.x;
  __shared__ float w[3 * CH];
  for (int i = threadIdx.x; i < 3 * CH; i += 256) w[i] = Wend[i];
  __syncthreads();
  float a[3][4];
  #pragma unroll
  for (int j = 0; j < 4; j++) { a[0][j] = 0.f; a[1][j] = 0.f; a[2][j] = 0.f; }
  const float* Zb = Z + (size_t)b * CH * NN;
  for (int c = 0; c < CH; c++) {
    const float w0 = w[c], w1 = w[CH + c], w2 = w[2 * CH + c];
    #pragma unroll
    for (int j = 0; j < 4; j++) {
      float zv = Zb[(size_t)c * NN + threadIdx.x + j * 256];
      a[0][j] += w0 * zv; a[1][j] += w1 * zv; a[2][j] += w2 * zv;
    }
  }
  float sum[3] = {0.f, 0.f, 0.f};
  #pragma unroll
  for (int j = 0; j < 4; j++) {
    const int n = threadIdx.x + j * 256;
    const float mv = mask[b * NN + n];
    #pragma unroll
    for (int o = 0; o < 3; o++) {
      a[o][j] *= mv;
      outZ[((size_t)b * 3 + o) * NN + n] = a[o][j];
      sum[o] += a[o][j];
    }
  }
  for (int o = 0; o < 3; o++) {
    float s = blockReduceSum(sum[o]);
    const float mean = s * (1.0f / NN);
    #pragma unroll
    for (int j = 0; j < 4; j++) {
      const int n = threadIdx.x + j * 256;
      Zcent[((size_t)b * 3 + o) * NN + n] = a[o][j] - mean;
    }
  }
}

// ---------- final distances ----------
__global__ void dist_kernel(const float* __restrict__ Zcent, float* __restrict__ outD) {
  const int b = blockIdx.z;
  const int n = blockIdx.y;
  const int m = blockIdx.x * 256 + threadIdx.x;
  const float* Zb = Zcent + (size_t)b * 3 * NN;
  const float x0 = Zb[n], x1 = Zb[NN + n], x2 = Zb[2 * NN + n];
  const float d0 = x0 - Zb[m], d1 = x1 - Zb[NN + m], d2 = x2 - Zb[2 * NN + m];
  const float D = d0 * d0 + d1 * d1 + d2 * d2;
  outD[((size_t)b * NN + n) * NN + m] = sqrtf(fmaxf(D, 1e-12f));
}

extern "C" void kernel_launch(void* const* d_in, const int* in_sizes, int n_in,
                              void* d_out, int out_size, void* d_ws, size_t ws_size,
                              hipStream_t stream) {
  const float* Zin  = (const float*)d_in[0];
  const float* mask = (const float*)d_in[1];
  const float* K0   = (const float*)d_in[2];
  const float* Knet = (const float*)d_in[3];
  const float* W    = (const float*)d_in[4];
  const float* Wend = (const float*)d_in[5];
  float* out = (float*)d_out;

  // d_out scratch: W split pair (67 MB) lives in the dist region until the end.
  ush* Whb = (ush*)out;                           // BB*NN*NN
  ush* Wlb = Whb + (size_t)BB * NN * NN;
  float* outZ = out + (size_t)BB * NN * NN;

  float* p = (float*)d_ws;
  // union region: [Y fp32 | Yth | Ytl] (gram phase)  ∪  [Ch | Cl] (cv/mm1 phase)
  float* uni = p; p += (size_t)BB * 768 * NN;     // 12.58M floats
  float* Y = uni;
  ush* Yth = (ush*)(uni + (size_t)BB * KP * NN);
  ush* Ytl = Yth + (size_t)BB * NN * KPAD;
  ush* Chb = (ush*)uni;
  ush* Clb = Chb + (size_t)BB * 768 * NN;

  float* Zcur = p; p += (size_t)BB * CH * NN;
  float* U    = p; p += (size_t)BB * CH * NN;
  ush* Zth = (ush*)p; p += (size_t)BB * NN * CH / 2;
  ush* Ztl = (ush*)p; p += (size_t)BB * NN * CH / 2;
  ush* Thb = Zth;   // alias: Zth dead after cvall, T dead before next tsplit
  ush* Tlb = Ztl;
  ush* Wmh = (ush*)p; p += (size_t)18 * CH * CH / 2;
  ush* Wml = (ush*)p; p += (size_t)18 * CH * CH / 2;
  ush* Wth = (ush*)p; p += (size_t)18 * CH * CH / 2;
  ush* Wtl = (ush*)p; p += (size_t)18 * CH * CH / 2;
  float* n2b  = p; p += BB * NN;
  float* wsb  = p; p += BB * NN;
  float* msum = p; p += BB;
  float* sigp = p; p += BB * 64;
  float* fbuf = p; p += BB;
  float* Zcent= p; p += BB * 3 * NN;

  const dim3 ggram(NN / 128, NN / 128, BB);   // 8,8,16
  const dim3 gcv(NN / 128, 768 / 128, BB);    // 8,6,16
  const dim3 gmm(NN / 128, CH / 64, BB);      // 8,4,16
  const dim3 gtsZ(NN / 64, CH / 32, BB);
  const dim3 gtsY(NN / 64, KPAD / 32, BB);
  const size_t sC = (size_t)768 * NN;         // C batch stride
  const size_t sT = (size_t)CH * NN;

  masksum_kernel<<<BB, 256, 0, stream>>>(mask, msum);
  wprep_kernel<<<dim3(16, 18), 256, 0, stream>>>(W, Wmh, Wml, Wth, Wtl);
  k0_kernel<<<dim3(CH, BB), 256, 0, stream>>>(Zin, K0, mask, Zcur);

  for (int layer = 0; layer < NLAYERS; layer++) {
    rownorm_kernel<<<dim3(KROWS, BB), 256, 0, stream>>>(Zcur, mask, msum, Y);
    n2_kernel<<<BB * NN / 256, 256, 0, stream>>>(Y, n2b);
    tsplit_kernel<<<gtsY, 256, 0, stream>>>(Y, KP * NN, KROWS, Yth, Ytl, KPAD);
    gram_v2_kernel<<<ggram, 256, 0, stream>>>(Yth, Ytl, n2b, mask, Whb, Wlb, sigp);
    sigfinal_kernel<<<BB, 256, 0, stream>>>(sigp, msum, fbuf);
    exp2_kernel<<<dim3(NN, BB), 256, 0, stream>>>(Whb, Wlb, mask, fbuf, wsb);
    tsplit_kernel<<<gtsZ, 256, 0, stream>>>(Zcur, CH * NN, CH, Zth, Ztl, CH);

    const ush* Amh = Wmh + (size_t)layer * 3 * CH * CH;
    const ush* Aml = Wml + (size_t)layer * 3 * CH * CH;
    const ush* Ath = Wth + (size_t)layer * 3 * CH * CH;
    const ush* Atl = Wtl + (size_t)layer * 3 * CH * CH;
    const float* Ki = Knet + layer * 3;

    // ---- Ai = C0 + mm1(C1 + mm1(C2)), C = Ki*(Wi@Z)*mask ----
    cvall_kernel<<<gcv, 256, 0, stream>>>(Amh, Aml, Zth, Ztl, mask, Ki, Chb, Clb);
    mm1_v2_kernel<0><<<gmm, 256, 0, stream>>>(
        Chb + (size_t)512 * NN, Clb + (size_t)512 * NN, sC, Whb, Wlb,
        Chb + (size_t)256 * NN, Clb + (size_t)256 * NN, sC,
        nullptr, wsb, nullptr, Thb, Tlb);
    mm1_v2_kernel<1><<<gmm, 256, 0, stream>>>(
        Thb, Tlb, sT, Whb, Wlb, Chb, Clb, sC, nullptr, wsb, U, nullptr, nullptr);

    centerA_kernel<<<dim3(CH, BB), 256, 0, stream>>>(U, mask, msum);
    colnorm_kernel<<<BB * NN / 256, 256, 0, stream>>>(U);
    tsplit_kernel<<<gtsZ, 256, 0, stream>>>(U, CH * NN, CH, Zth, Ztl, CH);

    // ---- Z -= h * (C0 + mm1(C1 + mm1(C2))), C = Ki*(Wi^T@A)*mask ----
    cvall_kernel<<<gcv, 256, 0, stream>>>(Ath, Atl, Zth, Ztl, mask, Ki, Chb, Clb);
    mm1_v2_kernel<0><<<gmm, 256, 0, stream>>>(
        Chb + (size_t)512 * NN, Clb + (size_t)512 * NN, sC, Whb, Wlb,
        Chb + (size_t)256 * NN, Clb + (size_t)256 * NN, sC,
        nullptr, wsb, nullptr, Thb, Tlb);
    mm1_v2_kernel<2><<<gmm, 256, 0, stream>>>(
        Thb, Tlb, sT, Whb, Wlb, Chb, Clb, sC, Zcur, wsb, Zcur, nullptr, nullptr);
  }

  zout_kernel<<<BB, 256, 0, stream>>>(Zcur, Wend, mask, outZ, Zcent);
  dist_kernel<<<dim3(NN / 256, NN, BB), 256, 0, stream>>>(Zcent, out);
}

// Round 5
// 2455.761 us; speedup vs baseline: 2.3374x; 1.0836x over previous
//
#include <hip/hip_runtime.h>
#include <math.h>

#define BB 16
#define CIN 40
#define CH 256
#define NN 1024
#define KROWS 257
#define KP 272
#define KPAD 288        // gram K padded to 9*32
#define NLAYERS 6

typedef unsigned short ush;
typedef __attribute__((ext_vector_type(8))) short bh8;
typedef __attribute__((ext_vector_type(4))) float f4;

__device__ __forceinline__ ush bf16_rne(float x) {
  unsigned int u = __float_as_uint(x);
  u += 0x7fffu + ((u >> 16) & 1u);
  return (ush)(u >> 16);
}
__device__ __forceinline__ float bf16_f(ush h) {
  return __uint_as_float(((unsigned int)h) << 16);
}

#define GLD16(gp, lp) __builtin_amdgcn_global_load_lds( \
    (const __attribute__((address_space(1))) void*)(gp), \
    (__attribute__((address_space(3))) void*)(lp), 16, 0, 0)

// ---------- block reduction (256 threads = 4 waves) ----------
__device__ __forceinline__ float blockReduceSum(float v) {
  __shared__ float sred[4];
  const int lane = threadIdx.x & 63;
  const int wid  = threadIdx.x >> 6;
  #pragma unroll
  for (int off = 32; off > 0; off >>= 1) v += __shfl_down(v, off, 64);
  __syncthreads();
  if (lane == 0) sred[wid] = v;
  __syncthreads();
  return sred[0] + sred[1] + sred[2] + sred[3];
}

// ================= core A: 128x128 tile, BK=32, double-buffered =================
__device__ __forceinline__ void stageA(
    const ush* __restrict__ Ah, const ush* __restrict__ Al, const int sA,
    const ush* __restrict__ Bh, const ush* __restrict__ Bl, const int sB,
    const int kt, ush* buf) {
  const int lane = threadIdx.x & 63;
  const int wid = threadIdx.x >> 6;
  const int srow = lane >> 2;
  const int sl = (lane & 3) ^ ((srow >> 1) & 3);
  #pragma unroll
  for (int cc = 0; cc < 8; cc++) {
    const int c = wid * 8 + cc;
    const ush* src;
    if (c < 8)       src = Ah + (size_t)(c * 16 + srow) * sA + kt + sl * 8;
    else if (c < 16) src = Al + (size_t)((c - 8) * 16 + srow) * sA + kt + sl * 8;
    else if (c < 24) src = Bh + (size_t)((c - 16) * 16 + srow) * sB + kt + sl * 8;
    else             src = Bl + (size_t)((c - 24) * 16 + srow) * sB + kt + sl * 8;
    GLD16(src, buf + c * 512 + lane * 8);
  }
}

__device__ __forceinline__ void computeA(const ush* buf, f4 acc[4][4]) {
  const int lane = threadIdx.x & 63;
  const int wid = threadIdx.x >> 6;
  const int wr = wid >> 1, wc = wid & 1;
  const int frow = lane & 15;
  const int slot8 = (((lane >> 4) ^ ((frow >> 1) & 3)) << 3);
  bh8 ah[4], al[4], bh_[4], bl_[4];
  #pragma unroll
  for (int mi = 0; mi < 4; mi++) {
    const int off = (wr * 64 + mi * 16 + frow) * 32 + slot8;
    ah[mi] = *(const bh8*)&buf[off];
    al[mi] = *(const bh8*)&buf[4096 + off];
  }
  #pragma unroll
  for (int ni = 0; ni < 4; ni++) {
    const int off = (wc * 64 + ni * 16 + frow) * 32 + slot8;
    bh_[ni] = *(const bh8*)&buf[8192 + off];
    bl_[ni] = *(const bh8*)&buf[12288 + off];
  }
  #pragma unroll
  for (int mi = 0; mi < 4; mi++)
    #pragma unroll
    for (int ni = 0; ni < 4; ni++) {
      acc[mi][ni] = __builtin_amdgcn_mfma_f32_16x16x32_bf16(ah[mi], bh_[ni], acc[mi][ni], 0, 0, 0);
      acc[mi][ni] = __builtin_amdgcn_mfma_f32_16x16x32_bf16(ah[mi], bl_[ni], acc[mi][ni], 0, 0, 0);
      acc[mi][ni] = __builtin_amdgcn_mfma_f32_16x16x32_bf16(al[mi], bh_[ni], acc[mi][ni], 0, 0, 0);
    }
}

// ================= core B: 64x128 tile, BK=32, double-buffered =================
__device__ __forceinline__ void stageB(
    const ush* __restrict__ Ah, const ush* __restrict__ Al, const int sA,
    const ush* __restrict__ Bh, const ush* __restrict__ Bl, const int sB,
    const int kt, ush* buf) {
  const int lane = threadIdx.x & 63;
  const int wid = threadIdx.x >> 6;
  const int srow = lane >> 2;
  const int sl = (lane & 3) ^ ((srow >> 1) & 3);
  #pragma unroll
  for (int cc = 0; cc < 6; cc++) {
    const int c = wid * 6 + cc;
    const ush* src;
    if (c < 4)       src = Ah + (size_t)(c * 16 + srow) * sA + kt + sl * 8;
    else if (c < 8)  src = Al + (size_t)((c - 4) * 16 + srow) * sA + kt + sl * 8;
    else if (c < 16) src = Bh + (size_t)((c - 8) * 16 + srow) * sB + kt + sl * 8;
    else             src = Bl + (size_t)((c - 16) * 16 + srow) * sB + kt + sl * 8;
    GLD16(src, buf + c * 512 + lane * 8);
  }
}

__device__ __forceinline__ void computeB(const ush* buf, f4 acc[4][2]) {
  const int lane = threadIdx.x & 63;
  const int wid = threadIdx.x >> 6;
  const int frow = lane & 15;
  const int slot8 = (((lane >> 4) ^ ((frow >> 1) & 3)) << 3);
  bh8 ah[4], al[4], bh_[2], bl_[2];
  #pragma unroll
  for (int mi = 0; mi < 4; mi++) {
    const int off = (mi * 16 + frow) * 32 + slot8;
    ah[mi] = *(const bh8*)&buf[off];
    al[mi] = *(const bh8*)&buf[2048 + off];
  }
  #pragma unroll
  for (int ni = 0; ni < 2; ni++) {
    const int off = (wid * 32 + ni * 16 + frow) * 32 + slot8;
    bh_[ni] = *(const bh8*)&buf[4096 + off];
    bl_[ni] = *(const bh8*)&buf[8192 + off];
  }
  #pragma unroll
  for (int mi = 0; mi < 4; mi++)
    #pragma unroll
    for (int ni = 0; ni < 2; ni++) {
      acc[mi][ni] = __builtin_amdgcn_mfma_f32_16x16x32_bf16(ah[mi], bh_[ni], acc[mi][ni], 0, 0, 0);
      acc[mi][ni] = __builtin_amdgcn_mfma_f32_16x16x32_bf16(ah[mi], bl_[ni], acc[mi][ni], 0, 0, 0);
      acc[mi][ni] = __builtin_amdgcn_mfma_f32_16x16x32_bf16(al[mi], bh_[ni], acc[mi][ni], 0, 0, 0);
    }
}

// ---------- Z0 = tanh(K0 @ Zin) * mask ----------
__global__ void k0_kernel(const float* __restrict__ Zin, const float* __restrict__ K0,
                          const float* __restrict__ mask, float* __restrict__ Zc) {
  const int b = blockIdx.y;
  const int o = blockIdx.x;
  __shared__ float w[CIN];
  if (threadIdx.x < CIN) w[threadIdx.x] = K0[o * CIN + threadIdx.x];
  __syncthreads();
  for (int n = threadIdx.x; n < NN; n += 256) {
    float acc = 0.f;
    #pragma unroll
    for (int c = 0; c < CIN; c++) acc += w[c] * Zin[((size_t)b * CIN + c) * NN + n];
    Zc[((size_t)b * CH + o) * NN + n] = tanhf(acc) * mask[b * NN + n];
  }
}

__global__ void masksum_kernel(const float* __restrict__ mask, float* __restrict__ msum) {
  const int b = blockIdx.x;
  float v = 0.f;
  for (int n = threadIdx.x; n < NN; n += 256) v += mask[b * NN + n];
  v = blockReduceSum(v);
  if (threadIdx.x == 0) msum[b] = v;
}

// ---------- W prep: split-bf16 of W and W^T for all 18 matrices ----------
__global__ void wprep_kernel(const float* __restrict__ W, ush* __restrict__ Wmh,
                             ush* __restrict__ Wml, ush* __restrict__ Wth,
                             ush* __restrict__ Wtl) {
  __shared__ float t[64][65];
  const int mat = blockIdx.y;
  const int ty = blockIdx.x >> 2, tx = blockIdx.x & 3;
  const float* src = W + (size_t)mat * CH * CH;
  const int tid = threadIdx.x;
  const int lr = tid >> 2;
  const int lc = (tid & 3) * 16;
  float v[16];
  #pragma unroll
  for (int j = 0; j < 16; j += 4)
    *(float4*)&v[j] = *(const float4*)&src[(size_t)(ty * 64 + lr) * CH + tx * 64 + lc + j];
  ush hv[16], lv[16];
  #pragma unroll
  for (int j = 0; j < 16; j++) {
    hv[j] = bf16_rne(v[j]); lv[j] = bf16_rne(v[j] - bf16_f(hv[j]));
    t[lr][lc + j] = v[j];
  }
  const size_t offm = (size_t)mat * CH * CH + (size_t)(ty * 64 + lr) * CH + tx * 64 + lc;
  #pragma unroll
  for (int j = 0; j < 16; j += 4) {
    *(ushort4*)&Wmh[offm + j] = *(ushort4*)&hv[j];
    *(ushort4*)&Wml[offm + j] = *(ushort4*)&lv[j];
  }
  __syncthreads();
  #pragma unroll
  for (int j = 0; j < 16; j++) {
    const float w = t[lc + j][lr];
    hv[j] = bf16_rne(w); lv[j] = bf16_rne(w - bf16_f(hv[j]));
  }
  const size_t offt = (size_t)mat * CH * CH + (size_t)(tx * 64 + lr) * CH + ty * 64 + lc;
  #pragma unroll
  for (int j = 0; j < 16; j += 4) {
    *(ushort4*)&Wth[offt + j] = *(ushort4*)&hv[j];
    *(ushort4*)&Wtl[offt + j] = *(ushort4*)&lv[j];
  }
}

// ---------- per-row masked center + normalize, then plain center; writes Y ----------
__global__ void rownorm_kernel(const float* __restrict__ Z, const float* __restrict__ mask,
                               const float* __restrict__ msum, float* __restrict__ Y) {
  const int b = blockIdx.y;
  const int c = blockIdx.x;
  const int t = threadIdx.x;
  const float* mrow = mask + b * NN;
  float x[4];
  if (c < CH) {
    const float* row = Z + ((size_t)b * CH + c) * NN;
    float mv[4];
    float s = 0.f;
    #pragma unroll
    for (int j = 0; j < 4; j++) { int n = t + j * 256; x[j] = row[n]; mv[j] = mrow[n]; s += x[j] * mv[j]; }
    s = blockReduceSum(s);
    const float mean = s / msum[b];
    float q = 0.f;
    #pragma unroll
    for (int j = 0; j < 4; j++) { x[j] -= mean * mv[j]; q += x[j] * x[j]; }
    q = blockReduceSum(q);
    const float rs = 1.0f / sqrtf(q / msum[b] + 1e-4f);
    #pragma unroll
    for (int j = 0; j < 4; j++) x[j] *= rs;
  } else {
    #pragma unroll
    for (int j = 0; j < 4; j++) { int n = t + j * 256; x[j] = 0.5f * ((float)n * (1.0f / (NN - 1))) * mrow[n]; }
  }
  float s2 = 0.f;
  #pragma unroll
  for (int j = 0; j < 4; j++) s2 += x[j];
  s2 = blockReduceSum(s2);
  const float pm = s2 * (1.0f / NN);
  float* yrow = Y + ((size_t)b * KP + c) * NN;
  #pragma unroll
  for (int j = 0; j < 4; j++) yrow[t + j * 256] = x[j] - pm;
}

// ---------- transpose+split: in fp32 [M][NN] -> Th/Tl bf16 [NN][Kpad] ----------
__global__ void tsplit_kernel(const float* __restrict__ in, const int inBatch, const int Mvalid,
                              ush* __restrict__ Th, ush* __restrict__ Tl, const int Kpad) {
  __shared__ float t[32][65];
  const int b = blockIdx.z;
  const int n0 = blockIdx.x * 64;
  const int k0 = blockIdx.y * 32;
  const float* src = in + (size_t)b * inBatch;
  const int tid = threadIdx.x;
  const int lr = tid >> 3;
  const int lc = (tid & 7) * 8;
  const int gk = k0 + lr;
  if (gk < Mvalid) {
    *(float4*)&t[lr][lc]     = *(const float4*)&src[(size_t)gk * NN + n0 + lc];
    *(float4*)&t[lr][lc + 4] = *(const float4*)&src[(size_t)gk * NN + n0 + lc + 4];
  } else {
    const float4 z4 = {0.f, 0.f, 0.f, 0.f};
    *(float4*)&t[lr][lc] = z4; *(float4*)&t[lr][lc + 4] = z4;
  }
  __syncthreads();
  const int on = tid >> 2;
  const int ok = (tid & 3) * 8;
  ush hv[8], lv[8];
  #pragma unroll
  for (int j = 0; j < 8; j++) {
    const float v = t[ok + j][on];
    hv[j] = bf16_rne(v); lv[j] = bf16_rne(v - bf16_f(hv[j]));
  }
  const size_t off = ((size_t)b * NN + n0 + on) * Kpad + k0 + ok;
  *(ushort4*)&Th[off] = *(ushort4*)&hv[0];
  *(ushort4*)&Th[off + 4] = *(ushort4*)&hv[4];
  *(ushort4*)&Tl[off] = *(ushort4*)&lv[0];
  *(ushort4*)&Tl[off + 4] = *(ushort4*)&lv[4];
}

// ---------- n2 from transposed splits (coalesced): n2[b,n] = sum_k y^2 ----------
__global__ void n2split_kernel(const ush* __restrict__ Yth, const ush* __restrict__ Ytl,
                               float* __restrict__ n2) {
  const int t = threadIdx.x;
  const int gid = blockIdx.x * 64 + (t >> 2);
  const int kq = (t & 3) * 72;
  const ush* ph = Yth + (size_t)gid * KPAD + kq;
  const ush* pl = Ytl + (size_t)gid * KPAD + kq;
  float s = 0.f;
  #pragma unroll
  for (int j = 0; j < 72; j += 8) {
    ushort4 h0 = *(const ushort4*)&ph[j];
    ushort4 h1 = *(const ushort4*)&ph[j + 4];
    ushort4 l0 = *(const ushort4*)&pl[j];
    ushort4 l1 = *(const ushort4*)&pl[j + 4];
    float v;
    v = bf16_f(h0.x) + bf16_f(l0.x); s += v * v;
    v = bf16_f(h0.y) + bf16_f(l0.y); s += v * v;
    v = bf16_f(h0.z) + bf16_f(l0.z); s += v * v;
    v = bf16_f(h0.w) + bf16_f(l0.w); s += v * v;
    v = bf16_f(h1.x) + bf16_f(l1.x); s += v * v;
    v = bf16_f(h1.y) + bf16_f(l1.y); s += v * v;
    v = bf16_f(h1.z) + bf16_f(l1.z); s += v * v;
    v = bf16_f(h1.w) + bf16_f(l1.w); s += v * v;
  }
  s += __shfl_xor(s, 1, 64);
  s += __shfl_xor(s, 2, 64);
  if ((t & 3) == 0) n2[gid] = s;
}

// ---------- gram: 128x128 dbuf; LDS-transpose packed epilogue ----------
__global__ __launch_bounds__(256, 2)
void gram_v2_kernel(const ush* __restrict__ Yth, const ush* __restrict__ Ytl,
                    const float* __restrict__ n2, const float* __restrict__ mask,
                    ush* __restrict__ Dh, ush* __restrict__ Dl,
                    float* __restrict__ sigpart) {
  __shared__ ush lds[32768];
  const int b = blockIdx.z;
  const int i0 = blockIdx.y * 128;
  const int j0 = blockIdx.x * 128;
  const ush* Ah = Yth + (size_t)b * NN * KPAD + (size_t)i0 * KPAD;
  const ush* Al = Ytl + (size_t)b * NN * KPAD + (size_t)i0 * KPAD;
  const ush* Bh = Yth + (size_t)b * NN * KPAD + (size_t)j0 * KPAD;
  const ush* Bl = Ytl + (size_t)b * NN * KPAD + (size_t)j0 * KPAD;
  f4 acc[4][4];
  const f4 z4 = {0.f, 0.f, 0.f, 0.f};
  #pragma unroll
  for (int mi = 0; mi < 4; mi++)
    #pragma unroll
    for (int ni = 0; ni < 4; ni++) acc[mi][ni] = z4;
  stageA(Ah, Al, KPAD, Bh, Bl, KPAD, 0, lds);
  __syncthreads();
  int pb = 0;
  for (int kt = 32; kt < KPAD; kt += 32) {
    stageA(Ah, Al, KPAD, Bh, Bl, KPAD, kt, lds + (pb ^ 1) * 16384);
    computeA(lds + pb * 16384, acc);
    __syncthreads();
    pb ^= 1;
  }
  computeA(lds + pb * 16384, acc);
  __syncthreads();
  unsigned int* tl = (unsigned int*)lds;   // [128][128] swizzled
  const int lane = threadIdx.x & 63;
  const int wid = threadIdx.x >> 6;
  const int wr = wid >> 1, wc = wid & 1;
  const int frow = lane & 15, hh = lane >> 4;
  const float scale = 3.0f / 257.0f;
  float lsum = 0.f;
  #pragma unroll
  for (int ni = 0; ni < 4; ni++) {
    const int jl = wc * 64 + ni * 16 + frow;
    const int j = j0 + jl;
    const float n2j = n2[b * NN + j];
    const float mkj = mask[b * NN + j];
    #pragma unroll
    for (int mi = 0; mi < 4; mi++) {
      const int il = wr * 64 + mi * 16 + hh * 4;
      unsigned int pv[4];
      #pragma unroll
      for (int r = 0; r < 4; r++) {
        const int i = i0 + il + r;
        const float D = scale * (n2[b * NN + i] + n2j - 2.0f * acc[mi][ni][r]);
        const float d = sqrtf(fmaxf(D, 1e-12f));
        const float mmv = mask[b * NN + i] * mkj;
        const float wd = d * mmv;
        lsum += wd * mmv;
        const ush h = bf16_rne(wd);
        const ush l = bf16_rne(wd - bf16_f(h));
        pv[r] = (unsigned int)h | ((unsigned int)l << 16);
      }
      const int slot = (il >> 2) ^ (jl & 31);
      *(uint4*)&tl[jl * 128 + slot * 4] = *(uint4*)pv;
    }
  }
  __syncthreads();
  const int rrow = threadIdx.x >> 1;
  const int rch = (threadIdx.x & 1) * 64;
  const size_t obase = ((size_t)b * NN + i0 + rrow) * NN + j0 + rch;
  #pragma unroll
  for (int g = 0; g < 8; g++) {
    unsigned int hw[4], lw[4];
    #pragma unroll
    for (int q = 0; q < 4; q++) {
      unsigned int h2[2], l2[2];
      #pragma unroll
      for (int e = 0; e < 2; e++) {
        const int jl = rch + g * 8 + q * 2 + e;
        const int slot = (rrow >> 2) ^ (jl & 31);
        const unsigned int v = tl[jl * 128 + slot * 4 + (rrow & 3)];
        h2[e] = v & 0xffffu; l2[e] = v >> 16;
      }
      hw[q] = h2[0] | (h2[1] << 16);
      lw[q] = l2[0] | (l2[1] << 16);
    }
    *(uint4*)&Dh[obase + g * 8] = *(uint4*)hw;
    *(uint4*)&Dl[obase + g * 8] = *(uint4*)lw;
  }
  #pragma unroll
  for (int off = 32; off > 0; off >>= 1) lsum += __shfl_down(lsum, off, 64);
  __syncthreads();
  float* rbuf = (float*)lds;
  if (lane == 0) rbuf[wid] = lsum;
  __syncthreads();
  if (threadIdx.x == 0)
    sigpart[(size_t)b * 64 + blockIdx.y * 8 + blockIdx.x] =
        rbuf[0] + rbuf[1] + rbuf[2] + rbuf[3];
}

// ---------- finalize sigma -> fb = -10*msum^2/signum ----------
__global__ void sigfinal_kernel(const float* __restrict__ sigpart, const float* __restrict__ msum,
                                float* __restrict__ fbuf) {
  const int b = blockIdx.x;
  float v = (threadIdx.x < 64) ? sigpart[b * 64 + threadIdx.x] : 0.f;
  v = blockReduceSum(v);
  if (threadIdx.x == 0) { const float ms = msum[b]; fbuf[b] = -10.0f * ms * ms / v; }
}

// ---------- expw: W' = diag(rowsum) - W, split planes, in place ----------
__global__ void expw_kernel(ush* __restrict__ Wh, ush* __restrict__ Wl,
                            const float* __restrict__ mask, const float* __restrict__ fbuf) {
  const int b = blockIdx.y, n = blockIdx.x;
  const float fb = fbuf[b];
  const float mn = mask[b * NN + n];
  const size_t roff = ((size_t)b * NN + n) * NN;
  const int t = threadIdx.x;
  const float4 mk = ((const float4*)(mask + b * NN))[t];
  ushort4 dh = *(ushort4*)&Wh[roff + t * 4];
  ushort4 dl = *(ushort4*)&Wl[roff + t * 4];
  float w0 = expf(fb * (bf16_f(dh.x) + bf16_f(dl.x))) * mn * mk.x;
  float w1 = expf(fb * (bf16_f(dh.y) + bf16_f(dl.y))) * mn * mk.y;
  float w2 = expf(fb * (bf16_f(dh.z) + bf16_f(dl.z))) * mn * mk.z;
  float w3 = expf(fb * (bf16_f(dh.w) + bf16_f(dl.w))) * mn * mk.w;
  float s = blockReduceSum(w0 + w1 + w2 + w3);
  float v0 = -w0, v1 = -w1, v2 = -w2, v3 = -w3;
  if ((n >> 2) == t) {
    const int r = n & 3;
    if (r == 0) v0 += s; else if (r == 1) v1 += s; else if (r == 2) v2 += s; else v3 += s;
  }
  ushort4 h4, l4;
  h4.x = bf16_rne(v0); l4.x = bf16_rne(v0 - bf16_f(h4.x));
  h4.y = bf16_rne(v1); l4.y = bf16_rne(v1 - bf16_f(h4.y));
  h4.z = bf16_rne(v2); l4.z = bf16_rne(v2 - bf16_f(h4.z));
  h4.w = bf16_rne(v3); l4.w = bf16_rne(v3 - bf16_f(h4.w));
  *(ushort4*)&Wh[roff + t * 4] = h4;
  *(ushort4*)&Wl[roff + t * 4] = l4;
}

// ---------- cvall: C[g] = Kis[g]*(W[g]@X)*mask; g<2 packed u32, g==2 planar ----------
__global__ __launch_bounds__(256, 2)
void cvall_kernel(const ush* __restrict__ Amh, const ush* __restrict__ Aml,
                  const ush* __restrict__ Bth, const ush* __restrict__ Btl,
                  const float* __restrict__ mask, const float* __restrict__ Kis,
                  unsigned int* __restrict__ Cpack, ush* __restrict__ C2h,
                  ush* __restrict__ C2l) {
  __shared__ ush lds[32768];
  const int b = blockIdx.z;
  const int r0 = blockIdx.y * 128;
  const int c0 = blockIdx.x * 128;
  const ush* Ah = Amh + (size_t)r0 * CH;
  const ush* Al = Aml + (size_t)r0 * CH;
  const ush* Bh = Bth + (size_t)b * NN * CH + (size_t)c0 * CH;
  const ush* Bl = Btl + (size_t)b * NN * CH + (size_t)c0 * CH;
  f4 acc[4][4];
  const f4 z4 = {0.f, 0.f, 0.f, 0.f};
  #pragma unroll
  for (int mi = 0; mi < 4; mi++)
    #pragma unroll
    for (int ni = 0; ni < 4; ni++) acc[mi][ni] = z4;
  stageA(Ah, Al, CH, Bh, Bl, CH, 0, lds);
  __syncthreads();
  int pb = 0;
  for (int kt = 32; kt < CH; kt += 32) {
    stageA(Ah, Al, CH, Bh, Bl, CH, kt, lds + (pb ^ 1) * 16384);
    computeA(lds + pb * 16384, acc);
    __syncthreads();
    pb ^= 1;
  }
  computeA(lds + pb * 16384, acc);
  __syncthreads();
  unsigned int* tl = (unsigned int*)lds;
  const int lane = threadIdx.x & 63;
  const int wid = threadIdx.x >> 6;
  const int wr = wid >> 1, wc = wid & 1;
  const int frow = lane & 15, hh = lane >> 4;
  const float alpha = Kis[blockIdx.y >> 1];
  #pragma unroll
  for (int ni = 0; ni < 4; ni++) {
    const int jl = wc * 64 + ni * 16 + frow;
    const float am = alpha * mask[b * NN + c0 + jl];
    #pragma unroll
    for (int mi = 0; mi < 4; mi++) {
      const int il = wr * 64 + mi * 16 + hh * 4;
      unsigned int pv[4];
      #pragma unroll
      for (int r = 0; r < 4; r++) {
        const float v = acc[mi][ni][r] * am;
        const ush h = bf16_rne(v);
        const ush l = bf16_rne(v - bf16_f(h));
        pv[r] = (unsigned int)h | ((unsigned int)l << 16);
      }
      const int slot = (il >> 2) ^ (jl & 31);
      *(uint4*)&tl[jl * 128 + slot * 4] = *(uint4*)pv;
    }
  }
  __syncthreads();
  const int rrow = threadIdx.x >> 1;
  const int rch = (threadIdx.x & 1) * 64;
  if (blockIdx.y < 4) {
    unsigned int* dst = Cpack + ((size_t)b * 512 + r0 + rrow) * NN + c0 + rch;
    #pragma unroll
    for (int g = 0; g < 16; g++) {
      unsigned int pw[4];
      #pragma unroll
      for (int q = 0; q < 4; q++) {
        const int jl = rch + g * 4 + q;
        const int slot = (rrow >> 2) ^ (jl & 31);
        pw[q] = tl[jl * 128 + slot * 4 + (rrow & 3)];
      }
      *(uint4*)&dst[g * 4] = *(uint4*)pw;
    }
  } else {
    const size_t obase = ((size_t)b * 256 + (r0 - 512) + rrow) * NN + c0 + rch;
    #pragma unroll
    for (int g = 0; g < 8; g++) {
      unsigned int hw[4], lw[4];
      #pragma unroll
      for (int q = 0; q < 4; q++) {
        unsigned int h2[2], l2[2];
        #pragma unroll
        for (int e = 0; e < 2; e++) {
          const int jl = rch + g * 8 + q * 2 + e;
          const int slot = (rrow >> 2) ^ (jl & 31);
          const unsigned int v = tl[jl * 128 + slot * 4 + (rrow & 3)];
          h2[e] = v & 0xffffu; l2[e] = v >> 16;
        }
        hw[q] = h2[0] | (h2[1] << 16);
        lw[q] = l2[0] | (l2[1] << 16);
      }
      *(uint4*)&C2h[obase + g * 8] = *(uint4*)hw;
      *(uint4*)&C2l[obase + g * 8] = *(uint4*)lw;
    }
  }
}

// ---------- mm1 v3: out = X@W' + add(packed).  64x128 dbuf core ----------
// OUTMODE 0: planar split out (LDS transpose); 1: fp32; 2: outF = zin - 0.01*out
template <int OUTMODE>
__global__ __launch_bounds__(256, 3)
void mm1_v3_kernel(const ush* __restrict__ Xh, const ush* __restrict__ Xl, const size_t xStride,
                   const ush* __restrict__ Wh, const ush* __restrict__ Wl,
                   const unsigned int* __restrict__ addp, const size_t aStride,
                   const float* __restrict__ zin, float* __restrict__ outF,
                   ush* __restrict__ outH, ush* __restrict__ outL) {
  __shared__ ush lds[24576];
  const int b = blockIdx.z;
  const int r0 = blockIdx.y * 64;
  const int n0 = blockIdx.x * 128;
  const ush* Ah = Xh + (size_t)b * xStride + (size_t)r0 * NN;
  const ush* Al = Xl + (size_t)b * xStride + (size_t)r0 * NN;
  const ush* Bh = Wh + (size_t)b * NN * NN + (size_t)n0 * NN;
  const ush* Bl = Wl + (size_t)b * NN * NN + (size_t)n0 * NN;
  f4 acc[4][2];
  const f4 z4 = {0.f, 0.f, 0.f, 0.f};
  #pragma unroll
  for (int mi = 0; mi < 4; mi++) { acc[mi][0] = z4; acc[mi][1] = z4; }
  stageB(Ah, Al, NN, Bh, Bl, NN, 0, lds);
  __syncthreads();
  int pb = 0;
  for (int kt = 32; kt < NN; kt += 32) {
    stageB(Ah, Al, NN, Bh, Bl, NN, kt, lds + (pb ^ 1) * 12288);
    computeB(lds + pb * 12288, acc);
    __syncthreads();
    pb ^= 1;
  }
  computeB(lds + pb * 12288, acc);
  const int lane = threadIdx.x & 63;
  const int wid = threadIdx.x >> 6;
  const int frow = lane & 15, hh = lane >> 4;
  if (OUTMODE == 0) {
    __syncthreads();
    unsigned int* tl = (unsigned int*)lds;   // [128][64] swizzled
    #pragma unroll
    for (int ni = 0; ni < 2; ni++) {
      const int jl = wid * 32 + ni * 16 + frow;
      const int col = n0 + jl;
      #pragma unroll
      for (int mi = 0; mi < 4; mi++) {
        const int il = mi * 16 + hh * 4;
        unsigned int pv[4];
        #pragma unroll
        for (int r = 0; r < 4; r++) {
          const int row = r0 + il + r;
          const unsigned int av = addp[(size_t)b * aStride + (size_t)row * NN + col];
          const float o = acc[mi][ni][r] + bf16_f((ush)(av & 0xffffu)) + bf16_f((ush)(av >> 16));
          const ush h = bf16_rne(o);
          const ush l = bf16_rne(o - bf16_f(h));
          pv[r] = (unsigned int)h | ((unsigned int)l << 16);
        }
        const int slot = (il >> 2) ^ (jl & 15);
        *(uint4*)&tl[jl * 64 + slot * 4] = *(uint4*)pv;
      }
    }
    __syncthreads();
    const int rrow = threadIdx.x >> 2;
    const int rch = (threadIdx.x & 3) * 32;
    const size_t obase = ((size_t)b * 256 + r0 + rrow) * NN + n0 + rch;
    #pragma unroll
    for (int g = 0; g < 4; g++) {
      unsigned int hw[4], lw[4];
      #pragma unroll
      for (int q = 0; q < 4; q++) {
        unsigned int h2[2], l2[2];
        #pragma unroll
        for (int e = 0; e < 2; e++) {
          const int jl = rch + g * 8 + q * 2 + e;
          const int slot = (rrow >> 2) ^ (jl & 15);
          const unsigned int v = tl[jl * 64 + slot * 4 + (rrow & 3)];
          h2[e] = v & 0xffffu; l2[e] = v >> 16;
        }
        hw[q] = h2[0] | (h2[1] << 16);
        lw[q] = l2[0] | (l2[1] << 16);
      }
      *(uint4*)&outH[obase + g * 8] = *(uint4*)hw;
      *(uint4*)&outL[obase + g * 8] = *(uint4*)lw;
    }
  } else {
    #pragma unroll
    for (int ni = 0; ni < 2; ni++) {
      const int col = n0 + wid * 32 + ni * 16 + frow;
      #pragma unroll
      for (int mi = 0; mi < 4; mi++) {
        #pragma unroll
        for (int r = 0; r < 4; r++) {
          const int row = r0 + mi * 16 + hh * 4 + r;
          const unsigned int av = addp[(size_t)b * aStride + (size_t)row * NN + col];
          const float o = acc[mi][ni][r] + bf16_f((ush)(av & 0xffffu)) + bf16_f((ush)(av >> 16));
          const size_t ooff = (size_t)b * CH * NN + (size_t)row * NN + col;
          if (OUTMODE == 1) outF[ooff] = o;
          else outF[ooff] = zin[ooff] - 0.01f * o;
        }
      }
    }
  }
}

// ---------- rmean[b][c] = sum(U*mask)/msum ----------
__global__ void rmean_kernel(const float* __restrict__ U, const float* __restrict__ mask,
                             const float* __restrict__ msum, float* __restrict__ rmean) {
  const int b = blockIdx.y, c = blockIdx.x;
  const float* row = U + ((size_t)b * CH + c) * NN;
  const float* mrow = mask + b * NN;
  float s = 0.f;
  #pragma unroll
  for (int j = 0; j < 4; j++) { const int n = threadIdx.x + j * 256; s += row[n] * mrow[n]; }
  s = blockReduceSum(s);
  if (threadIdx.x == 0) rmean[b * CH + c] = s / msum[b];
}

// ---------- csq: partial col sums of ((U-rmean)*mask)^2, 16 c-rows per block ----------
__global__ void csq_kernel(const float* __restrict__ U, const float* __restrict__ mask,
                           const float* __restrict__ rmean, float* __restrict__ part) {
  const int b = blockIdx.y, cc = blockIdx.x;
  const int n = threadIdx.x * 4;
  const float4 m4 = *(const float4*)&mask[b * NN + n];
  float4 s4 = {0.f, 0.f, 0.f, 0.f};
  for (int r = 0; r < 16; r++) {
    const int c = cc * 16 + r;
    const float rm = rmean[b * CH + c];
    const float4 u4 = *(const float4*)&U[((size_t)b * CH + c) * NN + n];
    float a;
    a = (u4.x - rm) * m4.x; s4.x += a * a;
    a = (u4.y - rm) * m4.y; s4.y += a * a;
    a = (u4.z - rm) * m4.z; s4.z += a * a;
    a = (u4.w - rm) * m4.w; s4.w += a * a;
  }
  *(float4*)&part[((size_t)(b * 16 + cc)) * NN + n] = s4;
}

__global__ void csq2_kernel(const float* __restrict__ part, float* __restrict__ rs) {
  const int b = blockIdx.y;
  const int n = blockIdx.x * 256 + threadIdx.x;
  float s = 0.001f;
  #pragma unroll
  for (int cc = 0; cc < 16; cc++) s += part[((size_t)(b * 16 + cc)) * NN + n];
  rs[b * NN + n] = 1.0f / sqrtf(s);
}

// ---------- fused: A=(U-rmean)*mask; out = relu(A*rs) transposed splits ----------
__global__ void tsplitN_kernel(const float* __restrict__ U, const float* __restrict__ mask,
                               const float* __restrict__ rmean, const float* __restrict__ rs,
                               ush* __restrict__ Th, ush* __restrict__ Tl) {
  __shared__ float t[32][65];
  const int b = blockIdx.z;
  const int n0 = blockIdx.x * 64;
  const int k0 = blockIdx.y * 32;
  const int tid = threadIdx.x;
  const int lr = tid >> 3;
  const int lc = (tid & 7) * 8;
  const int gc = k0 + lr;
  const float rm = rmean[b * CH + gc];
  const float4 ma = *(const float4*)&mask[b * NN + n0 + lc];
  const float4 mb = *(const float4*)&mask[b * NN + n0 + lc + 4];
  const float4 ra = *(const float4*)&rs[b * NN + n0 + lc];
  const float4 rb = *(const float4*)&rs[b * NN + n0 + lc + 4];
  const float4 ua = *(const float4*)&U[((size_t)b * CH + gc) * NN + n0 + lc];
  const float4 ub = *(const float4*)&U[((size_t)b * CH + gc) * NN + n0 + lc + 4];
  t[lr][lc + 0] = fmaxf((ua.x - rm) * ma.x * ra.x, 0.f);
  t[lr][lc + 1] = fmaxf((ua.y - rm) * ma.y * ra.y, 0.f);
  t[lr][lc + 2] = fmaxf((ua.z - rm) * ma.z * ra.z, 0.f);
  t[lr][lc + 3] = fmaxf((ua.w - rm) * ma.w * ra.w, 0.f);
  t[lr][lc + 4] = fmaxf((ub.x - rm) * mb.x * rb.x, 0.f);
  t[lr][lc + 5] = fmaxf((ub.y - rm) * mb.y * rb.y, 0.f);
  t[lr][lc + 6] = fmaxf((ub.z - rm) * mb.z * rb.z, 0.f);
  t[lr][lc + 7] = fmaxf((ub.w - rm) * mb.w * rb.w, 0.f);
  __syncthreads();
  const int on = tid >> 2;
  const int ok = (tid & 3) * 8;
  ush hv[8], lv[8];
  #pragma unroll
  for (int j = 0; j < 8; j++) {
    const float v = t[ok + j][on];
    hv[j] = bf16_rne(v); lv[j] = bf16_rne(v - bf16_f(hv[j]));
  }
  const size_t off = ((size_t)b * NN + n0 + on) * CH + k0 + ok;
  *(ushort4*)&Th[off] = *(ushort4*)&hv[0];
  *(ushort4*)&Th[off + 4] = *(ushort4*)&hv[4];
  *(ushort4*)&Tl[off] = *(ushort4*)&lv[0];
  *(ushort4*)&Tl[off + 4] = *(ushort4*)&lv[4];
}

// ---------- Zout = (Wend @ Z)*mask; write + centered copy ----------
__global__ void zout_kernel(const float* __restrict__ Z, const float* __restrict__ Wend,
                            const float* __restrict__ mask, float* __restrict__ outZ,
                            float* __restrict__ Zcent) {
  const int b = blockIdx.x;
  __shared__ float w[3 * CH];
  for (int i = threadIdx.x; i < 3 * CH; i += 256) w[i] = Wend[i];
  __syncthreads();
  float a[3][4];
  #pragma unroll
  for (int j = 0; j < 4; j++) { a[0][j] = 0.f; a[1][j] = 0.f; a[2][j] = 0.f; }
  const float* Zb = Z + (size_t)b * CH * NN;
  for (int c = 0; c < CH; c++) {
    const float w0 = w[c], w1 = w[CH + c], w2 = w[2 * CH + c];
    #pragma unroll
    for (int j = 0; j < 4; j++) {
      float zv = Zb[(size_t)c * NN + threadIdx.x + j * 256];
      a[0][j] += w0 * zv; a[1][j] += w1 * zv; a[2][j] += w2 * zv;
    }
  }
  float sum[3] = {0.f, 0.f, 0.f};
  #pragma unroll
  for (int j = 0; j < 4; j++) {
    const int n = threadIdx.x + j * 256;
    const float mv = mask[b * NN + n];
    #pragma unroll
    for (int o = 0; o < 3; o++) {
      a[o][j] *= mv;
      outZ[((size_t)b * 3 + o) * NN + n] = a[o][j];
      sum[o] += a[o][j];
    }
  }
  for (int o = 0; o < 3; o++) {
    float s = blockReduceSum(sum[o]);
    const float mean = s * (1.0f / NN);
    #pragma unroll
    for (int j = 0; j < 4; j++) {
      const int n = threadIdx.x + j * 256;
      Zcent[((size_t)b * 3 + o) * NN + n] = a[o][j] - mean;
    }
  }
}

// ---------- final distances ----------
__global__ void dist_kernel(const float* __restrict__ Zcent, float* __restrict__ outD) {
  const int b = blockIdx.z;
  const int n = blockIdx.y;
  const int m = blockIdx.x * 256 + threadIdx.x;
  const float* Zb = Zcent + (size_t)b * 3 * NN;
  const float x0 = Zb[n], x1 = Zb[NN + n], x2 = Zb[2 * NN + n];
  const float d0 = x0 - Zb[m], d1 = x1 - Zb[NN + m], d2 = x2 - Zb[2 * NN + m];
  const float D = d0 * d0 + d1 * d1 + d2 * d2;
  outD[((size_t)b * NN + n) * NN + m] = sqrtf(fmaxf(D, 1e-12f));
}

extern "C" void kernel_launch(void* const* d_in, const int* in_sizes, int n_in,
                              void* d_out, int out_size, void* d_ws, size_t ws_size,
                              hipStream_t stream) {
  const float* Zin  = (const float*)d_in[0];
  const float* mask = (const float*)d_in[1];
  const float* K0   = (const float*)d_in[2];
  const float* Knet = (const float*)d_in[3];
  const float* W    = (const float*)d_in[4];
  const float* Wend = (const float*)d_in[5];
  float* out = (float*)d_out;

  ush* Whb = (ush*)out;                           // BB*NN*NN (dist splits -> W')
  ush* Wlb = Whb + (size_t)BB * NN * NN;
  float* outZ = out + (size_t)BB * NN * NN;

  float* p = (float*)d_ws;
  // union: gram phase {Y fp32 | Yth | Ytl}; GEMM phase {Cpack u32 | C2h | C2l}
  float* uni = p; p += (size_t)BB * 768 * NN;     // 50.33 MB
  float* Y = uni;
  ush* Yth = (ush*)(uni + (size_t)BB * KP * NN);
  ush* Ytl = Yth + (size_t)BB * NN * KPAD;
  unsigned int* Cpack = (unsigned int*)uni;       // BB*512*NN u32
  ush* C2h = (ush*)(uni + (size_t)BB * 512 * NN); // BB*256*NN
  ush* C2l = C2h + (size_t)BB * 256 * NN;

  float* Zcur = p; p += (size_t)BB * CH * NN;
  float* U    = p; p += (size_t)BB * CH * NN;
  ush* Zth = (ush*)p; p += (size_t)BB * NN * CH / 2;
  ush* Ztl = (ush*)p; p += (size_t)BB * NN * CH / 2;
  ush* Thb = Zth;   // alias: Zth dead after cvall; T dead before tsplitN
  ush* Tlb = Ztl;
  ush* Wmh = (ush*)p; p += (size_t)18 * CH * CH / 2;
  ush* Wml = (ush*)p; p += (size_t)18 * CH * CH / 2;
  ush* Wth = (ush*)p; p += (size_t)18 * CH * CH / 2;
  ush* Wtl = (ush*)p; p += (size_t)18 * CH * CH / 2;
  float* n2b   = p; p += BB * NN;
  float* rsb   = p; p += BB * NN;
  float* msum  = p; p += BB;
  float* sigp  = p; p += BB * 64;
  float* fbuf  = p; p += BB;
  float* rmeanb= p; p += BB * CH;
  float* partb = p; p += (size_t)BB * 16 * NN;
  float* Zcent = p; p += BB * 3 * NN;

  const dim3 ggram(NN / 128, NN / 128, BB);   // 8,8,16
  const dim3 gcv(NN / 128, 768 / 128, BB);    // 8,6,16
  const dim3 gmm(NN / 128, CH / 64, BB);      // 8,4,16
  const dim3 gtsZ(NN / 64, CH / 32, BB);
  const dim3 gtsY(NN / 64, KPAD / 32, BB);
  const size_t sC = (size_t)512 * NN;         // Cpack batch stride
  const size_t sT = (size_t)CH * NN;

  masksum_kernel<<<BB, 256, 0, stream>>>(mask, msum);
  wprep_kernel<<<dim3(16, 18), 256, 0, stream>>>(W, Wmh, Wml, Wth, Wtl);
  k0_kernel<<<dim3(CH, BB), 256, 0, stream>>>(Zin, K0, mask, Zcur);

  for (int layer = 0; layer < NLAYERS; layer++) {
    rownorm_kernel<<<dim3(KROWS, BB), 256, 0, stream>>>(Zcur, mask, msum, Y);
    tsplit_kernel<<<gtsY, 256, 0, stream>>>(Y, KP * NN, KROWS, Yth, Ytl, KPAD);
    n2split_kernel<<<BB * NN / 64, 256, 0, stream>>>(Yth, Ytl, n2b);
    gram_v2_kernel<<<ggram, 256, 0, stream>>>(Yth, Ytl, n2b, mask, Whb, Wlb, sigp);
    sigfinal_kernel<<<BB, 256, 0, stream>>>(sigp, msum, fbuf);
    expw_kernel<<<dim3(NN, BB), 256, 0, stream>>>(Whb, Wlb, mask, fbuf);
    tsplit_kernel<<<gtsZ, 256, 0, stream>>>(Zcur, CH * NN, CH, Zth, Ztl, CH);

    const ush* Amh = Wmh + (size_t)layer * 3 * CH * CH;
    const ush* Aml = Wml + (size_t)layer * 3 * CH * CH;
    const ush* Ath = Wth + (size_t)layer * 3 * CH * CH;
    const ush* Atl = Wtl + (size_t)layer * 3 * CH * CH;
    const float* Ki = Knet + layer * 3;

    // ---- Ai = C0 + (C1 + C2@L)@L, C = Ki*(Wi@Z)*mask, L rows = W' ----
    cvall_kernel<<<gcv, 256, 0, stream>>>(Amh, Aml, Zth, Ztl, mask, Ki, Cpack, C2h, C2l);
    mm1_v3_kernel<0><<<gmm, 256, 0, stream>>>(C2h, C2l, sT, Whb, Wlb,
        Cpack + (size_t)256 * NN, sC, nullptr, nullptr, Thb, Tlb);
    mm1_v3_kernel<1><<<gmm, 256, 0, stream>>>(Thb, Tlb, sT, Whb, Wlb,
        Cpack, sC, nullptr, U, nullptr, nullptr);

    rmean_kernel<<<dim3(CH, BB), 256, 0, stream>>>(U, mask, msum, rmeanb);
    csq_kernel<<<dim3(16, BB), 256, 0, stream>>>(U, mask, rmeanb, partb);
    csq2_kernel<<<dim3(NN / 256, BB), 256, 0, stream>>>(partb, rsb);
    tsplitN_kernel<<<gtsZ, 256, 0, stream>>>(U, mask, rmeanb, rsb, Zth, Ztl);

    // ---- Z -= 0.01 * (C0 + (C1 + C2@L)@L), C = Ki*(Wi^T@A)*mask ----
    cvall_kernel<<<gcv, 256, 0, stream>>>(Ath, Atl, Zth, Ztl, mask, Ki, Cpack, C2h, C2l);
    mm1_v3_kernel<0><<<gmm, 256, 0, stream>>>(C2h, C2l, sT, Whb, Wlb,
        Cpack + (size_t)256 * NN, sC, nullptr, nullptr, Thb, Tlb);
    mm1_v3_kernel<2><<<gmm, 256, 0, stream>>>(Thb, Tlb, sT, Whb, Wlb,
        Cpack, sC, Zcur, Zcur, nullptr, nullptr);
  }

  zout_kernel<<<BB, 256, 0, stream>>>(Zcur, Wend, mask, outZ, Zcent);
  dist_kernel<<<dim3(NN / 256, NN, BB), 256, 0, stream>>>(Zcent, out);
}

// Round 6
// 2261.777 us; speedup vs baseline: 2.5379x; 1.0858x over previous
//
#include <hip/hip_runtime.h>
#include <math.h>

#define BB 16
#define CIN 40
#define CH 256
#define NN 1024
#define KROWS 257
#define KP 272
#define KPAD 288        // gram K padded to 9*32
#define NLAYERS 6

typedef unsigned short ush;
typedef __attribute__((ext_vector_type(8))) short bh8;
typedef __attribute__((ext_vector_type(4))) float f4;

__device__ __forceinline__ ush bf16_rne(float x) {
  unsigned int u = __float_as_uint(x);
  u += 0x7fffu + ((u >> 16) & 1u);
  return (ush)(u >> 16);
}
__device__ __forceinline__ float bf16_f(ush h) {
  return __uint_as_float(((unsigned int)h) << 16);
}

#define GLD16(gp, lp) __builtin_amdgcn_global_load_lds( \
    (const __attribute__((address_space(1))) void*)(gp), \
    (__attribute__((address_space(3))) void*)(lp), 16, 0, 0)

// ---------- block reduction (256 threads = 4 waves) ----------
__device__ __forceinline__ float blockReduceSum(float v) {
  __shared__ float sred[4];
  const int lane = threadIdx.x & 63;
  const int wid  = threadIdx.x >> 6;
  #pragma unroll
  for (int off = 32; off > 0; off >>= 1) v += __shfl_down(v, off, 64);
  __syncthreads();
  if (lane == 0) sred[wid] = v;
  __syncthreads();
  return sred[0] + sred[1] + sred[2] + sred[3];
}

// ================= core A: 128x128 tile, BK=32, double-buffered =================
__device__ __forceinline__ void stageA(
    const ush* __restrict__ Ah, const ush* __restrict__ Al, const int sA,
    const ush* __restrict__ Bh, const ush* __restrict__ Bl, const int sB,
    const int kt, ush* buf) {
  const int lane = threadIdx.x & 63;
  const int wid = threadIdx.x >> 6;
  const int srow = lane >> 2;
  const int sl = (lane & 3) ^ ((srow >> 1) & 3);
  #pragma unroll
  for (int cc = 0; cc < 8; cc++) {
    const int c = wid * 8 + cc;
    const ush* src;
    if (c < 8)       src = Ah + (size_t)(c * 16 + srow) * sA + kt + sl * 8;
    else if (c < 16) src = Al + (size_t)((c - 8) * 16 + srow) * sA + kt + sl * 8;
    else if (c < 24) src = Bh + (size_t)((c - 16) * 16 + srow) * sB + kt + sl * 8;
    else             src = Bl + (size_t)((c - 24) * 16 + srow) * sB + kt + sl * 8;
    GLD16(src, buf + c * 512 + lane * 8);
  }
}

__device__ __forceinline__ void computeA(const ush* buf, f4 acc[4][4]) {
  const int lane = threadIdx.x & 63;
  const int wid = threadIdx.x >> 6;
  const int wr = wid >> 1, wc = wid & 1;
  const int frow = lane & 15;
  const int slot8 = (((lane >> 4) ^ ((frow >> 1) & 3)) << 3);
  bh8 ah[4], al[4], bh_[4], bl_[4];
  #pragma unroll
  for (int mi = 0; mi < 4; mi++) {
    const int off = (wr * 64 + mi * 16 + frow) * 32 + slot8;
    ah[mi] = *(const bh8*)&buf[off];
    al[mi] = *(const bh8*)&buf[4096 + off];
  }
  #pragma unroll
  for (int ni = 0; ni < 4; ni++) {
    const int off = (wc * 64 + ni * 16 + frow) * 32 + slot8;
    bh_[ni] = *(const bh8*)&buf[8192 + off];
    bl_[ni] = *(const bh8*)&buf[12288 + off];
  }
  #pragma unroll
  for (int mi = 0; mi < 4; mi++)
    #pragma unroll
    for (int ni = 0; ni < 4; ni++) {
      acc[mi][ni] = __builtin_amdgcn_mfma_f32_16x16x32_bf16(ah[mi], bh_[ni], acc[mi][ni], 0, 0, 0);
      acc[mi][ni] = __builtin_amdgcn_mfma_f32_16x16x32_bf16(ah[mi], bl_[ni], acc[mi][ni], 0, 0, 0);
      acc[mi][ni] = __builtin_amdgcn_mfma_f32_16x16x32_bf16(al[mi], bh_[ni], acc[mi][ni], 0, 0, 0);
    }
}

// ================= core B: 64x128 tile, BK=32, double-buffered =================
__device__ __forceinline__ void stageB(
    const ush* __restrict__ Ah, const ush* __restrict__ Al, const int sA,
    const ush* __restrict__ Bh, const ush* __restrict__ Bl, const int sB,
    const int kt, ush* buf) {
  const int lane = threadIdx.x & 63;
  const int wid = threadIdx.x >> 6;
  const int srow = lane >> 2;
  const int sl = (lane & 3) ^ ((srow >> 1) & 3);
  #pragma unroll
  for (int cc = 0; cc < 6; cc++) {
    const int c = wid * 6 + cc;
    const ush* src;
    if (c < 4)       src = Ah + (size_t)(c * 16 + srow) * sA + kt + sl * 8;
    else if (c < 8)  src = Al + (size_t)((c - 4) * 16 + srow) * sA + kt + sl * 8;
    else if (c < 16) src = Bh + (size_t)((c - 8) * 16 + srow) * sB + kt + sl * 8;
    else             src = Bl + (size_t)((c - 16) * 16 + srow) * sB + kt + sl * 8;
    GLD16(src, buf + c * 512 + lane * 8);
  }
}

__device__ __forceinline__ void computeB(const ush* buf, f4 acc[4][2]) {
  const int lane = threadIdx.x & 63;
  const int wid = threadIdx.x >> 6;
  const int frow = lane & 15;
  const int slot8 = (((lane >> 4) ^ ((frow >> 1) & 3)) << 3);
  bh8 ah[4], al[4], bh_[2], bl_[2];
  #pragma unroll
  for (int mi = 0; mi < 4; mi++) {
    const int off = (mi * 16 + frow) * 32 + slot8;
    ah[mi] = *(const bh8*)&buf[off];
    al[mi] = *(const bh8*)&buf[2048 + off];
  }
  #pragma unroll
  for (int ni = 0; ni < 2; ni++) {
    const int off = (wid * 32 + ni * 16 + frow) * 32 + slot8;
    bh_[ni] = *(const bh8*)&buf[4096 + off];
    bl_[ni] = *(const bh8*)&buf[8192 + off];
  }
  #pragma unroll
  for (int mi = 0; mi < 4; mi++)
    #pragma unroll
    for (int ni = 0; ni < 2; ni++) {
      acc[mi][ni] = __builtin_amdgcn_mfma_f32_16x16x32_bf16(ah[mi], bh_[ni], acc[mi][ni], 0, 0, 0);
      acc[mi][ni] = __builtin_amdgcn_mfma_f32_16x16x32_bf16(ah[mi], bl_[ni], acc[mi][ni], 0, 0, 0);
      acc[mi][ni] = __builtin_amdgcn_mfma_f32_16x16x32_bf16(al[mi], bh_[ni], acc[mi][ni], 0, 0, 0);
    }
}

// ---------- Z0 = tanh(K0 @ Zin) * mask ----------
__global__ void k0_kernel(const float* __restrict__ Zin, const float* __restrict__ K0,
                          const float* __restrict__ mask, float* __restrict__ Zc) {
  const int b = blockIdx.y;
  const int o = blockIdx.x;
  __shared__ float w[CIN];
  if (threadIdx.x < CIN) w[threadIdx.x] = K0[o * CIN + threadIdx.x];
  __syncthreads();
  for (int n = threadIdx.x; n < NN; n += 256) {
    float acc = 0.f;
    #pragma unroll
    for (int c = 0; c < CIN; c++) acc += w[c] * Zin[((size_t)b * CIN + c) * NN + n];
    Zc[((size_t)b * CH + o) * NN + n] = tanhf(acc) * mask[b * NN + n];
  }
}

__global__ void masksum_kernel(const float* __restrict__ mask, float* __restrict__ msum) {
  const int b = blockIdx.x;
  float v = 0.f;
  for (int n = threadIdx.x; n < NN; n += 256) v += mask[b * NN + n];
  v = blockReduceSum(v);
  if (threadIdx.x == 0) msum[b] = v;
}

// ---------- W prep: split-bf16 of W and W^T for all 18 matrices ----------
__global__ void wprep_kernel(const float* __restrict__ W, ush* __restrict__ Wmh,
                             ush* __restrict__ Wml, ush* __restrict__ Wth,
                             ush* __restrict__ Wtl) {
  __shared__ float t[64][65];
  const int mat = blockIdx.y;
  const int ty = blockIdx.x >> 2, tx = blockIdx.x & 3;
  const float* src = W + (size_t)mat * CH * CH;
  const int tid = threadIdx.x;
  const int lr = tid >> 2;
  const int lc = (tid & 3) * 16;
  float v[16];
  #pragma unroll
  for (int j = 0; j < 16; j += 4)
    *(float4*)&v[j] = *(const float4*)&src[(size_t)(ty * 64 + lr) * CH + tx * 64 + lc + j];
  ush hv[16], lv[16];
  #pragma unroll
  for (int j = 0; j < 16; j++) {
    hv[j] = bf16_rne(v[j]); lv[j] = bf16_rne(v[j] - bf16_f(hv[j]));
    t[lr][lc + j] = v[j];
  }
  const size_t offm = (size_t)mat * CH * CH + (size_t)(ty * 64 + lr) * CH + tx * 64 + lc;
  #pragma unroll
  for (int j = 0; j < 16; j += 4) {
    *(ushort4*)&Wmh[offm + j] = *(ushort4*)&hv[j];
    *(ushort4*)&Wml[offm + j] = *(ushort4*)&lv[j];
  }
  __syncthreads();
  #pragma unroll
  for (int j = 0; j < 16; j++) {
    const float w = t[lc + j][lr];
    hv[j] = bf16_rne(w); lv[j] = bf16_rne(w - bf16_f(hv[j]));
  }
  const size_t offt = (size_t)mat * CH * CH + (size_t)(tx * 64 + lr) * CH + ty * 64 + lc;
  #pragma unroll
  for (int j = 0; j < 16; j += 4) {
    *(ushort4*)&Wth[offt + j] = *(ushort4*)&hv[j];
    *(ushort4*)&Wtl[offt + j] = *(ushort4*)&lv[j];
  }
}

// ---------- per-row masked center + normalize, then plain center; writes Y ----------
__global__ void rownorm_kernel(const float* __restrict__ Z, const float* __restrict__ mask,
                               const float* __restrict__ msum, float* __restrict__ Y) {
  const int b = blockIdx.y;
  const int c = blockIdx.x;
  const int t = threadIdx.x;
  const float* mrow = mask + b * NN;
  float x[4];
  if (c < CH) {
    const float* row = Z + ((size_t)b * CH + c) * NN;
    float mv[4];
    float s = 0.f;
    #pragma unroll
    for (int j = 0; j < 4; j++) { int n = t + j * 256; x[j] = row[n]; mv[j] = mrow[n]; s += x[j] * mv[j]; }
    s = blockReduceSum(s);
    const float mean = s / msum[b];
    float q = 0.f;
    #pragma unroll
    for (int j = 0; j < 4; j++) { x[j] -= mean * mv[j]; q += x[j] * x[j]; }
    q = blockReduceSum(q);
    const float rs = 1.0f / sqrtf(q / msum[b] + 1e-4f);
    #pragma unroll
    for (int j = 0; j < 4; j++) x[j] *= rs;
  } else {
    #pragma unroll
    for (int j = 0; j < 4; j++) { int n = t + j * 256; x[j] = 0.5f * ((float)n * (1.0f / (NN - 1))) * mrow[n]; }
  }
  float s2 = 0.f;
  #pragma unroll
  for (int j = 0; j < 4; j++) s2 += x[j];
  s2 = blockReduceSum(s2);
  const float pm = s2 * (1.0f / NN);
  float* yrow = Y + ((size_t)b * KP + c) * NN;
  #pragma unroll
  for (int j = 0; j < 4; j++) yrow[t + j * 256] = x[j] - pm;
}

// ---------- transpose+split: in fp32 [M][NN] -> Th/Tl bf16 [NN][Kpad] ----------
__global__ void tsplit_kernel(const float* __restrict__ in, const int inBatch, const int Mvalid,
                              ush* __restrict__ Th, ush* __restrict__ Tl, const int Kpad) {
  __shared__ float t[32][65];
  const int b = blockIdx.z;
  const int n0 = blockIdx.x * 64;
  const int k0 = blockIdx.y * 32;
  const float* src = in + (size_t)b * inBatch;
  const int tid = threadIdx.x;
  const int lr = tid >> 3;
  const int lc = (tid & 7) * 8;
  const int gk = k0 + lr;
  if (gk < Mvalid) {
    *(float4*)&t[lr][lc]     = *(const float4*)&src[(size_t)gk * NN + n0 + lc];
    *(float4*)&t[lr][lc + 4] = *(const float4*)&src[(size_t)gk * NN + n0 + lc + 4];
  } else {
    const float4 z4 = {0.f, 0.f, 0.f, 0.f};
    *(float4*)&t[lr][lc] = z4; *(float4*)&t[lr][lc + 4] = z4;
  }
  __syncthreads();
  const int on = tid >> 2;
  const int ok = (tid & 3) * 8;
  ush hv[8], lv[8];
  #pragma unroll
  for (int j = 0; j < 8; j++) {
    const float v = t[ok + j][on];
    hv[j] = bf16_rne(v); lv[j] = bf16_rne(v - bf16_f(hv[j]));
  }
  const size_t off = ((size_t)b * NN + n0 + on) * Kpad + k0 + ok;
  *(ushort4*)&Th[off] = *(ushort4*)&hv[0];
  *(ushort4*)&Th[off + 4] = *(ushort4*)&hv[4];
  *(ushort4*)&Tl[off] = *(ushort4*)&lv[0];
  *(ushort4*)&Tl[off + 4] = *(ushort4*)&lv[4];
}

// ---------- n2 from transposed splits (coalesced): n2[b,n] = sum_k y^2 ----------
__global__ void n2split_kernel(const ush* __restrict__ Yth, const ush* __restrict__ Ytl,
                               float* __restrict__ n2) {
  const int t = threadIdx.x;
  const int gid = blockIdx.x * 64 + (t >> 2);
  const int kq = (t & 3) * 72;
  const ush* ph = Yth + (size_t)gid * KPAD + kq;
  const ush* pl = Ytl + (size_t)gid * KPAD + kq;
  float s = 0.f;
  #pragma unroll
  for (int j = 0; j < 72; j += 8) {
    ushort4 h0 = *(const ushort4*)&ph[j];
    ushort4 h1 = *(const ushort4*)&ph[j + 4];
    ushort4 l0 = *(const ushort4*)&pl[j];
    ushort4 l1 = *(const ushort4*)&pl[j + 4];
    float v;
    v = bf16_f(h0.x) + bf16_f(l0.x); s += v * v;
    v = bf16_f(h0.y) + bf16_f(l0.y); s += v * v;
    v = bf16_f(h0.z) + bf16_f(l0.z); s += v * v;
    v = bf16_f(h0.w) + bf16_f(l0.w); s += v * v;
    v = bf16_f(h1.x) + bf16_f(l1.x); s += v * v;
    v = bf16_f(h1.y) + bf16_f(l1.y); s += v * v;
    v = bf16_f(h1.z) + bf16_f(l1.z); s += v * v;
    v = bf16_f(h1.w) + bf16_f(l1.w); s += v * v;
  }
  s += __shfl_xor(s, 1, 64);
  s += __shfl_xor(s, 2, 64);
  if ((t & 3) == 0) n2[gid] = s;
}

// ---------- gram v3: upper-triangle tiles + mirror writes, XCD-swizzled ----------
__global__ __launch_bounds__(256, 2)
void gram_v3_kernel(const ush* __restrict__ Yth, const ush* __restrict__ Ytl,
                    const float* __restrict__ n2, const float* __restrict__ mask,
                    ush* __restrict__ Dh, ush* __restrict__ Dl,
                    float* __restrict__ sigpart) {
  __shared__ ush lds[32768];
  // grid = 576 1D; XCD-chunked swizzle keeps each batch's 36 tiles on one XCD
  const int bid = blockIdx.x;
  const int logical = (bid & 7) * 72 + (bid >> 3);
  const int b = logical / 36;
  int t = logical - b * 36;
  int ty = 0;
  while (t >= 8 - ty) { t -= 8 - ty; ++ty; }
  const int tx = ty + t;                 // ty <= tx (upper triangle)
  const int i0 = ty * 128;
  const int j0 = tx * 128;
  const ush* Ah = Yth + (size_t)b * NN * KPAD + (size_t)i0 * KPAD;
  const ush* Al = Ytl + (size_t)b * NN * KPAD + (size_t)i0 * KPAD;
  const ush* Bh = Yth + (size_t)b * NN * KPAD + (size_t)j0 * KPAD;
  const ush* Bl = Ytl + (size_t)b * NN * KPAD + (size_t)j0 * KPAD;
  f4 acc[4][4];
  const f4 z4 = {0.f, 0.f, 0.f, 0.f};
  #pragma unroll
  for (int mi = 0; mi < 4; mi++)
    #pragma unroll
    for (int ni = 0; ni < 4; ni++) acc[mi][ni] = z4;
  stageA(Ah, Al, KPAD, Bh, Bl, KPAD, 0, lds);
  __syncthreads();
  int pb = 0;
  for (int kt = 32; kt < KPAD; kt += 32) {
    stageA(Ah, Al, KPAD, Bh, Bl, KPAD, kt, lds + (pb ^ 1) * 16384);
    computeA(lds + pb * 16384, acc);
    __syncthreads();
    pb ^= 1;
  }
  computeA(lds + pb * 16384, acc);
  __syncthreads();
  unsigned int* tl = (unsigned int*)lds;   // [128][128] swizzled, packed (h|l<<16)
  const int lane = threadIdx.x & 63;
  const int wid = threadIdx.x >> 6;
  const int wr = wid >> 1, wc = wid & 1;
  const int frow = lane & 15, hh = lane >> 4;
  const float scale = 3.0f / 257.0f;
  float lsum = 0.f;
  #pragma unroll
  for (int ni = 0; ni < 4; ni++) {
    const int jl = wc * 64 + ni * 16 + frow;
    const int j = j0 + jl;
    const float n2j = n2[b * NN + j];
    const float mkj = mask[b * NN + j];
    #pragma unroll
    for (int mi = 0; mi < 4; mi++) {
      const int il = wr * 64 + mi * 16 + hh * 4;
      unsigned int pv[4];
      #pragma unroll
      for (int r = 0; r < 4; r++) {
        const int i = i0 + il + r;
        const float D = scale * (n2[b * NN + i] + n2j - 2.0f * acc[mi][ni][r]);
        const float d = sqrtf(fmaxf(D, 1e-12f));
        const float mmv = mask[b * NN + i] * mkj;
        const float wd = d * mmv;
        lsum += wd * mmv;
        const ush h = bf16_rne(wd);
        const ush l = bf16_rne(wd - bf16_f(h));
        pv[r] = (unsigned int)h | ((unsigned int)l << 16);
      }
      const int slot = (il >> 2) ^ (jl & 31);
      *(uint4*)&tl[jl * 128 + slot * 4] = *(uint4*)pv;
    }
  }
  __syncthreads();
  // primary tile store (rows i0.., cols j0..)
  const int rrow = threadIdx.x >> 1;
  const int rch = (threadIdx.x & 1) * 64;
  const size_t obase = ((size_t)b * NN + i0 + rrow) * NN + j0 + rch;
  #pragma unroll
  for (int g = 0; g < 8; g++) {
    unsigned int hw[4], lw[4];
    #pragma unroll
    for (int q = 0; q < 4; q++) {
      unsigned int h2[2], l2[2];
      #pragma unroll
      for (int e = 0; e < 2; e++) {
        const int jl = rch + g * 8 + q * 2 + e;
        const int slot = (rrow >> 2) ^ (jl & 31);
        const unsigned int v = tl[jl * 128 + slot * 4 + (rrow & 3)];
        h2[e] = v & 0xffffu; l2[e] = v >> 16;
      }
      hw[q] = h2[0] | (h2[1] << 16);
      lw[q] = l2[0] | (l2[1] << 16);
    }
    *(uint4*)&Dh[obase + g * 8] = *(uint4*)hw;
    *(uint4*)&Dl[obase + g * 8] = *(uint4*)lw;
  }
  // mirror tile store (rows j0.., cols i0..) — D is symmetric
  if (ty != tx) {
    const int jrow = threadIdx.x >> 1;
    const int ihalf = (threadIdx.x & 1) * 64;
    const int jx = jrow & 31;
    const size_t mbase = ((size_t)b * NN + j0 + jrow) * NN + i0 + ihalf;
    #pragma unroll
    for (int c2 = 0; c2 < 8; c2++) {
      const int cc0 = (ihalf >> 2) + c2 * 2;
      const uint4 v0 = *(const uint4*)&tl[jrow * 128 + (cc0 ^ jx) * 4];
      const uint4 v1 = *(const uint4*)&tl[jrow * 128 + ((cc0 + 1) ^ jx) * 4];
      uint4 hw, lw;
      hw.x = (v0.x & 0xffffu) | (v0.y << 16);
      hw.y = (v0.z & 0xffffu) | (v0.w << 16);
      hw.z = (v1.x & 0xffffu) | (v1.y << 16);
      hw.w = (v1.z & 0xffffu) | (v1.w << 16);
      lw.x = (v0.x >> 16) | (v0.y & 0xffff0000u);
      lw.y = (v0.z >> 16) | (v0.w & 0xffff0000u);
      lw.z = (v1.x >> 16) | (v1.w << 16 >> 16 << 16 ? (v1.w & 0xffff0000u) : (v1.w & 0xffff0000u));
      lw.z = (v1.x >> 16) | (v1.y & 0xffff0000u);
      lw.w = (v1.z >> 16) | (v1.w & 0xffff0000u);
      *(uint4*)&Dh[mbase + c2 * 8] = hw;
      *(uint4*)&Dl[mbase + c2 * 8] = lw;
    }
  }
  // sigma partial (off-diagonal tiles count twice)
  if (ty != tx) lsum *= 2.0f;
  #pragma unroll
  for (int off = 32; off > 0; off >>= 1) lsum += __shfl_down(lsum, off, 64);
  __syncthreads();
  float* rbuf = (float*)lds;
  if (lane == 0) rbuf[wid] = lsum;
  __syncthreads();
  if (threadIdx.x == 0)
    sigpart[(size_t)b * 64 + ty * 8 + tx] = rbuf[0] + rbuf[1] + rbuf[2] + rbuf[3];
}

// ---------- finalize sigma -> fb = -10*msum^2/signum (upper-tri entries only) ----------
__global__ void sigfinal_kernel(const float* __restrict__ sigpart, const float* __restrict__ msum,
                                float* __restrict__ fbuf) {
  const int b = blockIdx.x;
  float v = 0.f;
  if (threadIdx.x < 64) {
    const int ty = threadIdx.x >> 3, tx = threadIdx.x & 7;
    if (ty <= tx) v = sigpart[b * 64 + threadIdx.x];
  }
  v = blockReduceSum(v);
  if (threadIdx.x == 0) { const float ms = msum[b]; fbuf[b] = -10.0f * ms * ms / v; }
}

// ---------- expw: W' = diag(rowsum) - W, split planes, in place ----------
__global__ void expw_kernel(ush* __restrict__ Wh, ush* __restrict__ Wl,
                            const float* __restrict__ mask, const float* __restrict__ fbuf) {
  const int b = blockIdx.y, n = blockIdx.x;
  const float fb = fbuf[b];
  const float mn = mask[b * NN + n];
  const size_t roff = ((size_t)b * NN + n) * NN;
  const int t = threadIdx.x;
  const float4 mk = ((const float4*)(mask + b * NN))[t];
  ushort4 dh = *(ushort4*)&Wh[roff + t * 4];
  ushort4 dl = *(ushort4*)&Wl[roff + t * 4];
  float w0 = expf(fb * (bf16_f(dh.x) + bf16_f(dl.x))) * mn * mk.x;
  float w1 = expf(fb * (bf16_f(dh.y) + bf16_f(dl.y))) * mn * mk.y;
  float w2 = expf(fb * (bf16_f(dh.z) + bf16_f(dl.z))) * mn * mk.z;
  float w3 = expf(fb * (bf16_f(dh.w) + bf16_f(dl.w))) * mn * mk.w;
  float s = blockReduceSum(w0 + w1 + w2 + w3);
  float v0 = -w0, v1 = -w1, v2 = -w2, v3 = -w3;
  if ((n >> 2) == t) {
    const int r = n & 3;
    if (r == 0) v0 += s; else if (r == 1) v1 += s; else if (r == 2) v2 += s; else v3 += s;
  }
  ushort4 h4, l4;
  h4.x = bf16_rne(v0); l4.x = bf16_rne(v0 - bf16_f(h4.x));
  h4.y = bf16_rne(v1); l4.y = bf16_rne(v1 - bf16_f(h4.y));
  h4.z = bf16_rne(v2); l4.z = bf16_rne(v2 - bf16_f(h4.z));
  h4.w = bf16_rne(v3); l4.w = bf16_rne(v3 - bf16_f(h4.w));
  *(ushort4*)&Wh[roff + t * 4] = h4;
  *(ushort4*)&Wl[roff + t * 4] = l4;
}

// ---------- cvall: C[g] = Kis[g]*(W[g]@X)*mask; XCD-swizzled 1D grid (768) ----------
__global__ __launch_bounds__(256, 2)
void cvall_kernel(const ush* __restrict__ Amh, const ush* __restrict__ Aml,
                  const ush* __restrict__ Bth, const ush* __restrict__ Btl,
                  const float* __restrict__ mask, const float* __restrict__ Kis,
                  unsigned int* __restrict__ Cpack, ush* __restrict__ C2h,
                  ush* __restrict__ C2l) {
  __shared__ ush lds[32768];
  const int bid = blockIdx.x;
  const int logical = (bid & 7) * 96 + (bid >> 3);
  const int b = logical / 48;
  const int inner = logical - b * 48;
  const int c0g = inner & 7;
  const int r0g = inner >> 3;              // 0..5
  const int r0 = r0g * 128;
  const int c0 = c0g * 128;
  const ush* Ah = Amh + (size_t)r0 * CH;
  const ush* Al = Aml + (size_t)r0 * CH;
  const ush* Bh = Bth + (size_t)b * NN * CH + (size_t)c0 * CH;
  const ush* Bl = Btl + (size_t)b * NN * CH + (size_t)c0 * CH;
  f4 acc[4][4];
  const f4 z4 = {0.f, 0.f, 0.f, 0.f};
  #pragma unroll
  for (int mi = 0; mi < 4; mi++)
    #pragma unroll
    for (int ni = 0; ni < 4; ni++) acc[mi][ni] = z4;
  stageA(Ah, Al, CH, Bh, Bl, CH, 0, lds);
  __syncthreads();
  int pb = 0;
  for (int kt = 32; kt < CH; kt += 32) {
    stageA(Ah, Al, CH, Bh, Bl, CH, kt, lds + (pb ^ 1) * 16384);
    computeA(lds + pb * 16384, acc);
    __syncthreads();
    pb ^= 1;
  }
  computeA(lds + pb * 16384, acc);
  __syncthreads();
  unsigned int* tl = (unsigned int*)lds;
  const int lane = threadIdx.x & 63;
  const int wid = threadIdx.x >> 6;
  const int wr = wid >> 1, wc = wid & 1;
  const int frow = lane & 15, hh = lane >> 4;
  const float alpha = Kis[r0g >> 1];
  #pragma unroll
  for (int ni = 0; ni < 4; ni++) {
    const int jl = wc * 64 + ni * 16 + frow;
    const float am = alpha * mask[b * NN + c0 + jl];
    #pragma unroll
    for (int mi = 0; mi < 4; mi++) {
      const int il = wr * 64 + mi * 16 + hh * 4;
      unsigned int pv[4];
      #pragma unroll
      for (int r = 0; r < 4; r++) {
        const float v = acc[mi][ni][r] * am;
        const ush h = bf16_rne(v);
        const ush l = bf16_rne(v - bf16_f(h));
        pv[r] = (unsigned int)h | ((unsigned int)l << 16);
      }
      const int slot = (il >> 2) ^ (jl & 31);
      *(uint4*)&tl[jl * 128 + slot * 4] = *(uint4*)pv;
    }
  }
  __syncthreads();
  const int rrow = threadIdx.x >> 1;
  const int rch = (threadIdx.x & 1) * 64;
  if (r0g < 4) {
    unsigned int* dst = Cpack + ((size_t)b * 512 + r0 + rrow) * NN + c0 + rch;
    #pragma unroll
    for (int g = 0; g < 16; g++) {
      unsigned int pw[4];
      #pragma unroll
      for (int q = 0; q < 4; q++) {
        const int jl = rch + g * 4 + q;
        const int slot = (rrow >> 2) ^ (jl & 31);
        pw[q] = tl[jl * 128 + slot * 4 + (rrow & 3)];
      }
      *(uint4*)&dst[g * 4] = *(uint4*)pw;
    }
  } else {
    const size_t obase = ((size_t)b * 256 + (r0 - 512) + rrow) * NN + c0 + rch;
    #pragma unroll
    for (int g = 0; g < 8; g++) {
      unsigned int hw[4], lw[4];
      #pragma unroll
      for (int q = 0; q < 4; q++) {
        unsigned int h2[2], l2[2];
        #pragma unroll
        for (int e = 0; e < 2; e++) {
          const int jl = rch + g * 8 + q * 2 + e;
          const int slot = (rrow >> 2) ^ (jl & 31);
          const unsigned int v = tl[jl * 128 + slot * 4 + (rrow & 3)];
          h2[e] = v & 0xffffu; l2[e] = v >> 16;
        }
        hw[q] = h2[0] | (h2[1] << 16);
        lw[q] = l2[0] | (l2[1] << 16);
      }
      *(uint4*)&C2h[obase + g * 8] = *(uint4*)hw;
      *(uint4*)&C2l[obase + g * 8] = *(uint4*)lw;
    }
  }
}

// ---------- mm1 v3: out = X@W' + add(packed). 64x128 dbuf, XCD-swizzled (512) ----------
// OUTMODE 0: planar split out (LDS transpose); 1: fp32; 2: outF = zin - 0.01*out
template <int OUTMODE>
__global__ __launch_bounds__(256, 3)
void mm1_v3_kernel(const ush* __restrict__ Xh, const ush* __restrict__ Xl, const size_t xStride,
                   const ush* __restrict__ Wh, const ush* __restrict__ Wl,
                   const unsigned int* __restrict__ addp, const size_t aStride,
                   const float* __restrict__ zin, float* __restrict__ outF,
                   ush* __restrict__ outH, ush* __restrict__ outL) {
  __shared__ ush lds[24576];
  const int bid = blockIdx.x;
  const int logical = (bid & 7) * 64 + (bid >> 3);
  const int b = logical >> 5;
  const int inner = logical & 31;
  const int n0 = (inner & 7) * 128;
  const int r0 = (inner >> 3) * 64;
  const ush* Ah = Xh + (size_t)b * xStride + (size_t)r0 * NN;
  const ush* Al = Xl + (size_t)b * xStride + (size_t)r0 * NN;
  const ush* Bh = Wh + (size_t)b * NN * NN + (size_t)n0 * NN;
  const ush* Bl = Wl + (size_t)b * NN * NN + (size_t)n0 * NN;
  f4 acc[4][2];
  const f4 z4 = {0.f, 0.f, 0.f, 0.f};
  #pragma unroll
  for (int mi = 0; mi < 4; mi++) { acc[mi][0] = z4; acc[mi][1] = z4; }
  stageB(Ah, Al, NN, Bh, Bl, NN, 0, lds);
  __syncthreads();
  int pb = 0;
  for (int kt = 32; kt < NN; kt += 32) {
    stageB(Ah, Al, NN, Bh, Bl, NN, kt, lds + (pb ^ 1) * 12288);
    computeB(lds + pb * 12288, acc);
    __syncthreads();
    pb ^= 1;
  }
  computeB(lds + pb * 12288, acc);
  const int lane = threadIdx.x & 63;
  const int wid = threadIdx.x >> 6;
  const int frow = lane & 15, hh = lane >> 4;
  if (OUTMODE == 0) {
    __syncthreads();
    unsigned int* tl = (unsigned int*)lds;   // [128][64] swizzled
    #pragma unroll
    for (int ni = 0; ni < 2; ni++) {
      const int jl = wid * 32 + ni * 16 + frow;
      const int col = n0 + jl;
      #pragma unroll
      for (int mi = 0; mi < 4; mi++) {
        const int il = mi * 16 + hh * 4;
        unsigned int pv[4];
        #pragma unroll
        for (int r = 0; r < 4; r++) {
          const int row = r0 + il + r;
          const unsigned int av = addp[(size_t)b * aStride + (size_t)row * NN + col];
          const float o = acc[mi][ni][r] + bf16_f((ush)(av & 0xffffu)) + bf16_f((ush)(av >> 16));
          const ush h = bf16_rne(o);
          const ush l = bf16_rne(o - bf16_f(h));
          pv[r] = (unsigned int)h | ((unsigned int)l << 16);
        }
        const int slot = (il >> 2) ^ (jl & 15);
        *(uint4*)&tl[jl * 64 + slot * 4] = *(uint4*)pv;
      }
    }
    __syncthreads();
    const int rrow = threadIdx.x >> 2;
    const int rch = (threadIdx.x & 3) * 32;
    const size_t obase = ((size_t)b * 256 + r0 + rrow) * NN + n0 + rch;
    #pragma unroll
    for (int g = 0; g < 4; g++) {
      unsigned int hw[4], lw[4];
      #pragma unroll
      for (int q = 0; q < 4; q++) {
        unsigned int h2[2], l2[2];
        #pragma unroll
        for (int e = 0; e < 2; e++) {
          const int jl = rch + g * 8 + q * 2 + e;
          const int slot = (rrow >> 2) ^ (jl & 15);
          const unsigned int v = tl[jl * 64 + slot * 4 + (rrow & 3)];
          h2[e] = v & 0xffffu; l2[e] = v >> 16;
        }
        hw[q] = h2[0] | (h2[1] << 16);
        lw[q] = l2[0] | (l2[1] << 16);
      }
      *(uint4*)&outH[obase + g * 8] = *(uint4*)hw;
      *(uint4*)&outL[obase + g * 8] = *(uint4*)lw;
    }
  } else {
    #pragma unroll
    for (int ni = 0; ni < 2; ni++) {
      const int col = n0 + wid * 32 + ni * 16 + frow;
      #pragma unroll
      for (int mi = 0; mi < 4; mi++) {
        #pragma unroll
        for (int r = 0; r < 4; r++) {
          const int row = r0 + mi * 16 + hh * 4 + r;
          const unsigned int av = addp[(size_t)b * aStride + (size_t)row * NN + col];
          const float o = acc[mi][ni][r] + bf16_f((ush)(av & 0xffffu)) + bf16_f((ush)(av >> 16));
          const size_t ooff = (size_t)b * CH * NN + (size_t)row * NN + col;
          if (OUTMODE == 1) outF[ooff] = o;
          else outF[ooff] = zin[ooff] - 0.01f * o;
        }
      }
    }
  }
}

// ---------- rmean[b][c] = sum(U*mask)/msum ----------
__global__ void rmean_kernel(const float* __restrict__ U, const float* __restrict__ mask,
                             const float* __restrict__ msum, float* __restrict__ rmean) {
  const int b = blockIdx.y, c = blockIdx.x;
  const float* row = U + ((size_t)b * CH + c) * NN;
  const float* mrow = mask + b * NN;
  float s = 0.f;
  #pragma unroll
  for (int j = 0; j < 4; j++) { const int n = threadIdx.x + j * 256; s += row[n] * mrow[n]; }
  s = blockReduceSum(s);
  if (threadIdx.x == 0) rmean[b * CH + c] = s / msum[b];
}

// ---------- csq: partial col sums of ((U-rmean)*mask)^2, 16 c-rows per block ----------
__global__ void csq_kernel(const float* __restrict__ U, const float* __restrict__ mask,
                           const float* __restrict__ rmean, float* __restrict__ part) {
  const int b = blockIdx.y, cc = blockIdx.x;
  const int n = threadIdx.x * 4;
  const float4 m4 = *(const float4*)&mask[b * NN + n];
  float4 s4 = {0.f, 0.f, 0.f, 0.f};
  for (int r = 0; r < 16; r++) {
    const int c = cc * 16 + r;
    const float rm = rmean[b * CH + c];
    const float4 u4 = *(const float4*)&U[((size_t)b * CH + c) * NN + n];
    float a;
    a = (u4.x - rm) * m4.x; s4.x += a * a;
    a = (u4.y - rm) * m4.y; s4.y += a * a;
    a = (u4.z - rm) * m4.z; s4.z += a * a;
    a = (u4.w - rm) * m4.w; s4.w += a * a;
  }
  *(float4*)&part[((size_t)(b * 16 + cc)) * NN + n] = s4;
}

__global__ void csq2_kernel(const float* __restrict__ part, float* __restrict__ rs) {
  const int b = blockIdx.y;
  const int n = blockIdx.x * 256 + threadIdx.x;
  float s = 0.001f;
  #pragma unroll
  for (int cc = 0; cc < 16; cc++) s += part[((size_t)(b * 16 + cc)) * NN + n];
  rs[b * NN + n] = 1.0f / sqrtf(s);
}

// ---------- fused: A=(U-rmean)*mask; out = relu(A*rs) transposed splits ----------
__global__ void tsplitN_kernel(const float* __restrict__ U, const float* __restrict__ mask,
                               const float* __restrict__ rmean, const float* __restrict__ rs,
                               ush* __restrict__ Th, ush* __restrict__ Tl) {
  __shared__ float t[32][65];
  const int b = blockIdx.z;
  const int n0 = blockIdx.x * 64;
  const int k0 = blockIdx.y * 32;
  const int tid = threadIdx.x;
  const int lr = tid >> 3;
  const int lc = (tid & 7) * 8;
  const int gc = k0 + lr;
  const float rm = rmean[b * CH + gc];
  const float4 ma = *(const float4*)&mask[b * NN + n0 + lc];
  const float4 mb = *(const float4*)&mask[b * NN + n0 + lc + 4];
  const float4 ra = *(const float4*)&rs[b * NN + n0 + lc];
  const float4 rb = *(const float4*)&rs[b * NN + n0 + lc + 4];
  const float4 ua = *(const float4*)&U[((size_t)b * CH + gc) * NN + n0 + lc];
  const float4 ub = *(const float4*)&U[((size_t)b * CH + gc) * NN + n0 + lc + 4];
  t[lr][lc + 0] = fmaxf((ua.x - rm) * ma.x * ra.x, 0.f);
  t[lr][lc + 1] = fmaxf((ua.y - rm) * ma.y * ra.y, 0.f);
  t[lr][lc + 2] = fmaxf((ua.z - rm) * ma.z * ra.z, 0.f);
  t[lr][lc + 3] = fmaxf((ua.w - rm) * ma.w * ra.w, 0.f);
  t[lr][lc + 4] = fmaxf((ub.x - rm) * mb.x * rb.x, 0.f);
  t[lr][lc + 5] = fmaxf((ub.y - rm) * mb.y * rb.y, 0.f);
  t[lr][lc + 6] = fmaxf((ub.z - rm) * mb.z * rb.z, 0.f);
  t[lr][lc + 7] = fmaxf((ub.w - rm) * mb.w * rb.w, 0.f);
  __syncthreads();
  const int on = tid >> 2;
  const int ok = (tid & 3) * 8;
  ush hv[8], lv[8];
  #pragma unroll
  for (int j = 0; j < 8; j++) {
    const float v = t[ok + j][on];
    hv[j] = bf16_rne(v); lv[j] = bf16_rne(v - bf16_f(hv[j]));
  }
  const size_t off = ((size_t)b * NN + n0 + on) * CH + k0 + ok;
  *(ushort4*)&Th[off] = *(ushort4*)&hv[0];
  *(ushort4*)&Th[off + 4] = *(ushort4*)&hv[4];
  *(ushort4*)&Tl[off] = *(ushort4*)&lv[0];
  *(ushort4*)&Tl[off + 4] = *(ushort4*)&lv[4];
}

// ---------- Zout = (Wend @ Z)*mask; write + centered copy ----------
__global__ void zout_kernel(const float* __restrict__ Z, const float* __restrict__ Wend,
                            const float* __restrict__ mask, float* __restrict__ outZ,
                            float* __restrict__ Zcent) {
  const int b = blockIdx.x;
  __shared__ float w[3 * CH];
  for (int i = threadIdx.x; i < 3 * CH; i += 256) w[i] = Wend[i];
  __syncthreads();
  float a[3][4];
  #pragma unroll
  for (int j = 0; j < 4; j++) { a[0][j] = 0.f; a[1][j] = 0.f; a[2][j] = 0.f; }
  const float* Zb = Z + (size_t)b * CH * NN;
  for (int c = 0; c < CH; c++) {
    const float w0 = w[c], w1 = w[CH + c], w2 = w[2 * CH + c];
    #pragma unroll
    for (int j = 0; j < 4; j++) {
      float zv = Zb[(size_t)c * NN + threadIdx.x + j * 256];
      a[0][j] += w0 * zv; a[1][j] += w1 * zv; a[2][j] += w2 * zv;
    }
  }
  float sum[3] = {0.f, 0.f, 0.f};
  #pragma unroll
  for (int j = 0; j < 4; j++) {
    const int n = threadIdx.x + j * 256;
    const float mv = mask[b * NN + n];
    #pragma unroll
    for (int o = 0; o < 3; o++) {
      a[o][j] *= mv;
      outZ[((size_t)b * 3 + o) * NN + n] = a[o][j];
      sum[o] += a[o][j];
    }
  }
  for (int o = 0; o < 3; o++) {
    float s = blockReduceSum(sum[o]);
    const float mean = s * (1.0f / NN);
    #pragma unroll
    for (int j = 0; j < 4; j++) {
      const int n = threadIdx.x + j * 256;
      Zcent[((size_t)b * 3 + o) * NN + n] = a[o][j] - mean;
    }
  }
}

// ---------- final distances ----------
__global__ void dist_kernel(const float* __restrict__ Zcent, float* __restrict__ outD) {
  const int b = blockIdx.z;
  const int n = blockIdx.y;
  const int m = blockIdx.x * 256 + threadIdx.x;
  const float* Zb = Zcent + (size_t)b * 3 * NN;
  const float x0 = Zb[n], x1 = Zb[NN + n], x2 = Zb[2 * NN + n];
  const float d0 = x0 - Zb[m], d1 = x1 - Zb[NN + m], d2 = x2 - Zb[2 * NN + m];
  const float D = d0 * d0 + d1 * d1 + d2 * d2;
  outD[((size_t)b * NN + n) * NN + m] = sqrtf(fmaxf(D, 1e-12f));
}

extern "C" void kernel_launch(void* const* d_in, const int* in_sizes, int n_in,
                              void* d_out, int out_size, void* d_ws, size_t ws_size,
                              hipStream_t stream) {
  const float* Zin  = (const float*)d_in[0];
  const float* mask = (const float*)d_in[1];
  const float* K0   = (const float*)d_in[2];
  const float* Knet = (const float*)d_in[3];
  const float* W    = (const float*)d_in[4];
  const float* Wend = (const float*)d_in[5];
  float* out = (float*)d_out;

  ush* Whb = (ush*)out;                           // BB*NN*NN (dist splits -> W')
  ush* Wlb = Whb + (size_t)BB * NN * NN;
  float* outZ = out + (size_t)BB * NN * NN;

  float* p = (float*)d_ws;
  // union: gram phase {Y fp32 | Yth | Ytl}; GEMM phase {Cpack u32 | C2h | C2l}
  float* uni = p; p += (size_t)BB * 768 * NN;     // 50.33 MB
  float* Y = uni;
  ush* Yth = (ush*)(uni + (size_t)BB * KP * NN);
  ush* Ytl = Yth + (size_t)BB * NN * KPAD;
  unsigned int* Cpack = (unsigned int*)uni;       // BB*512*NN u32
  ush* C2h = (ush*)(uni + (size_t)BB * 512 * NN); // BB*256*NN
  ush* C2l = C2h + (size_t)BB * 256 * NN;

  float* Zcur = p; p += (size_t)BB * CH * NN;
  float* U    = p; p += (size_t)BB * CH * NN;
  ush* Zth = (ush*)p; p += (size_t)BB * NN * CH / 2;
  ush* Ztl = (ush*)p; p += (size_t)BB * NN * CH / 2;
  ush* Thb = Zth;   // alias: Zth dead after cvall; T dead before tsplitN
  ush* Tlb = Ztl;
  ush* Wmh = (ush*)p; p += (size_t)18 * CH * CH / 2;
  ush* Wml = (ush*)p; p += (size_t)18 * CH * CH / 2;
  ush* Wth = (ush*)p; p += (size_t)18 * CH * CH / 2;
  ush* Wtl = (ush*)p; p += (size_t)18 * CH * CH / 2;
  float* n2b   = p; p += BB * NN;
  float* rsb   = p; p += BB * NN;
  float* msum  = p; p += BB;
  float* sigp  = p; p += BB * 64;
  float* fbuf  = p; p += BB;
  float* rmeanb= p; p += BB * CH;
  float* partb = p; p += (size_t)BB * 16 * NN;
  float* Zcent = p; p += BB * 3 * NN;

  const dim3 gtsZ(NN / 64, CH / 32, BB);
  const dim3 gtsY(NN / 64, KPAD / 32, BB);
  const size_t sC = (size_t)512 * NN;         // Cpack batch stride
  const size_t sT = (size_t)CH * NN;

  masksum_kernel<<<BB, 256, 0, stream>>>(mask, msum);
  wprep_kernel<<<dim3(16, 18), 256, 0, stream>>>(W, Wmh, Wml, Wth, Wtl);
  k0_kernel<<<dim3(CH, BB), 256, 0, stream>>>(Zin, K0, mask, Zcur);

  for (int layer = 0; layer < NLAYERS; layer++) {
    rownorm_kernel<<<dim3(KROWS, BB), 256, 0, stream>>>(Zcur, mask, msum, Y);
    tsplit_kernel<<<gtsY, 256, 0, stream>>>(Y, KP * NN, KROWS, Yth, Ytl, KPAD);
    n2split_kernel<<<BB * NN / 64, 256, 0, stream>>>(Yth, Ytl, n2b);
    gram_v3_kernel<<<576, 256, 0, stream>>>(Yth, Ytl, n2b, mask, Whb, Wlb, sigp);
    sigfinal_kernel<<<BB, 256, 0, stream>>>(sigp, msum, fbuf);
    expw_kernel<<<dim3(NN, BB), 256, 0, stream>>>(Whb, Wlb, mask, fbuf);
    tsplit_kernel<<<gtsZ, 256, 0, stream>>>(Zcur, CH * NN, CH, Zth, Ztl, CH);

    const ush* Amh = Wmh + (size_t)layer * 3 * CH * CH;
    const ush* Aml = Wml + (size_t)layer * 3 * CH * CH;
    const ush* Ath = Wth + (size_t)layer * 3 * CH * CH;
    const ush* Atl = Wtl + (size_t)layer * 3 * CH * CH;
    const float* Ki = Knet + layer * 3;

    // ---- Ai = C0 + (C1 + C2@L)@L, C = Ki*(Wi@Z)*mask, L rows = W' ----
    cvall_kernel<<<768, 256, 0, stream>>>(Amh, Aml, Zth, Ztl, mask, Ki, Cpack, C2h, C2l);
    mm1_v3_kernel<0><<<512, 256, 0, stream>>>(C2h, C2l, sT, Whb, Wlb,
        Cpack + (size_t)256 * NN, sC, nullptr, nullptr, Thb, Tlb);
    mm1_v3_kernel<1><<<512, 256, 0, stream>>>(Thb, Tlb, sT, Whb, Wlb,
        Cpack, sC, nullptr, U, nullptr, nullptr);

    rmean_kernel<<<dim3(CH, BB), 256, 0, stream>>>(U, mask, msum, rmeanb);
    csq_kernel<<<dim3(16, BB), 256, 0, stream>>>(U, mask, rmeanb, partb);
    csq2_kernel<<<dim3(NN / 256, BB), 256, 0, stream>>>(partb, rsb);
    tsplitN_kernel<<<gtsZ, 256, 0, stream>>>(U, mask, rmeanb, rsb, Zth, Ztl);

    // ---- Z -= 0.01 * (C0 + (C1 + C2@L)@L), C = Ki*(Wi^T@A)*mask ----
    cvall_kernel<<<768, 256, 0, stream>>>(Ath, Atl, Zth, Ztl, mask, Ki, Cpack, C2h, C2l);
    mm1_v3_kernel<0><<<512, 256, 0, stream>>>(C2h, C2l, sT, Whb, Wlb,
        Cpack + (size_t)256 * NN, sC, nullptr, nullptr, Thb, Tlb);
    mm1_v3_kernel<2><<<512, 256, 0, stream>>>(Thb, Tlb, sT, Whb, Wlb,
        Cpack, sC, Zcur, Zcur, nullptr, nullptr);
  }

  zout_kernel<<<BB, 256, 0, stream>>>(Zcur, Wend, mask, outZ, Zcent);
  dist_kernel<<<dim3(NN / 256, NN, BB), 256, 0, stream>>>(Zcent, out);
}

// Round 7
// 2129.561 us; speedup vs baseline: 2.6954x; 1.0621x over previous
//
#include <hip/hip_runtime.h>
#include <hip/hip_fp16.h>
#include <math.h>

#define BB 16
#define CIN 40
#define CH 256
#define NN 1024
#define KROWS 257
#define KPAD 288        // gram K padded to 9*32
#define NLAYERS 6

typedef unsigned short ush;
typedef __attribute__((ext_vector_type(8))) short bh8;
typedef __attribute__((ext_vector_type(4))) float f4;

__device__ __forceinline__ ush bf16_rne(float x) {
  unsigned int u = __float_as_uint(x);
  u += 0x7fffu + ((u >> 16) & 1u);
  return (ush)(u >> 16);
}
__device__ __forceinline__ float bf16_f(ush h) {
  return __uint_as_float(((unsigned int)h) << 16);
}
__device__ __forceinline__ ush f2h(float x) {
  __half h = __float2half(x);
  return *(ush*)&h;
}
__device__ __forceinline__ float h2f(ush u) {
  __half h = *(__half*)&u;
  return __half2float(h);
}

#define GLD16(gp, lp) __builtin_amdgcn_global_load_lds( \
    (const __attribute__((address_space(1))) void*)(gp), \
    (__attribute__((address_space(3))) void*)(lp), 16, 0, 0)

// ---------- block reduction (256 threads = 4 waves) ----------
__device__ __forceinline__ float blockReduceSum(float v) {
  __shared__ float sred[4];
  const int lane = threadIdx.x & 63;
  const int wid  = threadIdx.x >> 6;
  #pragma unroll
  for (int off = 32; off > 0; off >>= 1) v += __shfl_down(v, off, 64);
  __syncthreads();
  if (lane == 0) sred[wid] = v;
  __syncthreads();
  return sred[0] + sred[1] + sred[2] + sred[3];
}

// ================= core A: 128x128 tile, BK=32, double-buffered =================
__device__ __forceinline__ void stageA(
    const ush* __restrict__ Ah, const ush* __restrict__ Al, const int sA,
    const ush* __restrict__ Bh, const ush* __restrict__ Bl, const int sB,
    const int kt, ush* buf) {
  const int lane = threadIdx.x & 63;
  const int wid = threadIdx.x >> 6;
  const int srow = lane >> 2;
  const int sl = (lane & 3) ^ ((srow >> 1) & 3);
  #pragma unroll
  for (int cc = 0; cc < 8; cc++) {
    const int c = wid * 8 + cc;
    const ush* src;
    if (c < 8)       src = Ah + (size_t)(c * 16 + srow) * sA + kt + sl * 8;
    else if (c < 16) src = Al + (size_t)((c - 8) * 16 + srow) * sA + kt + sl * 8;
    else if (c < 24) src = Bh + (size_t)((c - 16) * 16 + srow) * sB + kt + sl * 8;
    else             src = Bl + (size_t)((c - 24) * 16 + srow) * sB + kt + sl * 8;
    GLD16(src, buf + c * 512 + lane * 8);
  }
}

__device__ __forceinline__ void computeA(const ush* buf, f4 acc[4][4]) {
  const int lane = threadIdx.x & 63;
  const int wid = threadIdx.x >> 6;
  const int wr = wid >> 1, wc = wid & 1;
  const int frow = lane & 15;
  const int slot8 = (((lane >> 4) ^ ((frow >> 1) & 3)) << 3);
  bh8 ah[4], al[4], bh_[4], bl_[4];
  #pragma unroll
  for (int mi = 0; mi < 4; mi++) {
    const int off = (wr * 64 + mi * 16 + frow) * 32 + slot8;
    ah[mi] = *(const bh8*)&buf[off];
    al[mi] = *(const bh8*)&buf[4096 + off];
  }
  #pragma unroll
  for (int ni = 0; ni < 4; ni++) {
    const int off = (wc * 64 + ni * 16 + frow) * 32 + slot8;
    bh_[ni] = *(const bh8*)&buf[8192 + off];
    bl_[ni] = *(const bh8*)&buf[12288 + off];
  }
  #pragma unroll
  for (int mi = 0; mi < 4; mi++)
    #pragma unroll
    for (int ni = 0; ni < 4; ni++) {
      acc[mi][ni] = __builtin_amdgcn_mfma_f32_16x16x32_bf16(ah[mi], bh_[ni], acc[mi][ni], 0, 0, 0);
      acc[mi][ni] = __builtin_amdgcn_mfma_f32_16x16x32_bf16(ah[mi], bl_[ni], acc[mi][ni], 0, 0, 0);
      acc[mi][ni] = __builtin_amdgcn_mfma_f32_16x16x32_bf16(al[mi], bh_[ni], acc[mi][ni], 0, 0, 0);
    }
}

// ================= core B: 64x128 tile, BK=32, double-buffered =================
__device__ __forceinline__ void stageB(
    const ush* __restrict__ Ah, const ush* __restrict__ Al, const int sA,
    const ush* __restrict__ Bh, const ush* __restrict__ Bl, const int sB,
    const int kt, ush* buf) {
  const int lane = threadIdx.x & 63;
  const int wid = threadIdx.x >> 6;
  const int srow = lane >> 2;
  const int sl = (lane & 3) ^ ((srow >> 1) & 3);
  #pragma unroll
  for (int cc = 0; cc < 6; cc++) {
    const int c = wid * 6 + cc;
    const ush* src;
    if (c < 4)       src = Ah + (size_t)(c * 16 + srow) * sA + kt + sl * 8;
    else if (c < 8)  src = Al + (size_t)((c - 4) * 16 + srow) * sA + kt + sl * 8;
    else if (c < 16) src = Bh + (size_t)((c - 8) * 16 + srow) * sB + kt + sl * 8;
    else             src = Bl + (size_t)((c - 16) * 16 + srow) * sB + kt + sl * 8;
    GLD16(src, buf + c * 512 + lane * 8);
  }
}

__device__ __forceinline__ void computeB(const ush* buf, f4 acc[4][2]) {
  const int lane = threadIdx.x & 63;
  const int wid = threadIdx.x >> 6;
  const int frow = lane & 15;
  const int slot8 = (((lane >> 4) ^ ((frow >> 1) & 3)) << 3);
  bh8 ah[4], al[4], bh_[2], bl_[2];
  #pragma unroll
  for (int mi = 0; mi < 4; mi++) {
    const int off = (mi * 16 + frow) * 32 + slot8;
    ah[mi] = *(const bh8*)&buf[off];
    al[mi] = *(const bh8*)&buf[2048 + off];
  }
  #pragma unroll
  for (int ni = 0; ni < 2; ni++) {
    const int off = (wid * 32 + ni * 16 + frow) * 32 + slot8;
    bh_[ni] = *(const bh8*)&buf[4096 + off];
    bl_[ni] = *(const bh8*)&buf[8192 + off];
  }
  #pragma unroll
  for (int mi = 0; mi < 4; mi++)
    #pragma unroll
    for (int ni = 0; ni < 2; ni++) {
      acc[mi][ni] = __builtin_amdgcn_mfma_f32_16x16x32_bf16(ah[mi], bh_[ni], acc[mi][ni], 0, 0, 0);
      acc[mi][ni] = __builtin_amdgcn_mfma_f32_16x16x32_bf16(ah[mi], bl_[ni], acc[mi][ni], 0, 0, 0);
      acc[mi][ni] = __builtin_amdgcn_mfma_f32_16x16x32_bf16(al[mi], bh_[ni], acc[mi][ni], 0, 0, 0);
    }
}

// ---------- Z0 = tanh(K0 @ Zin) * mask  (+ row stats S1,S2) ----------
__global__ void k0_kernel(const float* __restrict__ Zin, const float* __restrict__ K0,
                          const float* __restrict__ mask, float* __restrict__ Zc,
                          float* __restrict__ statS1, float* __restrict__ statS2) {
  const int b = blockIdx.y;
  const int o = blockIdx.x;
  __shared__ float w[CIN];
  if (threadIdx.x < CIN) w[threadIdx.x] = K0[o * CIN + threadIdx.x];
  __syncthreads();
  float s1 = 0.f, s2 = 0.f;
  for (int n = threadIdx.x; n < NN; n += 256) {
    float acc = 0.f;
    #pragma unroll
    for (int c = 0; c < CIN; c++) acc += w[c] * Zin[((size_t)b * CIN + c) * NN + n];
    const float z = tanhf(acc) * mask[b * NN + n];
    Zc[((size_t)b * CH + o) * NN + n] = z;
    s1 += z; s2 += z * z;
  }
  s1 = blockReduceSum(s1);
  s2 = blockReduceSum(s2);
  if (threadIdx.x == 0) {
    const size_t base = ((size_t)b * CH + o) * 8;
    statS1[base] = s1; statS2[base] = s2;
    #pragma unroll
    for (int k = 1; k < 8; k++) { statS1[base + k] = 0.f; statS2[base + k] = 0.f; }
  }
}

// ---------- masksum + pos-row mean (mask-only, computed once) ----------
__global__ void masksum_kernel(const float* __restrict__ mask, float* __restrict__ msum,
                               float* __restrict__ pmpos) {
  const int b = blockIdx.x;
  float v = 0.f, p = 0.f;
  for (int n = threadIdx.x; n < NN; n += 256) {
    const float m = mask[b * NN + n];
    v += m;
    p += 0.5f * ((float)n * (1.0f / (NN - 1))) * m;
  }
  v = blockReduceSum(v);
  p = blockReduceSum(p);
  if (threadIdx.x == 0) { msum[b] = v; pmpos[b] = p * (1.0f / NN); }
}

// ---------- W prep: split-bf16 of W and W^T for all 18 matrices ----------
__global__ void wprep_kernel(const float* __restrict__ W, ush* __restrict__ Wmh,
                             ush* __restrict__ Wml, ush* __restrict__ Wth,
                             ush* __restrict__ Wtl) {
  __shared__ float t[64][65];
  const int mat = blockIdx.y;
  const int ty = blockIdx.x >> 2, tx = blockIdx.x & 3;
  const float* src = W + (size_t)mat * CH * CH;
  const int tid = threadIdx.x;
  const int lr = tid >> 2;
  const int lc = (tid & 3) * 16;
  float v[16];
  #pragma unroll
  for (int j = 0; j < 16; j += 4)
    *(float4*)&v[j] = *(const float4*)&src[(size_t)(ty * 64 + lr) * CH + tx * 64 + lc + j];
  ush hv[16], lv[16];
  #pragma unroll
  for (int j = 0; j < 16; j++) {
    hv[j] = bf16_rne(v[j]); lv[j] = bf16_rne(v[j] - bf16_f(hv[j]));
    t[lr][lc + j] = v[j];
  }
  const size_t offm = (size_t)mat * CH * CH + (size_t)(ty * 64 + lr) * CH + tx * 64 + lc;
  #pragma unroll
  for (int j = 0; j < 16; j += 4) {
    *(ushort4*)&Wmh[offm + j] = *(ushort4*)&hv[j];
    *(ushort4*)&Wml[offm + j] = *(ushort4*)&lv[j];
  }
  __syncthreads();
  #pragma unroll
  for (int j = 0; j < 16; j++) {
    const float w = t[lc + j][lr];
    hv[j] = bf16_rne(w); lv[j] = bf16_rne(w - bf16_f(hv[j]));
  }
  const size_t offt = (size_t)mat * CH * CH + (size_t)(tx * 64 + lr) * CH + ty * 64 + lc;
  #pragma unroll
  for (int j = 0; j < 16; j += 4) {
    *(ushort4*)&Wth[offt + j] = *(ushort4*)&hv[j];
    *(ushort4*)&Wtl[offt + j] = *(ushort4*)&lv[j];
  }
}

// ---------- row stats -> mu, rs (Z normalization) ----------
__global__ void rowstatZ_kernel(const float* __restrict__ statS1, const float* __restrict__ statS2,
                                const float* __restrict__ msum, float* __restrict__ muZ,
                                float* __restrict__ rsZ) {
  const int b = blockIdx.x;
  const int c = threadIdx.x;
  const size_t base = ((size_t)b * CH + c) * 8;
  float S1 = 0.f, S2 = 0.f;
  #pragma unroll
  for (int k = 0; k < 8; k++) { S1 += statS1[base + k]; S2 += statS2[base + k]; }
  const float M = msum[b];
  const float mu = S1 / M;
  const float q = fmaxf(S2 - mu * S1, 0.f);    // S2 - 2 mu S1 + mu^2 M = S2 - mu S1
  muZ[b * CH + c] = mu;
  rsZ[b * CH + c] = 1.0f / sqrtf(q / M + 1e-4f);
}

// ---------- row stats -> rmean (U centering) ----------
__global__ void rowstatU_kernel(const float* __restrict__ statS1, const float* __restrict__ msum,
                                float* __restrict__ rmean) {
  const int b = blockIdx.x;
  const int c = threadIdx.x;
  const size_t base = ((size_t)b * CH + c) * 8;
  float S1 = 0.f;
  #pragma unroll
  for (int k = 0; k < 8; k++) S1 += statS1[base + k];
  rmean[b * CH + c] = S1 / msum[b];
}

// ---------- fused: normalize Zcur rows + pos row, transpose, split, n2 partials ----------
__global__ void tsplitY_kernel(const float* __restrict__ Zcur, const float* __restrict__ mask,
                               const float* __restrict__ muZ, const float* __restrict__ rsZ,
                               const float* __restrict__ pmpos, ush* __restrict__ Th,
                               ush* __restrict__ Tl, float* __restrict__ n2part) {
  __shared__ float t[32][65];
  const int b = blockIdx.z;
  const int n0 = blockIdx.x * 64;
  const int k0 = blockIdx.y * 32;
  const int tid = threadIdx.x;
  const int lr = tid >> 3;
  const int lc = (tid & 7) * 8;
  const int gk = k0 + lr;
  float xv[8];
  if (gk < CH) {
    const float mu = muZ[b * CH + gk];
    const float rs = rsZ[b * CH + gk];
    const float* zr = Zcur + ((size_t)b * CH + gk) * NN + n0 + lc;
    const float* mr = mask + b * NN + n0 + lc;
    const float4 z0 = *(const float4*)&zr[0];
    const float4 z1 = *(const float4*)&zr[4];
    const float4 m0 = *(const float4*)&mr[0];
    const float4 m1 = *(const float4*)&mr[4];
    xv[0] = (z0.x - mu * m0.x) * rs; xv[1] = (z0.y - mu * m0.y) * rs;
    xv[2] = (z0.z - mu * m0.z) * rs; xv[3] = (z0.w - mu * m0.w) * rs;
    xv[4] = (z1.x - mu * m1.x) * rs; xv[5] = (z1.y - mu * m1.y) * rs;
    xv[6] = (z1.z - mu * m1.z) * rs; xv[7] = (z1.w - mu * m1.w) * rs;
  } else if (gk == CH) {
    const float pm = pmpos[b];
    #pragma unroll
    for (int j = 0; j < 8; j++) {
      const int n = n0 + lc + j;
      xv[j] = 0.5f * ((float)n * (1.0f / (NN - 1))) * mask[b * NN + n] - pm;
    }
  } else {
    #pragma unroll
    for (int j = 0; j < 8; j++) xv[j] = 0.f;
  }
  #pragma unroll
  for (int j = 0; j < 8; j++) t[lr][lc + j] = xv[j];
  __syncthreads();
  const int on = tid >> 2;
  const int ok = (tid & 3) * 8;
  ush hv[8], lv[8];
  float s = 0.f;
  #pragma unroll
  for (int j = 0; j < 8; j++) {
    const float v = t[ok + j][on];
    s += v * v;
    hv[j] = bf16_rne(v); lv[j] = bf16_rne(v - bf16_f(hv[j]));
  }
  const size_t off = ((size_t)b * NN + n0 + on) * KPAD + k0 + ok;
  *(ushort4*)&Th[off] = *(ushort4*)&hv[0];
  *(ushort4*)&Th[off + 4] = *(ushort4*)&hv[4];
  *(ushort4*)&Tl[off] = *(ushort4*)&lv[0];
  *(ushort4*)&Tl[off + 4] = *(ushort4*)&lv[4];
  s += __shfl_xor(s, 1, 64);
  s += __shfl_xor(s, 2, 64);
  if ((tid & 3) == 0) n2part[((size_t)b * 9 + blockIdx.y) * NN + n0 + on] = s;
}

// ---------- n2 reduce over 9 k-blocks ----------
__global__ void n2red_kernel(const float* __restrict__ n2part, float* __restrict__ n2) {
  const int idx = blockIdx.x * 256 + threadIdx.x;
  const int b = idx >> 10, n = idx & 1023;
  float s = 0.f;
  #pragma unroll
  for (int kb = 0; kb < 9; kb++) s += n2part[((size_t)b * 9 + kb) * NN + n];
  n2[idx] = s;
}

// ---------- gram v4: upper-tri tiles, fp16 D direct fragment stores ----------
__global__ __launch_bounds__(256, 2)
void gram_v4_kernel(const ush* __restrict__ Yth, const ush* __restrict__ Ytl,
                    const float* __restrict__ n2, const float* __restrict__ mask,
                    ush* __restrict__ Dp, float* __restrict__ sigpart) {
  __shared__ ush lds[32768];
  const int bid = blockIdx.x;
  const int logical = (bid & 7) * 72 + (bid >> 3);
  const int b = logical / 36;
  int t = logical - b * 36;
  int ty = 0;
  while (t >= 8 - ty) { t -= 8 - ty; ++ty; }
  const int tx = ty + t;                 // ty <= tx (upper triangle)
  const int i0 = ty * 128;
  const int j0 = tx * 128;
  const ush* Ah = Yth + (size_t)b * NN * KPAD + (size_t)i0 * KPAD;
  const ush* Al = Ytl + (size_t)b * NN * KPAD + (size_t)i0 * KPAD;
  const ush* Bh = Yth + (size_t)b * NN * KPAD + (size_t)j0 * KPAD;
  const ush* Bl = Ytl + (size_t)b * NN * KPAD + (size_t)j0 * KPAD;
  f4 acc[4][4];
  const f4 z4 = {0.f, 0.f, 0.f, 0.f};
  #pragma unroll
  for (int mi = 0; mi < 4; mi++)
    #pragma unroll
    for (int ni = 0; ni < 4; ni++) acc[mi][ni] = z4;
  stageA(Ah, Al, KPAD, Bh, Bl, KPAD, 0, lds);
  __syncthreads();
  int pb = 0;
  for (int kt = 32; kt < KPAD; kt += 32) {
    stageA(Ah, Al, KPAD, Bh, Bl, KPAD, kt, lds + (pb ^ 1) * 16384);
    computeA(lds + pb * 16384, acc);
    __syncthreads();
    pb ^= 1;
  }
  computeA(lds + pb * 16384, acc);
  const int lane = threadIdx.x & 63;
  const int wid = threadIdx.x >> 6;
  const int wr = wid >> 1, wc = wid & 1;
  const int frow = lane & 15, hh = lane >> 4;
  const float scale = 3.0f / 257.0f;
  float lsum = 0.f;
  #pragma unroll
  for (int ni = 0; ni < 4; ni++) {
    const int jl = wc * 64 + ni * 16 + frow;
    const int j = j0 + jl;
    const float n2j = n2[b * NN + j];
    const float mkj = mask[b * NN + j];
    #pragma unroll
    for (int mi = 0; mi < 4; mi++) {
      const int il = wr * 64 + mi * 16 + hh * 4;
      ush dv[4];
      #pragma unroll
      for (int r = 0; r < 4; r++) {
        const int i = i0 + il + r;
        const float D = scale * (n2[b * NN + i] + n2j - 2.0f * acc[mi][ni][r]);
        const float d = sqrtf(fmaxf(D, 1e-12f));
        const float mmv = mask[b * NN + i] * mkj;
        const float wd = d * mmv;
        lsum += wd * mmv;
        dv[r] = f2h(wd);
      }
      // mirror store: D[j][i0+il..il+3] (8B/lane, 32B contiguous across hh)
      if (ty != tx) {
        uint2 mr;
        mr.x = (unsigned)dv[0] | ((unsigned)dv[1] << 16);
        mr.y = (unsigned)dv[2] | ((unsigned)dv[3] << 16);
        *(uint2*)&Dp[((size_t)b * NN + j) * NN + i0 + il] = mr;
      }
      // primary store: rows i, cols j; pair adjacent frow lanes -> u32
      #pragma unroll
      for (int r = 0; r < 4; r++) {
        const unsigned v = dv[r];
        const unsigned vp = (unsigned)__shfl_xor((int)v, 1, 64);
        if ((frow & 1) == 0)
          *(unsigned*)&Dp[((size_t)b * NN + i0 + il + r) * NN + j] = v | (vp << 16);
      }
    }
  }
  if (ty != tx) lsum *= 2.0f;
  #pragma unroll
  for (int off = 32; off > 0; off >>= 1) lsum += __shfl_down(lsum, off, 64);
  __syncthreads();
  float* rbuf = (float*)lds;
  if (lane == 0) rbuf[wid] = lsum;
  __syncthreads();
  if (threadIdx.x == 0)
    sigpart[(size_t)b * 64 + ty * 8 + tx] = rbuf[0] + rbuf[1] + rbuf[2] + rbuf[3];
}

// ---------- finalize sigma -> fb = -10*msum^2/signum ----------
__global__ void sigfinal_kernel(const float* __restrict__ sigpart, const float* __restrict__ msum,
                                float* __restrict__ fbuf) {
  const int b = blockIdx.x;
  float v = 0.f;
  if (threadIdx.x < 64) {
    const int ty = threadIdx.x >> 3, tx = threadIdx.x & 7;
    if (ty <= tx) v = sigpart[b * 64 + threadIdx.x];
  }
  v = blockReduceSum(v);
  if (threadIdx.x == 0) { const float ms = msum[b]; fbuf[b] = -10.0f * ms * ms / v; }
}

// ---------- expw v2: read fp16 D (in place over Wl), write W' = diag(s)-W splits ----------
__global__ void expw2_kernel(const ush* __restrict__ Dp, const float* __restrict__ mask,
                             const float* __restrict__ fbuf, ush* __restrict__ Wh,
                             ush* __restrict__ Wl) {
  const int b = blockIdx.y, n = blockIdx.x;
  const float fb = fbuf[b];
  const float mn = mask[b * NN + n];
  const size_t roff = ((size_t)b * NN + n) * NN;
  const int t = threadIdx.x;
  const float4 mk = ((const float4*)(mask + b * NN))[t];
  const ushort4 dp = *(const ushort4*)&Dp[roff + t * 4];
  const float w0 = expf(fb * h2f(dp.x)) * mn * mk.x;
  const float w1 = expf(fb * h2f(dp.y)) * mn * mk.y;
  const float w2 = expf(fb * h2f(dp.z)) * mn * mk.z;
  const float w3 = expf(fb * h2f(dp.w)) * mn * mk.w;
  const float s = blockReduceSum(w0 + w1 + w2 + w3);
  float v0 = -w0, v1 = -w1, v2 = -w2, v3 = -w3;
  if ((n >> 2) == t) {
    const int r = n & 3;
    if (r == 0) v0 += s; else if (r == 1) v1 += s; else if (r == 2) v2 += s; else v3 += s;
  }
  ushort4 h4, l4;
  h4.x = bf16_rne(v0); l4.x = bf16_rne(v0 - bf16_f(h4.x));
  h4.y = bf16_rne(v1); l4.y = bf16_rne(v1 - bf16_f(h4.y));
  h4.z = bf16_rne(v2); l4.z = bf16_rne(v2 - bf16_f(h4.z));
  h4.w = bf16_rne(v3); l4.w = bf16_rne(v3 - bf16_f(h4.w));
  *(ushort4*)&Wh[roff + t * 4] = h4;
  *(ushort4*)&Wl[roff + t * 4] = l4;
}

// ---------- transpose+split: in fp32 [M][NN] -> Th/Tl bf16 [NN][Kpad] ----------
__global__ void tsplit_kernel(const float* __restrict__ in, const int inBatch, const int Mvalid,
                              ush* __restrict__ Th, ush* __restrict__ Tl, const int Kpad) {
  __shared__ float t[32][65];
  const int b = blockIdx.z;
  const int n0 = blockIdx.x * 64;
  const int k0 = blockIdx.y * 32;
  const float* src = in + (size_t)b * inBatch;
  const int tid = threadIdx.x;
  const int lr = tid >> 3;
  const int lc = (tid & 7) * 8;
  const int gk = k0 + lr;
  if (gk < Mvalid) {
    *(float4*)&t[lr][lc]     = *(const float4*)&src[(size_t)gk * NN + n0 + lc];
    *(float4*)&t[lr][lc + 4] = *(const float4*)&src[(size_t)gk * NN + n0 + lc + 4];
  } else {
    const float4 z4 = {0.f, 0.f, 0.f, 0.f};
    *(float4*)&t[lr][lc] = z4; *(float4*)&t[lr][lc + 4] = z4;
  }
  __syncthreads();
  const int on = tid >> 2;
  const int ok = (tid & 3) * 8;
  ush hv[8], lv[8];
  #pragma unroll
  for (int j = 0; j < 8; j++) {
    const float v = t[ok + j][on];
    hv[j] = bf16_rne(v); lv[j] = bf16_rne(v - bf16_f(hv[j]));
  }
  const size_t off = ((size_t)b * NN + n0 + on) * Kpad + k0 + ok;
  *(ushort4*)&Th[off] = *(ushort4*)&hv[0];
  *(ushort4*)&Th[off + 4] = *(ushort4*)&hv[4];
  *(ushort4*)&Tl[off] = *(ushort4*)&lv[0];
  *(ushort4*)&Tl[off + 4] = *(ushort4*)&lv[4];
}

// ---------- cvall: C[g] = Kis[g]*(W[g]@X)*mask; XCD-swizzled 1D grid (768) ----------
__global__ __launch_bounds__(256, 2)
void cvall_kernel(const ush* __restrict__ Amh, const ush* __restrict__ Aml,
                  const ush* __restrict__ Bth, const ush* __restrict__ Btl,
                  const float* __restrict__ mask, const float* __restrict__ Kis,
                  unsigned int* __restrict__ Cpack, ush* __restrict__ C2h,
                  ush* __restrict__ C2l) {
  __shared__ ush lds[32768];
  const int bid = blockIdx.x;
  const int logical = (bid & 7) * 96 + (bid >> 3);
  const int b = logical / 48;
  const int inner = logical - b * 48;
  const int c0g = inner & 7;
  const int r0g = inner >> 3;              // 0..5
  const int r0 = r0g * 128;
  const int c0 = c0g * 128;
  const ush* Ah = Amh + (size_t)r0 * CH;
  const ush* Al = Aml + (size_t)r0 * CH;
  const ush* Bh = Bth + (size_t)b * NN * CH + (size_t)c0 * CH;
  const ush* Bl = Btl + (size_t)b * NN * CH + (size_t)c0 * CH;
  f4 acc[4][4];
  const f4 z4 = {0.f, 0.f, 0.f, 0.f};
  #pragma unroll
  for (int mi = 0; mi < 4; mi++)
    #pragma unroll
    for (int ni = 0; ni < 4; ni++) acc[mi][ni] = z4;
  stageA(Ah, Al, CH, Bh, Bl, CH, 0, lds);
  __syncthreads();
  int pb = 0;
  for (int kt = 32; kt < CH; kt += 32) {
    stageA(Ah, Al, CH, Bh, Bl, CH, kt, lds + (pb ^ 1) * 16384);
    computeA(lds + pb * 16384, acc);
    __syncthreads();
    pb ^= 1;
  }
  computeA(lds + pb * 16384, acc);
  __syncthreads();
  unsigned int* tl = (unsigned int*)lds;
  const int lane = threadIdx.x & 63;
  const int wid = threadIdx.x >> 6;
  const int wr = wid >> 1, wc = wid & 1;
  const int frow = lane & 15, hh = lane >> 4;
  const float alpha = Kis[r0g >> 1];
  #pragma unroll
  for (int ni = 0; ni < 4; ni++) {
    const int jl = wc * 64 + ni * 16 + frow;
    const float am = alpha * mask[b * NN + c0 + jl];
    #pragma unroll
    for (int mi = 0; mi < 4; mi++) {
      const int il = wr * 64 + mi * 16 + hh * 4;
      unsigned int pv[4];
      #pragma unroll
      for (int r = 0; r < 4; r++) {
        const float v = acc[mi][ni][r] * am;
        const ush h = bf16_rne(v);
        const ush l = bf16_rne(v - bf16_f(h));
        pv[r] = (unsigned int)h | ((unsigned int)l << 16);
      }
      const int slot = (il >> 2) ^ (jl & 31);
      *(uint4*)&tl[jl * 128 + slot * 4] = *(uint4*)pv;
    }
  }
  __syncthreads();
  const int rrow = threadIdx.x >> 1;
  const int rch = (threadIdx.x & 1) * 64;
  if (r0g < 4) {
    unsigned int* dst = Cpack + ((size_t)b * 512 + r0 + rrow) * NN + c0 + rch;
    #pragma unroll
    for (int g = 0; g < 16; g++) {
      unsigned int pw[4];
      #pragma unroll
      for (int q = 0; q < 4; q++) {
        const int jl = rch + g * 4 + q;
        const int slot = (rrow >> 2) ^ (jl & 31);
        pw[q] = tl[jl * 128 + slot * 4 + (rrow & 3)];
      }
      *(uint4*)&dst[g * 4] = *(uint4*)pw;
    }
  } else {
    const size_t obase = ((size_t)b * 256 + (r0 - 512) + rrow) * NN + c0 + rch;
    #pragma unroll
    for (int g = 0; g < 8; g++) {
      unsigned int hw[4], lw[4];
      #pragma unroll
      for (int q = 0; q < 4; q++) {
        unsigned int h2[2], l2[2];
        #pragma unroll
        for (int e = 0; e < 2; e++) {
          const int jl = rch + g * 8 + q * 2 + e;
          const int slot = (rrow >> 2) ^ (jl & 31);
          const unsigned int v = tl[jl * 128 + slot * 4 + (rrow & 3)];
          h2[e] = v & 0xffffu; l2[e] = v >> 16;
        }
        hw[q] = h2[0] | (h2[1] << 16);
        lw[q] = l2[0] | (l2[1] << 16);
      }
      *(uint4*)&C2h[obase + g * 8] = *(uint4*)hw;
      *(uint4*)&C2l[obase + g * 8] = *(uint4*)lw;
    }
  }
}

// ---------- mm1 v4: out = X@W' + add(packed); optional row-stat partials ----------
// OUTMODE 0: planar split out (LDS transpose); 1: fp32; 2: outF = zin - 0.01*out
template <int OUTMODE, int STATS>
__global__ __launch_bounds__(256, 3)
void mm1_v4_kernel(const ush* __restrict__ Xh, const ush* __restrict__ Xl, const size_t xStride,
                   const ush* __restrict__ Wh, const ush* __restrict__ Wl,
                   const unsigned int* __restrict__ addp, const size_t aStride,
                   const float* __restrict__ zin, const float* __restrict__ mask,
                   float* __restrict__ outF, ush* __restrict__ outH, ush* __restrict__ outL,
                   float* __restrict__ statS1, float* __restrict__ statS2) {
  __shared__ ush lds[24576];
  const int bid = blockIdx.x;
  const int logical = (bid & 7) * 64 + (bid >> 3);
  const int b = logical >> 5;
  const int inner = logical & 31;
  const int n0 = (inner & 7) * 128;
  const int r0 = (inner >> 3) * 64;
  const ush* Ah = Xh + (size_t)b * xStride + (size_t)r0 * NN;
  const ush* Al = Xl + (size_t)b * xStride + (size_t)r0 * NN;
  const ush* Bh = Wh + (size_t)b * NN * NN + (size_t)n0 * NN;
  const ush* Bl = Wl + (size_t)b * NN * NN + (size_t)n0 * NN;
  f4 acc[4][2];
  const f4 z4 = {0.f, 0.f, 0.f, 0.f};
  #pragma unroll
  for (int mi = 0; mi < 4; mi++) { acc[mi][0] = z4; acc[mi][1] = z4; }
  stageB(Ah, Al, NN, Bh, Bl, NN, 0, lds);
  __syncthreads();
  int pb = 0;
  for (int kt = 32; kt < NN; kt += 32) {
    stageB(Ah, Al, NN, Bh, Bl, NN, kt, lds + (pb ^ 1) * 12288);
    computeB(lds + pb * 12288, acc);
    __syncthreads();
    pb ^= 1;
  }
  computeB(lds + pb * 12288, acc);
  const int lane = threadIdx.x & 63;
  const int wid = threadIdx.x >> 6;
  const int frow = lane & 15, hh = lane >> 4;
  if (OUTMODE == 0) {
    __syncthreads();
    unsigned int* tl = (unsigned int*)lds;   // [128][64] swizzled
    #pragma unroll
    for (int ni = 0; ni < 2; ni++) {
      const int jl = wid * 32 + ni * 16 + frow;
      const int col = n0 + jl;
      #pragma unroll
      for (int mi = 0; mi < 4; mi++) {
        const int il = mi * 16 + hh * 4;
        unsigned int pv[4];
        #pragma unroll
        for (int r = 0; r < 4; r++) {
          const int row = r0 + il + r;
          const unsigned int av = addp[(size_t)b * aStride + (size_t)row * NN + col];
          const float o = acc[mi][ni][r] + bf16_f((ush)(av & 0xffffu)) + bf16_f((ush)(av >> 16));
          const ush h = bf16_rne(o);
          const ush l = bf16_rne(o - bf16_f(h));
          pv[r] = (unsigned int)h | ((unsigned int)l << 16);
        }
        const int slot = (il >> 2) ^ (jl & 15);
        *(uint4*)&tl[jl * 64 + slot * 4] = *(uint4*)pv;
      }
    }
    __syncthreads();
    const int rrow = threadIdx.x >> 2;
    const int rch = (threadIdx.x & 3) * 32;
    const size_t obase = ((size_t)b * 256 + r0 + rrow) * NN + n0 + rch;
    #pragma unroll
    for (int g = 0; g < 4; g++) {
      unsigned int hw[4], lw[4];
      #pragma unroll
      for (int q = 0; q < 4; q++) {
        unsigned int h2[2], l2[2];
        #pragma unroll
        for (int e = 0; e < 2; e++) {
          const int jl = rch + g * 8 + q * 2 + e;
          const int slot = (rrow >> 2) ^ (jl & 15);
          const unsigned int v = tl[jl * 64 + slot * 4 + (rrow & 3)];
          h2[e] = v & 0xffffu; l2[e] = v >> 16;
        }
        hw[q] = h2[0] | (h2[1] << 16);
        lw[q] = l2[0] | (l2[1] << 16);
      }
      *(uint4*)&outH[obase + g * 8] = *(uint4*)hw;
      *(uint4*)&outL[obase + g * 8] = *(uint4*)lw;
    }
  } else {
    float a1[4][4];
    float a2[4][4];
    if (STATS) {
      #pragma unroll
      for (int mi = 0; mi < 4; mi++)
        #pragma unroll
        for (int r = 0; r < 4; r++) { a1[mi][r] = 0.f; a2[mi][r] = 0.f; }
    }
    #pragma unroll
    for (int ni = 0; ni < 2; ni++) {
      const int col = n0 + wid * 32 + ni * 16 + frow;
      const float mk = STATS ? mask[b * NN + col] : 0.f;
      #pragma unroll
      for (int mi = 0; mi < 4; mi++) {
        #pragma unroll
        for (int r = 0; r < 4; r++) {
          const int row = r0 + mi * 16 + hh * 4 + r;
          const unsigned int av = addp[(size_t)b * aStride + (size_t)row * NN + col];
          const float o = acc[mi][ni][r] + bf16_f((ush)(av & 0xffffu)) + bf16_f((ush)(av >> 16));
          const size_t ooff = (size_t)b * CH * NN + (size_t)row * NN + col;
          float val;
          if (OUTMODE == 1) val = o;
          else val = zin[ooff] - 0.01f * o;
          outF[ooff] = val;
          if (STATS) { a1[mi][r] += val * mk; a2[mi][r] += val * val * mk; }
        }
      }
    }
    if (STATS) {
      #pragma unroll
      for (int mi = 0; mi < 4; mi++)
        #pragma unroll
        for (int r = 0; r < 4; r++) {
          #pragma unroll
          for (int d = 1; d < 16; d <<= 1) {
            a1[mi][r] += __shfl_xor(a1[mi][r], d, 64);
            a2[mi][r] += __shfl_xor(a2[mi][r], d, 64);
          }
        }
      __syncthreads();
      float* s1b = (float*)lds;
      float* s2b = s1b + 256;
      if (frow == 0) {
        #pragma unroll
        for (int mi = 0; mi < 4; mi++)
          #pragma unroll
          for (int r = 0; r < 4; r++) {
            const int row = mi * 16 + hh * 4 + r;
            s1b[wid * 64 + row] = a1[mi][r];
            s2b[wid * 64 + row] = a2[mi][r];
          }
      }
      __syncthreads();
      if (threadIdx.x < 64) {
        const int row = threadIdx.x;
        const float p1 = s1b[row] + s1b[64 + row] + s1b[128 + row] + s1b[192 + row];
        const float p2 = s2b[row] + s2b[64 + row] + s2b[128 + row] + s2b[192 + row];
        const int nblk = n0 >> 7;
        statS1[((size_t)b * CH + r0 + row) * 8 + nblk] = p1;
        statS2[((size_t)b * CH + r0 + row) * 8 + nblk] = p2;
      }
    }
  }
}

// ---------- csq: partial col sums of ((U-rmean)*mask)^2, 16 c-rows per block ----------
__global__ void csq_kernel(const float* __restrict__ U, const float* __restrict__ mask,
                           const float* __restrict__ rmean, float* __restrict__ part) {
  const int b = blockIdx.y, cc = blockIdx.x;
  const int n = threadIdx.x * 4;
  const float4 m4 = *(const float4*)&mask[b * NN + n];
  float4 s4 = {0.f, 0.f, 0.f, 0.f};
  for (int r = 0; r < 16; r++) {
    const int c = cc * 16 + r;
    const float rm = rmean[b * CH + c];
    const float4 u4 = *(const float4*)&U[((size_t)b * CH + c) * NN + n];
    float a;
    a = (u4.x - rm) * m4.x; s4.x += a * a;
    a = (u4.y - rm) * m4.y; s4.y += a * a;
    a = (u4.z - rm) * m4.z; s4.z += a * a;
    a = (u4.w - rm) * m4.w; s4.w += a * a;
  }
  *(float4*)&part[((size_t)(b * 16 + cc)) * NN + n] = s4;
}

__global__ void csq2_kernel(const float* __restrict__ part, float* __restrict__ rs) {
  const int b = blockIdx.y;
  const int n = blockIdx.x * 256 + threadIdx.x;
  float s = 0.001f;
  #pragma unroll
  for (int cc = 0; cc < 16; cc++) s += part[((size_t)(b * 16 + cc)) * NN + n];
  rs[b * NN + n] = 1.0f / sqrtf(s);
}

// ---------- fused: A=(U-rmean)*mask; out = relu(A*rs) transposed splits ----------
__global__ void tsplitN_kernel(const float* __restrict__ U, const float* __restrict__ mask,
                               const float* __restrict__ rmean, const float* __restrict__ rs,
                               ush* __restrict__ Th, ush* __restrict__ Tl) {
  __shared__ float t[32][65];
  const int b = blockIdx.z;
  const int n0 = blockIdx.x * 64;
  const int k0 = blockIdx.y * 32;
  const int tid = threadIdx.x;
  const int lr = tid >> 3;
  const int lc = (tid & 7) * 8;
  const int gc = k0 + lr;
  const float rm = rmean[b * CH + gc];
  const float4 ma = *(const float4*)&mask[b * NN + n0 + lc];
  const float4 mb = *(const float4*)&mask[b * NN + n0 + lc + 4];
  const float4 ra = *(const float4*)&rs[b * NN + n0 + lc];
  const float4 rb = *(const float4*)&rs[b * NN + n0 + lc + 4];
  const float4 ua = *(const float4*)&U[((size_t)b * CH + gc) * NN + n0 + lc];
  const float4 ub = *(const float4*)&U[((size_t)b * CH + gc) * NN + n0 + lc + 4];
  t[lr][lc + 0] = fmaxf((ua.x - rm) * ma.x * ra.x, 0.f);
  t[lr][lc + 1] = fmaxf((ua.y - rm) * ma.y * ra.y, 0.f);
  t[lr][lc + 2] = fmaxf((ua.z - rm) * ma.z * ra.z, 0.f);
  t[lr][lc + 3] = fmaxf((ua.w - rm) * ma.w * ra.w, 0.f);
  t[lr][lc + 4] = fmaxf((ub.x - rm) * mb.x * rb.x, 0.f);
  t[lr][lc + 5] = fmaxf((ub.y - rm) * mb.y * rb.y, 0.f);
  t[lr][lc + 6] = fmaxf((ub.z - rm) * mb.z * rb.z, 0.f);
  t[lr][lc + 7] = fmaxf((ub.w - rm) * mb.w * rb.w, 0.f);
  __syncthreads();
  const int on = tid >> 2;
  const int ok = (tid & 3) * 8;
  ush hv[8], lv[8];
  #pragma unroll
  for (int j = 0; j < 8; j++) {
    const float v = t[ok + j][on];
    hv[j] = bf16_rne(v); lv[j] = bf16_rne(v - bf16_f(hv[j]));
  }
  const size_t off = ((size_t)b * NN + n0 + on) * CH + k0 + ok;
  *(ushort4*)&Th[off] = *(ushort4*)&hv[0];
  *(ushort4*)&Th[off + 4] = *(ushort4*)&hv[4];
  *(ushort4*)&Tl[off] = *(ushort4*)&lv[0];
  *(ushort4*)&Tl[off + 4] = *(ushort4*)&lv[4];
}

// ---------- Zout = (Wend @ Z)*mask; write + centered copy ----------
__global__ void zout_kernel(const float* __restrict__ Z, const float* __restrict__ Wend,
                            const float* __restrict__ mask, float* __restrict__ outZ,
                            float* __restrict__ Zcent) {
  const int b = blockIdx.x;
  __shared__ float w[3 * CH];
  for (int i = threadIdx.x; i < 3 * CH; i += 256) w[i] = Wend[i];
  __syncthreads();
  float a[3][4];
  #pragma unroll
  for (int j = 0; j < 4; j++) { a[0][j] = 0.f; a[1][j] = 0.f; a[2][j] = 0.f; }
  const float* Zb = Z + (size_t)b * CH * NN;
  for (int c = 0; c < CH; c++) {
    const float w0 = w[c], w1 = w[CH + c], w2 = w[2 * CH + c];
    #pragma unroll
    for (int j = 0; j < 4; j++) {
      float zv = Zb[(size_t)c * NN + threadIdx.x + j * 256];
      a[0][j] += w0 * zv; a[1][j] += w1 * zv; a[2][j] += w2 * zv;
    }
  }
  float sum[3] = {0.f, 0.f, 0.f};
  #pragma unroll
  for (int j = 0; j < 4; j++) {
    const int n = threadIdx.x + j * 256;
    const float mv = mask[b * NN + n];
    #pragma unroll
    for (int o = 0; o < 3; o++) {
      a[o][j] *= mv;
      outZ[((size_t)b * 3 + o) * NN + n] = a[o][j];
      sum[o] += a[o][j];
    }
  }
  for (int o = 0; o < 3; o++) {
    float s = blockReduceSum(sum[o]);
    const float mean = s * (1.0f / NN);
    #pragma unroll
    for (int j = 0; j < 4; j++) {
      const int n = threadIdx.x + j * 256;
      Zcent[((size_t)b * 3 + o) * NN + n] = a[o][j] - mean;
    }
  }
}

// ---------- final distances ----------
__global__ void dist_kernel(const float* __restrict__ Zcent, float* __restrict__ outD) {
  const int b = blockIdx.z;
  const int n = blockIdx.y;
  const int m = blockIdx.x * 256 + threadIdx.x;
  const float* Zb = Zcent + (size_t)b * 3 * NN;
  const float x0 = Zb[n], x1 = Zb[NN + n], x2 = Zb[2 * NN + n];
  const float d0 = x0 - Zb[m], d1 = x1 - Zb[NN + m], d2 = x2 - Zb[2 * NN + m];
  const float D = d0 * d0 + d1 * d1 + d2 * d2;
  outD[((size_t)b * NN + n) * NN + m] = sqrtf(fmaxf(D, 1e-12f));
}

extern "C" void kernel_launch(void* const* d_in, const int* in_sizes, int n_in,
                              void* d_out, int out_size, void* d_ws, size_t ws_size,
                              hipStream_t stream) {
  const float* Zin  = (const float*)d_in[0];
  const float* mask = (const float*)d_in[1];
  const float* K0   = (const float*)d_in[2];
  const float* Knet = (const float*)d_in[3];
  const float* W    = (const float*)d_in[4];
  const float* Wend = (const float*)d_in[5];
  float* out = (float*)d_out;

  ush* Whb = (ush*)out;                           // BB*NN*NN bf16 hi plane of W'
  ush* Wlb = Whb + (size_t)BB * NN * NN;          // lo plane; Dp (fp16) aliases this
  ush* Dp  = Wlb;
  float* outZ = out + (size_t)BB * NN * NN;

  float* p = (float*)d_ws;
  // union: gram phase {Yth | Ytl}; GEMM phase {Cpack u32 | C2h | C2l}
  float* uni = p; p += (size_t)BB * 768 * NN;     // 50.33 MB
  ush* Yth = (ush*)uni;
  ush* Ytl = Yth + (size_t)BB * NN * KPAD;
  unsigned int* Cpack = (unsigned int*)uni;       // BB*512*NN u32
  ush* C2h = (ush*)(uni + (size_t)BB * 512 * NN); // BB*256*NN
  ush* C2l = C2h + (size_t)BB * 256 * NN;

  float* Zcur = p; p += (size_t)BB * CH * NN;
  float* U    = p; p += (size_t)BB * CH * NN;
  ush* Zth = (ush*)p; p += (size_t)BB * NN * CH / 2;
  ush* Ztl = (ush*)p; p += (size_t)BB * NN * CH / 2;
  ush* Thb = Zth;   // alias: Zth dead after cvall; T dead before tsplitN
  ush* Tlb = Ztl;
  ush* Wmh = (ush*)p; p += (size_t)18 * CH * CH / 2;
  ush* Wml = (ush*)p; p += (size_t)18 * CH * CH / 2;
  ush* Wth = (ush*)p; p += (size_t)18 * CH * CH / 2;
  ush* Wtl = (ush*)p; p += (size_t)18 * CH * CH / 2;
  float* n2b   = p; p += BB * NN;
  float* rsb   = p; p += BB * NN;
  float* msum  = p; p += BB;
  float* pmpos = p; p += BB;
  float* sigp  = p; p += BB * 64;
  float* fbuf  = p; p += BB;
  float* rmeanb= p; p += BB * CH;
  float* muZ   = p; p += BB * CH;
  float* rsZ   = p; p += BB * CH;
  float* statS1= p; p += (size_t)BB * CH * 8;
  float* statS2= p; p += (size_t)BB * CH * 8;
  float* n2part= p; p += (size_t)BB * 9 * NN;
  float* partb = p; p += (size_t)BB * 16 * NN;
  float* Zcent = p; p += BB * 3 * NN;

  const dim3 gtsZ(NN / 64, CH / 32, BB);
  const dim3 gtsY(NN / 64, KPAD / 32, BB);
  const size_t sC = (size_t)512 * NN;         // Cpack batch stride
  const size_t sT = (size_t)CH * NN;

  masksum_kernel<<<BB, 256, 0, stream>>>(mask, msum, pmpos);
  wprep_kernel<<<dim3(16, 18), 256, 0, stream>>>(W, Wmh, Wml, Wth, Wtl);
  k0_kernel<<<dim3(CH, BB), 256, 0, stream>>>(Zin, K0, mask, Zcur, statS1, statS2);

  for (int layer = 0; layer < NLAYERS; layer++) {
    rowstatZ_kernel<<<BB, 256, 0, stream>>>(statS1, statS2, msum, muZ, rsZ);
    tsplitY_kernel<<<gtsY, 256, 0, stream>>>(Zcur, mask, muZ, rsZ, pmpos, Yth, Ytl, n2part);
    n2red_kernel<<<BB * NN / 256, 256, 0, stream>>>(n2part, n2b);
    gram_v4_kernel<<<576, 256, 0, stream>>>(Yth, Ytl, n2b, mask, Dp, sigp);
    sigfinal_kernel<<<BB, 256, 0, stream>>>(sigp, msum, fbuf);
    expw2_kernel<<<dim3(NN, BB), 256, 0, stream>>>(Dp, mask, fbuf, Whb, Wlb);
    tsplit_kernel<<<gtsZ, 256, 0, stream>>>(Zcur, CH * NN, CH, Zth, Ztl, CH);

    const ush* Amh = Wmh + (size_t)layer * 3 * CH * CH;
    const ush* Aml = Wml + (size_t)layer * 3 * CH * CH;
    const ush* Ath = Wth + (size_t)layer * 3 * CH * CH;
    const ush* Atl = Wtl + (size_t)layer * 3 * CH * CH;
    const float* Ki = Knet + layer * 3;

    // ---- Ai = C0 + (C1 + C2@L)@L, C = Ki*(Wi@Z)*mask, L rows = W' ----
    cvall_kernel<<<768, 256, 0, stream>>>(Amh, Aml, Zth, Ztl, mask, Ki, Cpack, C2h, C2l);
    mm1_v4_kernel<0, 0><<<512, 256, 0, stream>>>(C2h, C2l, sT, Whb, Wlb,
        Cpack + (size_t)256 * NN, sC, nullptr, nullptr, nullptr, Thb, Tlb, nullptr, nullptr);
    mm1_v4_kernel<1, 1><<<512, 256, 0, stream>>>(Thb, Tlb, sT, Whb, Wlb,
        Cpack, sC, nullptr, mask, U, nullptr, nullptr, statS1, statS2);

    rowstatU_kernel<<<BB, 256, 0, stream>>>(statS1, msum, rmeanb);
    csq_kernel<<<dim3(16, BB), 256, 0, stream>>>(U, mask, rmeanb, partb);
    csq2_kernel<<<dim3(NN / 256, BB), 256, 0, stream>>>(partb, rsb);
    tsplitN_kernel<<<gtsZ, 256, 0, stream>>>(U, mask, rmeanb, rsb, Zth, Ztl);

    // ---- Z -= 0.01 * (C0 + (C1 + C2@L)@L), C = Ki*(Wi^T@A)*mask ----
    cvall_kernel<<<768, 256, 0, stream>>>(Ath, Atl, Zth, Ztl, mask, Ki, Cpack, C2h, C2l);
    mm1_v4_kernel<0, 0><<<512, 256, 0, stream>>>(C2h, C2l, sT, Whb, Wlb,
        Cpack + (size_t)256 * NN, sC, nullptr, nullptr, nullptr, Thb, Tlb, nullptr, nullptr);
    mm1_v4_kernel<2, 1><<<512, 256, 0, stream>>>(Thb, Tlb, sT, Whb, Wlb,
        Cpack, sC, Zcur, mask, Zcur, nullptr, nullptr, statS1, statS2);
  }

  zout_kernel<<<BB, 256, 0, stream>>>(Zcur, Wend, mask, outZ, Zcent);
  dist_kernel<<<dim3(NN / 256, NN, BB), 256, 0, stream>>>(Zcent, out);
}

// Round 8
// 1800.557 us; speedup vs baseline: 3.1879x; 1.1827x over previous
//
#include <hip/hip_runtime.h>
#include <hip/hip_fp16.h>
#include <math.h>

#define BB 16
#define CIN 40
#define CH 256
#define NN 1024
#define KROWS 257
#define KPAD 288        // gram K padded to 9*32
#define NLAYERS 6

typedef unsigned short ush;
typedef __attribute__((ext_vector_type(8))) short bh8;
typedef __attribute__((ext_vector_type(8))) _Float16 h8;
typedef __attribute__((ext_vector_type(4))) float f4;

__device__ __forceinline__ ush bf16_rne(float x) {
  unsigned int u = __float_as_uint(x);
  u += 0x7fffu + ((u >> 16) & 1u);
  return (ush)(u >> 16);
}
__device__ __forceinline__ float bf16_f(ush h) {
  return __uint_as_float(((unsigned int)h) << 16);
}
__device__ __forceinline__ ush f2h(float x) {
  __half h = __float2half(x);
  return *(ush*)&h;
}
__device__ __forceinline__ float h2f(ush u) {
  __half h = *(__half*)&u;
  return __half2float(h);
}

#define GLD16(gp, lp) __builtin_amdgcn_global_load_lds( \
    (const __attribute__((address_space(1))) void*)(gp), \
    (__attribute__((address_space(3))) void*)(lp), 16, 0, 0)

// ---------- block reduction (256 threads = 4 waves) ----------
__device__ __forceinline__ float blockReduceSum(float v) {
  __shared__ float sred[4];
  const int lane = threadIdx.x & 63;
  const int wid  = threadIdx.x >> 6;
  #pragma unroll
  for (int off = 32; off > 0; off >>= 1) v += __shfl_down(v, off, 64);
  __syncthreads();
  if (lane == 0) sred[wid] = v;
  __syncthreads();
  return sred[0] + sred[1] + sred[2] + sred[3];
}

// ================= gram core (bf16 split, 3 products): 128x128, BK=32 =================
__device__ __forceinline__ void stageA(
    const ush* __restrict__ Ah, const ush* __restrict__ Al, const int sA,
    const ush* __restrict__ Bh, const ush* __restrict__ Bl, const int sB,
    const int kt, ush* buf) {
  const int lane = threadIdx.x & 63;
  const int wid = threadIdx.x >> 6;
  const int srow = lane >> 2;
  const int sl = (lane & 3) ^ ((srow >> 1) & 3);
  #pragma unroll
  for (int cc = 0; cc < 8; cc++) {
    const int c = wid * 8 + cc;
    const ush* src;
    if (c < 8)       src = Ah + (size_t)(c * 16 + srow) * sA + kt + sl * 8;
    else if (c < 16) src = Al + (size_t)((c - 8) * 16 + srow) * sA + kt + sl * 8;
    else if (c < 24) src = Bh + (size_t)((c - 16) * 16 + srow) * sB + kt + sl * 8;
    else             src = Bl + (size_t)((c - 24) * 16 + srow) * sB + kt + sl * 8;
    GLD16(src, buf + c * 512 + lane * 8);
  }
}

__device__ __forceinline__ void computeA(const ush* buf, f4 acc[4][4]) {
  const int lane = threadIdx.x & 63;
  const int wid = threadIdx.x >> 6;
  const int wr = wid >> 1, wc = wid & 1;
  const int frow = lane & 15;
  const int slot8 = (((lane >> 4) ^ ((frow >> 1) & 3)) << 3);
  bh8 ah[4], al[4], bh_[4], bl_[4];
  #pragma unroll
  for (int mi = 0; mi < 4; mi++) {
    const int off = (wr * 64 + mi * 16 + frow) * 32 + slot8;
    ah[mi] = *(const bh8*)&buf[off];
    al[mi] = *(const bh8*)&buf[4096 + off];
  }
  #pragma unroll
  for (int ni = 0; ni < 4; ni++) {
    const int off = (wc * 64 + ni * 16 + frow) * 32 + slot8;
    bh_[ni] = *(const bh8*)&buf[8192 + off];
    bl_[ni] = *(const bh8*)&buf[12288 + off];
  }
  #pragma unroll
  for (int mi = 0; mi < 4; mi++)
    #pragma unroll
    for (int ni = 0; ni < 4; ni++) {
      acc[mi][ni] = __builtin_amdgcn_mfma_f32_16x16x32_bf16(ah[mi], bh_[ni], acc[mi][ni], 0, 0, 0);
      acc[mi][ni] = __builtin_amdgcn_mfma_f32_16x16x32_bf16(ah[mi], bl_[ni], acc[mi][ni], 0, 0, 0);
      acc[mi][ni] = __builtin_amdgcn_mfma_f32_16x16x32_bf16(al[mi], bh_[ni], acc[mi][ni], 0, 0, 0);
    }
}

// ================= cvall core (fp16): A 1 plane + B 2 planes, 128x128, 2 products ==========
__device__ __forceinline__ void stageCV(
    const ush* __restrict__ Ap, const int sA,
    const ush* __restrict__ Bh, const ush* __restrict__ Bl, const int sB,
    const int kt, ush* buf) {
  const int lane = threadIdx.x & 63;
  const int wid = threadIdx.x >> 6;
  const int srow = lane >> 2;
  const int sl = (lane & 3) ^ ((srow >> 1) & 3);
  #pragma unroll
  for (int cc = 0; cc < 6; cc++) {
    const int c = wid * 6 + cc;
    const ush* src;
    if (c < 8)       src = Ap + (size_t)(c * 16 + srow) * sA + kt + sl * 8;
    else if (c < 16) src = Bh + (size_t)((c - 8) * 16 + srow) * sB + kt + sl * 8;
    else             src = Bl + (size_t)((c - 16) * 16 + srow) * sB + kt + sl * 8;
    GLD16(src, buf + c * 512 + lane * 8);
  }
}

__device__ __forceinline__ void computeCV(const ush* buf, f4 acc[4][4]) {
  const int lane = threadIdx.x & 63;
  const int wid = threadIdx.x >> 6;
  const int wr = wid >> 1, wc = wid & 1;
  const int frow = lane & 15;
  const int slot8 = (((lane >> 4) ^ ((frow >> 1) & 3)) << 3);
  h8 a_[4], bh_[4], bl_[4];
  #pragma unroll
  for (int mi = 0; mi < 4; mi++) {
    const int off = (wr * 64 + mi * 16 + frow) * 32 + slot8;
    a_[mi] = *(const h8*)&buf[off];
  }
  #pragma unroll
  for (int ni = 0; ni < 4; ni++) {
    const int off = (wc * 64 + ni * 16 + frow) * 32 + slot8;
    bh_[ni] = *(const h8*)&buf[4096 + off];
    bl_[ni] = *(const h8*)&buf[8192 + off];
  }
  #pragma unroll
  for (int mi = 0; mi < 4; mi++)
    #pragma unroll
    for (int ni = 0; ni < 4; ni++) {
      acc[mi][ni] = __builtin_amdgcn_mfma_f32_16x16x32_f16(a_[mi], bh_[ni], acc[mi][ni], 0, 0, 0);
      acc[mi][ni] = __builtin_amdgcn_mfma_f32_16x16x32_f16(a_[mi], bl_[ni], acc[mi][ni], 0, 0, 0);
    }
}

// ================= mm1 core (fp16): A 2 planes + B 1 plane, 64x128, 2 products =============
__device__ __forceinline__ void stageMM(
    const ush* __restrict__ Ah, const ush* __restrict__ Al, const int sA,
    const ush* __restrict__ Bp, const int sB, const int kt, ush* buf) {
  const int lane = threadIdx.x & 63;
  const int wid = threadIdx.x >> 6;
  const int srow = lane >> 2;
  const int sl = (lane & 3) ^ ((srow >> 1) & 3);
  #pragma unroll
  for (int cc = 0; cc < 4; cc++) {
    const int c = wid * 4 + cc;
    const ush* src;
    if (c < 4)       src = Ah + (size_t)(c * 16 + srow) * sA + kt + sl * 8;
    else if (c < 8)  src = Al + (size_t)((c - 4) * 16 + srow) * sA + kt + sl * 8;
    else             src = Bp + (size_t)((c - 8) * 16 + srow) * sB + kt + sl * 8;
    GLD16(src, buf + c * 512 + lane * 8);
  }
}

__device__ __forceinline__ void computeMM(const ush* buf, f4 acc[4][2]) {
  const int lane = threadIdx.x & 63;
  const int wid = threadIdx.x >> 6;
  const int frow = lane & 15;
  const int slot8 = (((lane >> 4) ^ ((frow >> 1) & 3)) << 3);
  h8 ah[4], al[4], b_[2];
  #pragma unroll
  for (int mi = 0; mi < 4; mi++) {
    const int off = (mi * 16 + frow) * 32 + slot8;
    ah[mi] = *(const h8*)&buf[off];
    al[mi] = *(const h8*)&buf[2048 + off];
  }
  #pragma unroll
  for (int ni = 0; ni < 2; ni++) {
    const int off = (wid * 32 + ni * 16 + frow) * 32 + slot8;
    b_[ni] = *(const h8*)&buf[4096 + off];
  }
  #pragma unroll
  for (int mi = 0; mi < 4; mi++)
    #pragma unroll
    for (int ni = 0; ni < 2; ni++) {
      acc[mi][ni] = __builtin_amdgcn_mfma_f32_16x16x32_f16(ah[mi], b_[ni], acc[mi][ni], 0, 0, 0);
      acc[mi][ni] = __builtin_amdgcn_mfma_f32_16x16x32_f16(al[mi], b_[ni], acc[mi][ni], 0, 0, 0);
    }
}

// ---------- Z0 = tanh(K0 @ Zin) * mask  (+ row stats S1,S2) ----------
__global__ void k0_kernel(const float* __restrict__ Zin, const float* __restrict__ K0,
                          const float* __restrict__ mask, float* __restrict__ Zc,
                          float* __restrict__ statS1, float* __restrict__ statS2) {
  const int b = blockIdx.y;
  const int o = blockIdx.x;
  __shared__ float w[CIN];
  if (threadIdx.x < CIN) w[threadIdx.x] = K0[o * CIN + threadIdx.x];
  __syncthreads();
  float s1 = 0.f, s2 = 0.f;
  for (int n = threadIdx.x; n < NN; n += 256) {
    float acc = 0.f;
    #pragma unroll
    for (int c = 0; c < CIN; c++) acc += w[c] * Zin[((size_t)b * CIN + c) * NN + n];
    const float z = tanhf(acc) * mask[b * NN + n];
    Zc[((size_t)b * CH + o) * NN + n] = z;
    s1 += z; s2 += z * z;
  }
  s1 = blockReduceSum(s1);
  s2 = blockReduceSum(s2);
  if (threadIdx.x == 0) {
    const size_t base = ((size_t)b * CH + o) * 8;
    statS1[base] = s1; statS2[base] = s2;
    #pragma unroll
    for (int k = 1; k < 8; k++) { statS1[base + k] = 0.f; statS2[base + k] = 0.f; }
  }
}

// ---------- masksum + pos-row mean ----------
__global__ void masksum_kernel(const float* __restrict__ mask, float* __restrict__ msum,
                               float* __restrict__ pmpos) {
  const int b = blockIdx.x;
  float v = 0.f, p = 0.f;
  for (int n = threadIdx.x; n < NN; n += 256) {
    const float m = mask[b * NN + n];
    v += m;
    p += 0.5f * ((float)n * (1.0f / (NN - 1))) * m;
  }
  v = blockReduceSum(v);
  p = blockReduceSum(p);
  if (threadIdx.x == 0) { msum[b] = v; pmpos[b] = p * (1.0f / NN); }
}

// ---------- W prep: fp16 single plane of W and W^T for all 18 matrices ----------
__global__ void wprep_kernel(const float* __restrict__ W, ush* __restrict__ Wm,
                             ush* __restrict__ Wt) {
  __shared__ float t[64][65];
  const int mat = blockIdx.y;
  const int ty = blockIdx.x >> 2, tx = blockIdx.x & 3;
  const float* src = W + (size_t)mat * CH * CH;
  const int tid = threadIdx.x;
  const int lr = tid >> 2;
  const int lc = (tid & 3) * 16;
  float v[16];
  #pragma unroll
  for (int j = 0; j < 16; j += 4)
    *(float4*)&v[j] = *(const float4*)&src[(size_t)(ty * 64 + lr) * CH + tx * 64 + lc + j];
  ush hv[16];
  #pragma unroll
  for (int j = 0; j < 16; j++) {
    hv[j] = f2h(v[j]);
    t[lr][lc + j] = v[j];
  }
  const size_t offm = (size_t)mat * CH * CH + (size_t)(ty * 64 + lr) * CH + tx * 64 + lc;
  #pragma unroll
  for (int j = 0; j < 16; j += 4)
    *(ushort4*)&Wm[offm + j] = *(ushort4*)&hv[j];
  __syncthreads();
  #pragma unroll
  for (int j = 0; j < 16; j++) hv[j] = f2h(t[lc + j][lr]);
  const size_t offt = (size_t)mat * CH * CH + (size_t)(tx * 64 + lr) * CH + ty * 64 + lc;
  #pragma unroll
  for (int j = 0; j < 16; j += 4)
    *(ushort4*)&Wt[offt + j] = *(ushort4*)&hv[j];
}

// ---------- row stats -> mu, rs (Z normalization) ----------
__global__ void rowstatZ_kernel(const float* __restrict__ statS1, const float* __restrict__ statS2,
                                const float* __restrict__ msum, float* __restrict__ muZ,
                                float* __restrict__ rsZ) {
  const int b = blockIdx.x;
  const int c = threadIdx.x;
  const size_t base = ((size_t)b * CH + c) * 8;
  float S1 = 0.f, S2 = 0.f;
  #pragma unroll
  for (int k = 0; k < 8; k++) { S1 += statS1[base + k]; S2 += statS2[base + k]; }
  const float M = msum[b];
  const float mu = S1 / M;
  const float q = fmaxf(S2 - mu * S1, 0.f);
  muZ[b * CH + c] = mu;
  rsZ[b * CH + c] = 1.0f / sqrtf(q / M + 1e-4f);
}

// ---------- row stats -> rmean (U centering) ----------
__global__ void rowstatU_kernel(const float* __restrict__ statS1, const float* __restrict__ msum,
                                float* __restrict__ rmean) {
  const int b = blockIdx.x;
  const int c = threadIdx.x;
  const size_t base = ((size_t)b * CH + c) * 8;
  float S1 = 0.f;
  #pragma unroll
  for (int k = 0; k < 8; k++) S1 += statS1[base + k];
  rmean[b * CH + c] = S1 / msum[b];
}

// ---------- fused: normalize Zcur rows + pos row, transpose, bf16 split, n2 partials ------
__global__ void tsplitY_kernel(const float* __restrict__ Zcur, const float* __restrict__ mask,
                               const float* __restrict__ muZ, const float* __restrict__ rsZ,
                               const float* __restrict__ pmpos, ush* __restrict__ Th,
                               ush* __restrict__ Tl, float* __restrict__ n2part) {
  __shared__ float t[32][65];
  const int b = blockIdx.z;
  const int n0 = blockIdx.x * 64;
  const int k0 = blockIdx.y * 32;
  const int tid = threadIdx.x;
  const int lr = tid >> 3;
  const int lc = (tid & 7) * 8;
  const int gk = k0 + lr;
  float xv[8];
  if (gk < CH) {
    const float mu = muZ[b * CH + gk];
    const float rs = rsZ[b * CH + gk];
    const float* zr = Zcur + ((size_t)b * CH + gk) * NN + n0 + lc;
    const float* mr = mask + b * NN + n0 + lc;
    const float4 z0 = *(const float4*)&zr[0];
    const float4 z1 = *(const float4*)&zr[4];
    const float4 m0 = *(const float4*)&mr[0];
    const float4 m1 = *(const float4*)&mr[4];
    xv[0] = (z0.x - mu * m0.x) * rs; xv[1] = (z0.y - mu * m0.y) * rs;
    xv[2] = (z0.z - mu * m0.z) * rs; xv[3] = (z0.w - mu * m0.w) * rs;
    xv[4] = (z1.x - mu * m1.x) * rs; xv[5] = (z1.y - mu * m1.y) * rs;
    xv[6] = (z1.z - mu * m1.z) * rs; xv[7] = (z1.w - mu * m1.w) * rs;
  } else if (gk == CH) {
    const float pm = pmpos[b];
    #pragma unroll
    for (int j = 0; j < 8; j++) {
      const int n = n0 + lc + j;
      xv[j] = 0.5f * ((float)n * (1.0f / (NN - 1))) * mask[b * NN + n] - pm;
    }
  } else {
    #pragma unroll
    for (int j = 0; j < 8; j++) xv[j] = 0.f;
  }
  #pragma unroll
  for (int j = 0; j < 8; j++) t[lr][lc + j] = xv[j];
  __syncthreads();
  const int on = tid >> 2;
  const int ok = (tid & 3) * 8;
  ush hv[8], lv[8];
  float s = 0.f;
  #pragma unroll
  for (int j = 0; j < 8; j++) {
    const float v = t[ok + j][on];
    s += v * v;
    hv[j] = bf16_rne(v); lv[j] = bf16_rne(v - bf16_f(hv[j]));
  }
  const size_t off = ((size_t)b * NN + n0 + on) * KPAD + k0 + ok;
  *(ushort4*)&Th[off] = *(ushort4*)&hv[0];
  *(ushort4*)&Th[off + 4] = *(ushort4*)&hv[4];
  *(ushort4*)&Tl[off] = *(ushort4*)&lv[0];
  *(ushort4*)&Tl[off + 4] = *(ushort4*)&lv[4];
  s += __shfl_xor(s, 1, 64);
  s += __shfl_xor(s, 2, 64);
  if ((tid & 3) == 0) n2part[((size_t)b * 9 + blockIdx.y) * NN + n0 + on] = s;
}

// ---------- n2 reduce over 9 k-blocks ----------
__global__ void n2red_kernel(const float* __restrict__ n2part, float* __restrict__ n2) {
  const int idx = blockIdx.x * 256 + threadIdx.x;
  const int b = idx >> 10, n = idx & 1023;
  float s = 0.f;
  #pragma unroll
  for (int kb = 0; kb < 9; kb++) s += n2part[((size_t)b * 9 + kb) * NN + n];
  n2[idx] = s;
}

// ---------- gram v4: upper-tri tiles, fp16 D direct fragment stores ----------
__global__ __launch_bounds__(256, 2)
void gram_v4_kernel(const ush* __restrict__ Yth, const ush* __restrict__ Ytl,
                    const float* __restrict__ n2, const float* __restrict__ mask,
                    ush* __restrict__ Dp, float* __restrict__ sigpart) {
  __shared__ ush lds[32768];
  const int bid = blockIdx.x;
  const int logical = (bid & 7) * 72 + (bid >> 3);
  const int b = logical / 36;
  int t = logical - b * 36;
  int ty = 0;
  while (t >= 8 - ty) { t -= 8 - ty; ++ty; }
  const int tx = ty + t;
  const int i0 = ty * 128;
  const int j0 = tx * 128;
  const ush* Ah = Yth + (size_t)b * NN * KPAD + (size_t)i0 * KPAD;
  const ush* Al = Ytl + (size_t)b * NN * KPAD + (size_t)i0 * KPAD;
  const ush* Bh = Yth + (size_t)b * NN * KPAD + (size_t)j0 * KPAD;
  const ush* Bl = Ytl + (size_t)b * NN * KPAD + (size_t)j0 * KPAD;
  f4 acc[4][4];
  const f4 z4 = {0.f, 0.f, 0.f, 0.f};
  #pragma unroll
  for (int mi = 0; mi < 4; mi++)
    #pragma unroll
    for (int ni = 0; ni < 4; ni++) acc[mi][ni] = z4;
  stageA(Ah, Al, KPAD, Bh, Bl, KPAD, 0, lds);
  __syncthreads();
  int pb = 0;
  for (int kt = 32; kt < KPAD; kt += 32) {
    stageA(Ah, Al, KPAD, Bh, Bl, KPAD, kt, lds + (pb ^ 1) * 16384);
    computeA(lds + pb * 16384, acc);
    __syncthreads();
    pb ^= 1;
  }
  computeA(lds + pb * 16384, acc);
  const int lane = threadIdx.x & 63;
  const int wid = threadIdx.x >> 6;
  const int wr = wid >> 1, wc = wid & 1;
  const int frow = lane & 15, hh = lane >> 4;
  const float scale = 3.0f / 257.0f;
  float lsum = 0.f;
  #pragma unroll
  for (int ni = 0; ni < 4; ni++) {
    const int jl = wc * 64 + ni * 16 + frow;
    const int j = j0 + jl;
    const float n2j = n2[b * NN + j];
    const float mkj = mask[b * NN + j];
    #pragma unroll
    for (int mi = 0; mi < 4; mi++) {
      const int il = wr * 64 + mi * 16 + hh * 4;
      ush dv[4];
      #pragma unroll
      for (int r = 0; r < 4; r++) {
        const int i = i0 + il + r;
        const float D = scale * (n2[b * NN + i] + n2j - 2.0f * acc[mi][ni][r]);
        const float d = sqrtf(fmaxf(D, 1e-12f));
        const float mmv = mask[b * NN + i] * mkj;
        const float wd = d * mmv;
        lsum += wd * mmv;
        dv[r] = f2h(wd);
      }
      if (ty != tx) {
        uint2 mr;
        mr.x = (unsigned)dv[0] | ((unsigned)dv[1] << 16);
        mr.y = (unsigned)dv[2] | ((unsigned)dv[3] << 16);
        *(uint2*)&Dp[((size_t)b * NN + j) * NN + i0 + il] = mr;
      }
      #pragma unroll
      for (int r = 0; r < 4; r++) {
        const unsigned v = dv[r];
        const unsigned vp = (unsigned)__shfl_xor((int)v, 1, 64);
        if ((frow & 1) == 0)
          *(unsigned*)&Dp[((size_t)b * NN + i0 + il + r) * NN + j] = v | (vp << 16);
      }
    }
  }
  if (ty != tx) lsum *= 2.0f;
  #pragma unroll
  for (int off = 32; off > 0; off >>= 1) lsum += __shfl_down(lsum, off, 64);
  __syncthreads();
  float* rbuf = (float*)lds;
  if (lane == 0) rbuf[wid] = lsum;
  __syncthreads();
  if (threadIdx.x == 0)
    sigpart[(size_t)b * 64 + ty * 8 + tx] = rbuf[0] + rbuf[1] + rbuf[2] + rbuf[3];
}

// ---------- finalize sigma ----------
__global__ void sigfinal_kernel(const float* __restrict__ sigpart, const float* __restrict__ msum,
                                float* __restrict__ fbuf) {
  const int b = blockIdx.x;
  float v = 0.f;
  if (threadIdx.x < 64) {
    const int ty = threadIdx.x >> 3, tx = threadIdx.x & 7;
    if (ty <= tx) v = sigpart[b * 64 + threadIdx.x];
  }
  v = blockReduceSum(v);
  if (threadIdx.x == 0) { const float ms = msum[b]; fbuf[b] = -10.0f * ms * ms / v; }
}

// ---------- expw v3: read fp16 D, write W' = diag(s)-W as single fp16 plane ----------
__global__ void expw3_kernel(const ush* __restrict__ Dp, const float* __restrict__ mask,
                             const float* __restrict__ fbuf, ush* __restrict__ Wp) {
  const int b = blockIdx.y, n = blockIdx.x;
  const float fb = fbuf[b];
  const float mn = mask[b * NN + n];
  const size_t roff = ((size_t)b * NN + n) * NN;
  const int t = threadIdx.x;
  const float4 mk = ((const float4*)(mask + b * NN))[t];
  const ushort4 dp = *(const ushort4*)&Dp[roff + t * 4];
  const float w0 = expf(fb * h2f(dp.x)) * mn * mk.x;
  const float w1 = expf(fb * h2f(dp.y)) * mn * mk.y;
  const float w2 = expf(fb * h2f(dp.z)) * mn * mk.z;
  const float w3 = expf(fb * h2f(dp.w)) * mn * mk.w;
  const float s = blockReduceSum(w0 + w1 + w2 + w3);
  float v0 = -w0, v1 = -w1, v2 = -w2, v3 = -w3;
  if ((n >> 2) == t) {
    const int r = n & 3;
    if (r == 0) v0 += s; else if (r == 1) v1 += s; else if (r == 2) v2 += s; else v3 += s;
  }
  ushort4 h4;
  h4.x = f2h(v0); h4.y = f2h(v1); h4.z = f2h(v2); h4.w = f2h(v3);
  *(ushort4*)&Wp[roff + t * 4] = h4;
}

// ---------- transpose+split: Zcur fp32 [CH][NN] -> fp16 splits [NN][CH] ----------
__global__ void tsplitZ_kernel(const float* __restrict__ in, ush* __restrict__ Th,
                               ush* __restrict__ Tl) {
  __shared__ float t[32][65];
  const int b = blockIdx.z;
  const int n0 = blockIdx.x * 64;
  const int k0 = blockIdx.y * 32;
  const float* src = in + (size_t)b * CH * NN;
  const int tid = threadIdx.x;
  const int lr = tid >> 3;
  const int lc = (tid & 7) * 8;
  const int gk = k0 + lr;
  *(float4*)&t[lr][lc]     = *(const float4*)&src[(size_t)gk * NN + n0 + lc];
  *(float4*)&t[lr][lc + 4] = *(const float4*)&src[(size_t)gk * NN + n0 + lc + 4];
  __syncthreads();
  const int on = tid >> 2;
  const int ok = (tid & 3) * 8;
  ush hv[8], lv[8];
  #pragma unroll
  for (int j = 0; j < 8; j++) {
    const float v = t[ok + j][on];
    hv[j] = f2h(v); lv[j] = f2h(v - h2f(hv[j]));
  }
  const size_t off = ((size_t)b * NN + n0 + on) * CH + k0 + ok;
  *(ushort4*)&Th[off] = *(ushort4*)&hv[0];
  *(ushort4*)&Th[off + 4] = *(ushort4*)&hv[4];
  *(ushort4*)&Tl[off] = *(ushort4*)&lv[0];
  *(ushort4*)&Tl[off + 4] = *(ushort4*)&lv[4];
}

// ---------- cvall v3 (fp16): C[g] = Kis[g]*(W[g]@X)*mask ----------
__global__ __launch_bounds__(256, 2)
void cvall_kernel(const ush* __restrict__ Ap, const ush* __restrict__ Bth,
                  const ush* __restrict__ Btl, const float* __restrict__ mask,
                  const float* __restrict__ Kis, unsigned int* __restrict__ Cpack,
                  ush* __restrict__ C2h, ush* __restrict__ C2l) {
  __shared__ ush lds[32768];     // dbuf uses 2*12288; epilogue uses 64 KB as u32[128][128]
  const int bid = blockIdx.x;
  const int logical = (bid & 7) * 96 + (bid >> 3);
  const int b = logical / 48;
  const int inner = logical - b * 48;
  const int c0g = inner & 7;
  const int r0g = inner >> 3;
  const int r0 = r0g * 128;
  const int c0 = c0g * 128;
  const ush* Aq = Ap + (size_t)r0 * CH;
  const ush* Bh = Bth + (size_t)b * NN * CH + (size_t)c0 * CH;
  const ush* Bl = Btl + (size_t)b * NN * CH + (size_t)c0 * CH;
  f4 acc[4][4];
  const f4 z4 = {0.f, 0.f, 0.f, 0.f};
  #pragma unroll
  for (int mi = 0; mi < 4; mi++)
    #pragma unroll
    for (int ni = 0; ni < 4; ni++) acc[mi][ni] = z4;
  stageCV(Aq, CH, Bh, Bl, CH, 0, lds);
  __syncthreads();
  int pb = 0;
  for (int kt = 32; kt < CH; kt += 32) {
    stageCV(Aq, CH, Bh, Bl, CH, kt, lds + (pb ^ 1) * 12288);
    computeCV(lds + pb * 12288, acc);
    __syncthreads();
    pb ^= 1;
  }
  computeCV(lds + pb * 12288, acc);
  __syncthreads();
  unsigned int* tl = (unsigned int*)lds;
  const int lane = threadIdx.x & 63;
  const int wid = threadIdx.x >> 6;
  const int wr = wid >> 1, wc = wid & 1;
  const int frow = lane & 15, hh = lane >> 4;
  const float alpha = Kis[r0g >> 1];
  #pragma unroll
  for (int ni = 0; ni < 4; ni++) {
    const int jl = wc * 64 + ni * 16 + frow;
    const float am = alpha * mask[b * NN + c0 + jl];
    #pragma unroll
    for (int mi = 0; mi < 4; mi++) {
      const int il = wr * 64 + mi * 16 + hh * 4;
      unsigned int pv[4];
      #pragma unroll
      for (int r = 0; r < 4; r++) {
        const float v = acc[mi][ni][r] * am;
        const ush h = f2h(v);
        const ush l = f2h(v - h2f(h));
        pv[r] = (unsigned int)h | ((unsigned int)l << 16);
      }
      const int slot = (il >> 2) ^ (jl & 31);
      *(uint4*)&tl[jl * 128 + slot * 4] = *(uint4*)pv;
    }
  }
  __syncthreads();
  const int rrow = threadIdx.x >> 1;
  const int rch = (threadIdx.x & 1) * 64;
  if (r0g < 4) {
    unsigned int* dst = Cpack + ((size_t)b * 512 + r0 + rrow) * NN + c0 + rch;
    #pragma unroll
    for (int g = 0; g < 16; g++) {
      unsigned int pw[4];
      #pragma unroll
      for (int q = 0; q < 4; q++) {
        const int jl = rch + g * 4 + q;
        const int slot = (rrow >> 2) ^ (jl & 31);
        pw[q] = tl[jl * 128 + slot * 4 + (rrow & 3)];
      }
      *(uint4*)&dst[g * 4] = *(uint4*)pw;
    }
  } else {
    const size_t obase = ((size_t)b * 256 + (r0 - 512) + rrow) * NN + c0 + rch;
    #pragma unroll
    for (int g = 0; g < 8; g++) {
      unsigned int hw[4], lw[4];
      #pragma unroll
      for (int q = 0; q < 4; q++) {
        unsigned int h2[2], l2[2];
        #pragma unroll
        for (int e = 0; e < 2; e++) {
          const int jl = rch + g * 8 + q * 2 + e;
          const int slot = (rrow >> 2) ^ (jl & 31);
          const unsigned int v = tl[jl * 128 + slot * 4 + (rrow & 3)];
          h2[e] = v & 0xffffu; l2[e] = v >> 16;
        }
        hw[q] = h2[0] | (h2[1] << 16);
        lw[q] = l2[0] | (l2[1] << 16);
      }
      *(uint4*)&C2h[obase + g * 8] = *(uint4*)hw;
      *(uint4*)&C2l[obase + g * 8] = *(uint4*)lw;
    }
  }
}

// ---------- mm1 v5 (fp16): out = X@W' + add(packed); optional row-stat partials ----------
// OUTMODE 0: planar fp16 split out; 1: fp32; 2: outF = zin - 0.01*out
template <int OUTMODE, int STATS>
__global__ __launch_bounds__(256, 3)
void mm1_v5_kernel(const ush* __restrict__ Xh, const ush* __restrict__ Xl, const size_t xStride,
                   const ush* __restrict__ Wp,
                   const unsigned int* __restrict__ addp, const size_t aStride,
                   const float* __restrict__ zin, const float* __restrict__ mask,
                   float* __restrict__ outF, ush* __restrict__ outH, ush* __restrict__ outL,
                   float* __restrict__ statS1, float* __restrict__ statS2) {
  __shared__ ush lds[16384];     // dbuf 2*8192; OUTMODE0 epilogue uses 32 KB as u32[128][64]
  const int bid = blockIdx.x;
  const int logical = (bid & 7) * 64 + (bid >> 3);
  const int b = logical >> 5;
  const int inner = logical & 31;
  const int n0 = (inner & 7) * 128;
  const int r0 = (inner >> 3) * 64;
  const ush* Ah = Xh + (size_t)b * xStride + (size_t)r0 * NN;
  const ush* Al = Xl + (size_t)b * xStride + (size_t)r0 * NN;
  const ush* Bp = Wp + (size_t)b * NN * NN + (size_t)n0 * NN;
  f4 acc[4][2];
  const f4 z4 = {0.f, 0.f, 0.f, 0.f};
  #pragma unroll
  for (int mi = 0; mi < 4; mi++) { acc[mi][0] = z4; acc[mi][1] = z4; }
  stageMM(Ah, Al, NN, Bp, NN, 0, lds);
  __syncthreads();
  int pb = 0;
  for (int kt = 32; kt < NN; kt += 32) {
    stageMM(Ah, Al, NN, Bp, NN, kt, lds + (pb ^ 1) * 8192);
    computeMM(lds + pb * 8192, acc);
    __syncthreads();
    pb ^= 1;
  }
  computeMM(lds + pb * 8192, acc);
  const int lane = threadIdx.x & 63;
  const int wid = threadIdx.x >> 6;
  const int frow = lane & 15, hh = lane >> 4;
  if (OUTMODE == 0) {
    __syncthreads();
    unsigned int* tl = (unsigned int*)lds;   // [128][64] swizzled
    #pragma unroll
    for (int ni = 0; ni < 2; ni++) {
      const int jl = wid * 32 + ni * 16 + frow;
      const int col = n0 + jl;
      #pragma unroll
      for (int mi = 0; mi < 4; mi++) {
        const int il = mi * 16 + hh * 4;
        unsigned int pv[4];
        #pragma unroll
        for (int r = 0; r < 4; r++) {
          const int row = r0 + il + r;
          const unsigned int av = addp[(size_t)b * aStride + (size_t)row * NN + col];
          const float o = acc[mi][ni][r] + h2f((ush)(av & 0xffffu)) + h2f((ush)(av >> 16));
          const ush h = f2h(o);
          const ush l = f2h(o - h2f(h));
          pv[r] = (unsigned int)h | ((unsigned int)l << 16);
        }
        const int slot = (il >> 2) ^ (jl & 15);
        *(uint4*)&tl[jl * 64 + slot * 4] = *(uint4*)pv;
      }
    }
    __syncthreads();
    const int rrow = threadIdx.x >> 2;
    const int rch = (threadIdx.x & 3) * 32;
    const size_t obase = ((size_t)b * 256 + r0 + rrow) * NN + n0 + rch;
    #pragma unroll
    for (int g = 0; g < 4; g++) {
      unsigned int hw[4], lw[4];
      #pragma unroll
      for (int q = 0; q < 4; q++) {
        unsigned int h2[2], l2[2];
        #pragma unroll
        for (int e = 0; e < 2; e++) {
          const int jl = rch + g * 8 + q * 2 + e;
          const int slot = (rrow >> 2) ^ (jl & 15);
          const unsigned int v = tl[jl * 64 + slot * 4 + (rrow & 3)];
          h2[e] = v & 0xffffu; l2[e] = v >> 16;
        }
        hw[q] = h2[0] | (h2[1] << 16);
        lw[q] = l2[0] | (l2[1] << 16);
      }
      *(uint4*)&outH[obase + g * 8] = *(uint4*)hw;
      *(uint4*)&outL[obase + g * 8] = *(uint4*)lw;
    }
  } else {
    float a1[4][4];
    float a2[4][4];
    if (STATS) {
      #pragma unroll
      for (int mi = 0; mi < 4; mi++)
        #pragma unroll
        for (int r = 0; r < 4; r++) { a1[mi][r] = 0.f; a2[mi][r] = 0.f; }
    }
    #pragma unroll
    for (int ni = 0; ni < 2; ni++) {
      const int col = n0 + wid * 32 + ni * 16 + frow;
      const float mk = STATS ? mask[b * NN + col] : 0.f;
      #pragma unroll
      for (int mi = 0; mi < 4; mi++) {
        #pragma unroll
        for (int r = 0; r < 4; r++) {
          const int row = r0 + mi * 16 + hh * 4 + r;
          const unsigned int av = addp[(size_t)b * aStride + (size_t)row * NN + col];
          const float o = acc[mi][ni][r] + h2f((ush)(av & 0xffffu)) + h2f((ush)(av >> 16));
          const size_t ooff = (size_t)b * CH * NN + (size_t)row * NN + col;
          float val;
          if (OUTMODE == 1) val = o;
          else val = zin[ooff] - 0.01f * o;
          outF[ooff] = val;
          if (STATS) { a1[mi][r] += val * mk; a2[mi][r] += val * val * mk; }
        }
      }
    }
    if (STATS) {
      #pragma unroll
      for (int mi = 0; mi < 4; mi++)
        #pragma unroll
        for (int r = 0; r < 4; r++) {
          #pragma unroll
          for (int d = 1; d < 16; d <<= 1) {
            a1[mi][r] += __shfl_xor(a1[mi][r], d, 64);
            a2[mi][r] += __shfl_xor(a2[mi][r], d, 64);
          }
        }
      __syncthreads();
      float* s1b = (float*)lds;
      float* s2b = s1b + 256;
      if (frow == 0) {
        #pragma unroll
        for (int mi = 0; mi < 4; mi++)
          #pragma unroll
          for (int r = 0; r < 4; r++) {
            const int row = mi * 16 + hh * 4 + r;
            s1b[wid * 64 + row] = a1[mi][r];
            s2b[wid * 64 + row] = a2[mi][r];
          }
      }
      __syncthreads();
      if (threadIdx.x < 64) {
        const int row = threadIdx.x;
        const float p1 = s1b[row] + s1b[64 + row] + s1b[128 + row] + s1b[192 + row];
        const float p2 = s2b[row] + s2b[64 + row] + s2b[128 + row] + s2b[192 + row];
        const int nblk = n0 >> 7;
        statS1[((size_t)b * CH + r0 + row) * 8 + nblk] = p1;
        statS2[((size_t)b * CH + r0 + row) * 8 + nblk] = p2;
      }
    }
  }
}

// ---------- csq: partial col sums of ((U-rmean)*mask)^2 ----------
__global__ void csq_kernel(const float* __restrict__ U, const float* __restrict__ mask,
                           const float* __restrict__ rmean, float* __restrict__ part) {
  const int b = blockIdx.y, cc = blockIdx.x;
  const int n = threadIdx.x * 4;
  const float4 m4 = *(const float4*)&mask[b * NN + n];
  float4 s4 = {0.f, 0.f, 0.f, 0.f};
  for (int r = 0; r < 16; r++) {
    const int c = cc * 16 + r;
    const float rm = rmean[b * CH + c];
    const float4 u4 = *(const float4*)&U[((size_t)b * CH + c) * NN + n];
    float a;
    a = (u4.x - rm) * m4.x; s4.x += a * a;
    a = (u4.y - rm) * m4.y; s4.y += a * a;
    a = (u4.z - rm) * m4.z; s4.z += a * a;
    a = (u4.w - rm) * m4.w; s4.w += a * a;
  }
  *(float4*)&part[((size_t)(b * 16 + cc)) * NN + n] = s4;
}

__global__ void csq2_kernel(const float* __restrict__ part, float* __restrict__ rs) {
  const int b = blockIdx.y;
  const int n = blockIdx.x * 256 + threadIdx.x;
  float s = 0.001f;
  #pragma unroll
  for (int cc = 0; cc < 16; cc++) s += part[((size_t)(b * 16 + cc)) * NN + n];
  rs[b * NN + n] = 1.0f / sqrtf(s);
}

// ---------- fused: A=(U-rmean)*mask; out = relu(A*rs) transposed fp16 splits ----------
__global__ void tsplitN_kernel(const float* __restrict__ U, const float* __restrict__ mask,
                               const float* __restrict__ rmean, const float* __restrict__ rs,
                               ush* __restrict__ Th, ush* __restrict__ Tl) {
  __shared__ float t[32][65];
  const int b = blockIdx.z;
  const int n0 = blockIdx.x * 64;
  const int k0 = blockIdx.y * 32;
  const int tid = threadIdx.x;
  const int lr = tid >> 3;
  const int lc = (tid & 7) * 8;
  const int gc = k0 + lr;
  const float rm = rmean[b * CH + gc];
  const float4 ma = *(const float4*)&mask[b * NN + n0 + lc];
  const float4 mb = *(const float4*)&mask[b * NN + n0 + lc + 4];
  const float4 ra = *(const float4*)&rs[b * NN + n0 + lc];
  const float4 rb = *(const float4*)&rs[b * NN + n0 + lc + 4];
  const float4 ua = *(const float4*)&U[((size_t)b * CH + gc) * NN + n0 + lc];
  const float4 ub = *(const float4*)&U[((size_t)b * CH + gc) * NN + n0 + lc + 4];
  t[lr][lc + 0] = fmaxf((ua.x - rm) * ma.x * ra.x, 0.f);
  t[lr][lc + 1] = fmaxf((ua.y - rm) * ma.y * ra.y, 0.f);
  t[lr][lc + 2] = fmaxf((ua.z - rm) * ma.z * ra.z, 0.f);
  t[lr][lc + 3] = fmaxf((ua.w - rm) * ma.w * ra.w, 0.f);
  t[lr][lc + 4] = fmaxf((ub.x - rm) * mb.x * rb.x, 0.f);
  t[lr][lc + 5] = fmaxf((ub.y - rm) * mb.y * rb.y, 0.f);
  t[lr][lc + 6] = fmaxf((ub.z - rm) * mb.z * rb.z, 0.f);
  t[lr][lc + 7] = fmaxf((ub.w - rm) * mb.w * rb.w, 0.f);
  __syncthreads();
  const int on = tid >> 2;
  const int ok = (tid & 3) * 8;
  ush hv[8], lv[8];
  #pragma unroll
  for (int j = 0; j < 8; j++) {
    const float v = t[ok + j][on];
    hv[j] = f2h(v); lv[j] = f2h(v - h2f(hv[j]));
  }
  const size_t off = ((size_t)b * NN + n0 + on) * CH + k0 + ok;
  *(ushort4*)&Th[off] = *(ushort4*)&hv[0];
  *(ushort4*)&Th[off + 4] = *(ushort4*)&hv[4];
  *(ushort4*)&Tl[off] = *(ushort4*)&lv[0];
  *(ushort4*)&Tl[off + 4] = *(ushort4*)&lv[4];
}

// ---------- Zout = (Wend @ Z)*mask; write + centered copy ----------
__global__ void zout_kernel(const float* __restrict__ Z, const float* __restrict__ Wend,
                            const float* __restrict__ mask, float* __restrict__ outZ,
                            float* __restrict__ Zcent) {
  const int b = blockIdx.x;
  __shared__ float w[3 * CH];
  for (int i = threadIdx.x; i < 3 * CH; i += 256) w[i] = Wend[i];
  __syncthreads();
  float a[3][4];
  #pragma unroll
  for (int j = 0; j < 4; j++) { a[0][j] = 0.f; a[1][j] = 0.f; a[2][j] = 0.f; }
  const float* Zb = Z + (size_t)b * CH * NN;
  for (int c = 0; c < CH; c++) {
    const float w0 = w[c], w1 = w[CH + c], w2 = w[2 * CH + c];
    #pragma unroll
    for (int j = 0; j < 4; j++) {
      float zv = Zb[(size_t)c * NN + threadIdx.x + j * 256];
      a[0][j] += w0 * zv; a[1][j] += w1 * zv; a[2][j] += w2 * zv;
    }
  }
  float sum[3] = {0.f, 0.f, 0.f};
  #pragma unroll
  for (int j = 0; j < 4; j++) {
    const int n = threadIdx.x + j * 256;
    const float mv = mask[b * NN + n];
    #pragma unroll
    for (int o = 0; o < 3; o++) {
      a[o][j] *= mv;
      outZ[((size_t)b * 3 + o) * NN + n] = a[o][j];
      sum[o] += a[o][j];
    }
  }
  for (int o = 0; o < 3; o++) {
    float s = blockReduceSum(sum[o]);
    const float mean = s * (1.0f / NN);
    #pragma unroll
    for (int j = 0; j < 4; j++) {
      const int n = threadIdx.x + j * 256;
      Zcent[((size_t)b * 3 + o) * NN + n] = a[o][j] - mean;
    }
  }
}

// ---------- final distances ----------
__global__ void dist_kernel(const float* __restrict__ Zcent, float* __restrict__ outD) {
  const int b = blockIdx.z;
  const int n = blockIdx.y;
  const int m = blockIdx.x * 256 + threadIdx.x;
  const float* Zb = Zcent + (size_t)b * 3 * NN;
  const float x0 = Zb[n], x1 = Zb[NN + n], x2 = Zb[2 * NN + n];
  const float d0 = x0 - Zb[m], d1 = x1 - Zb[NN + m], d2 = x2 - Zb[2 * NN + m];
  const float D = d0 * d0 + d1 * d1 + d2 * d2;
  outD[((size_t)b * NN + n) * NN + m] = sqrtf(fmaxf(D, 1e-12f));
}

extern "C" void kernel_launch(void* const* d_in, const int* in_sizes, int n_in,
                              void* d_out, int out_size, void* d_ws, size_t ws_size,
                              hipStream_t stream) {
  const float* Zin  = (const float*)d_in[0];
  const float* mask = (const float*)d_in[1];
  const float* K0   = (const float*)d_in[2];
  const float* Knet = (const float*)d_in[3];
  const float* W    = (const float*)d_in[4];
  const float* Wend = (const float*)d_in[5];
  float* out = (float*)d_out;

  // d_out dist region (64 MB): Wp fp16 (32 MB) | Dp fp16 (32 MB)
  ush* Wp = (ush*)out;                            // BB*NN*NN fp16 W'
  ush* Dp = Wp + (size_t)BB * NN * NN;            // BB*NN*NN fp16 distances
  float* outZ = out + (size_t)BB * NN * NN;

  float* p = (float*)d_ws;
  // union: gram phase {Yth | Ytl bf16}; GEMM phase {Cpack u32 | C2h | C2l fp16}
  float* uni = p; p += (size_t)BB * 768 * NN;     // 50.33 MB
  ush* Yth = (ush*)uni;
  ush* Ytl = Yth + (size_t)BB * NN * KPAD;
  unsigned int* Cpack = (unsigned int*)uni;       // BB*512*NN u32 (fp16 pair packed)
  ush* C2h = (ush*)(uni + (size_t)BB * 512 * NN); // BB*256*NN fp16
  ush* C2l = C2h + (size_t)BB * 256 * NN;

  float* Zcur = p; p += (size_t)BB * CH * NN;
  float* U    = p; p += (size_t)BB * CH * NN;
  ush* Zth = (ush*)p; p += (size_t)BB * NN * CH / 2;   // fp16 splits
  ush* Ztl = (ush*)p; p += (size_t)BB * NN * CH / 2;
  ush* Thb = Zth;   // alias: Zth dead after cvall; T dead before tsplitN
  ush* Tlb = Ztl;
  ush* Wm = (ush*)p; p += (size_t)18 * CH * CH / 2;    // fp16 single plane
  ush* Wt = (ush*)p; p += (size_t)18 * CH * CH / 2;
  float* n2b   = p; p += BB * NN;
  float* rsb   = p; p += BB * NN;
  float* msum  = p; p += BB;
  float* pmpos = p; p += BB;
  float* sigp  = p; p += BB * 64;
  float* fbuf  = p; p += BB;
  float* rmeanb= p; p += BB * CH;
  float* muZ   = p; p += BB * CH;
  float* rsZ   = p; p += BB * CH;
  float* statS1= p; p += (size_t)BB * CH * 8;
  float* statS2= p; p += (size_t)BB * CH * 8;
  float* n2part= p; p += (size_t)BB * 9 * NN;
  float* partb = p; p += (size_t)BB * 16 * NN;
  float* Zcent = p; p += BB * 3 * NN;

  const dim3 gtsZ(NN / 64, CH / 32, BB);
  const dim3 gtsY(NN / 64, KPAD / 32, BB);
  const size_t sC = (size_t)512 * NN;
  const size_t sT = (size_t)CH * NN;

  masksum_kernel<<<BB, 256, 0, stream>>>(mask, msum, pmpos);
  wprep_kernel<<<dim3(16, 18), 256, 0, stream>>>(W, Wm, Wt);
  k0_kernel<<<dim3(CH, BB), 256, 0, stream>>>(Zin, K0, mask, Zcur, statS1, statS2);

  for (int layer = 0; layer < NLAYERS; layer++) {
    rowstatZ_kernel<<<BB, 256, 0, stream>>>(statS1, statS2, msum, muZ, rsZ);
    tsplitY_kernel<<<gtsY, 256, 0, stream>>>(Zcur, mask, muZ, rsZ, pmpos, Yth, Ytl, n2part);
    n2red_kernel<<<BB * NN / 256, 256, 0, stream>>>(n2part, n2b);
    gram_v4_kernel<<<576, 256, 0, stream>>>(Yth, Ytl, n2b, mask, Dp, sigp);
    sigfinal_kernel<<<BB, 256, 0, stream>>>(sigp, msum, fbuf);
    expw3_kernel<<<dim3(NN, BB), 256, 0, stream>>>(Dp, mask, fbuf, Wp);
    tsplitZ_kernel<<<gtsZ, 256, 0, stream>>>(Zcur, Zth, Ztl);

    const ush* Am = Wm + (size_t)layer * 3 * CH * CH;
    const ush* At = Wt + (size_t)layer * 3 * CH * CH;
    const float* Ki = Knet + layer * 3;

    // ---- Ai = C0 + (C1 + C2@L)@L, C = Ki*(Wi@Z)*mask, L rows = W' ----
    cvall_kernel<<<768, 256, 0, stream>>>(Am, Zth, Ztl, mask, Ki, Cpack, C2h, C2l);
    mm1_v5_kernel<0, 0><<<512, 256, 0, stream>>>(C2h, C2l, sT, Wp,
        Cpack + (size_t)256 * NN, sC, nullptr, nullptr, nullptr, Thb, Tlb, nullptr, nullptr);
    mm1_v5_kernel<1, 1><<<512, 256, 0, stream>>>(Thb, Tlb, sT, Wp,
        Cpack, sC, nullptr, mask, U, nullptr, nullptr, statS1, statS2);

    rowstatU_kernel<<<BB, 256, 0, stream>>>(statS1, msum, rmeanb);
    csq_kernel<<<dim3(16, BB), 256, 0, stream>>>(U, mask, rmeanb, partb);
    csq2_kernel<<<dim3(NN / 256, BB), 256, 0, stream>>>(partb, rsb);
    tsplitN_kernel<<<gtsZ, 256, 0, stream>>>(U, mask, rmeanb, rsb, Zth, Ztl);

    // ---- Z -= 0.01 * (C0 + (C1 + C2@L)@L), C = Ki*(Wi^T@A)*mask ----
    cvall_kernel<<<768, 256, 0, stream>>>(At, Zth, Ztl, mask, Ki, Cpack, C2h, C2l);
    mm1_v5_kernel<0, 0><<<512, 256, 0, stream>>>(C2h, C2l, sT, Wp,
        Cpack + (size_t)256 * NN, sC, nullptr, nullptr, nullptr, Thb, Tlb, nullptr, nullptr);
    mm1_v5_kernel<2, 1><<<512, 256, 0, stream>>>(Thb, Tlb, sT, Wp,
        Cpack, sC, Zcur, mask, Zcur, nullptr, nullptr, statS1, statS2);
  }

  zout_kernel<<<BB, 256, 0, stream>>>(Zcur, Wend, mask, outZ, Zcent);
  dist_kernel<<<dim3(NN / 256, NN, BB), 256, 0, stream>>>(Zcent, out);
}